// Round 17
// baseline (608.786 us; speedup 1.0000x reference)
//
#include <hip/hip_runtime.h>
#include <hip/hip_bf16.h>
#include <stdint.h>

#define BB 8
#define TT 1024
#define MM 8192
#define EE 1024
#define HH 128
#define SS (MM + TT)          // 9216
#define RKEEP (MM - 1024)     // 7168 rows kept after eviction
#define NSPLIT 8
#define SCHUNK (SS / NSPLIT)  // 1152
#define NT (SCHUNK / 64)      // 18
#define BK 32
#define NKVBLK (SS / 64)      // 144

typedef __attribute__((ext_vector_type(8))) short bf16x8;
typedef __attribute__((ext_vector_type(4))) short s16x4;
typedef __attribute__((ext_vector_type(4))) float f32x4;

#define SBAR()   __builtin_amdgcn_s_barrier()
#define SCB()    __builtin_amdgcn_sched_barrier(0)

static __device__ __forceinline__ unsigned f2ord(float f) {
    unsigned u = __float_as_uint(f);
    return u ^ ((u & 0x80000000u) ? 0xFFFFFFFFu : 0x80000000u);
}
static __device__ __forceinline__ float ord2f(unsigned o) {
    unsigned u = (o & 0x80000000u) ? (o ^ 0x80000000u) : ~o;
    return __uint_as_float(u);
}
static __device__ __forceinline__ unsigned short f2bf(float x) {
    unsigned u = __float_as_uint(x);
    unsigned r = u + 0x7FFFu + ((u >> 16) & 1u);   // RNE
    return (unsigned short)(r >> 16);
}

// async global->LDS, 16B per lane; dest = wave-uniform base + lane*16
static __device__ __forceinline__ void gload_lds16(const short* g, short* l) {
    __builtin_amdgcn_global_load_lds(
        (const __attribute__((address_space(1))) void*)g,
        (__attribute__((address_space(3))) void*)l, 16, 0, 0);
}

__device__ const float SCALEF = (float)(1.0 / 96.0);  // (M+T)^-0.5

// ---------------- K0: weights->bf16 planes + zero out/qtl/rmax (fused init) ----------------
__global__ __launch_bounds__(256) void k_init(
    const float* __restrict__ Wk, const float* __restrict__ Wq, const float* __restrict__ Wv,
    short* __restrict__ wk, short* __restrict__ wq, short* __restrict__ wv,
    float* __restrict__ outZ, float* __restrict__ rmax)
{
    const int blk = blockIdx.x, tid = threadIdx.x;
    if (blk < 384) {
        int idx = blk * 256 + tid;
        int m = idx >> 15;
        int o4 = (idx & 32767) * 4;
        const float* W = m == 0 ? Wk : (m == 1 ? Wq : Wv);
        short* D = m == 0 ? wk : (m == 1 ? wq : wv);
        f32x4 v = *(const f32x4*)&W[o4];
        s16x4 h;
#pragma unroll
        for (int j = 0; j < 4; ++j) h[j] = (short)f2bf(v[j]);
        *(s16x4*)&D[o4] = h;
    } else {
        const int z = (blk - 384) * 256 + tid;       // 128 blocks
        const f32x4 zero = (f32x4){0.f, 0.f, 0.f, 0.f};
        for (int i = z; i < (BB * TT * HH) / 4; i += 128 * 256)
            ((f32x4*)outZ)[i] = zero;
        if (z == 0) outZ[BB * TT * HH] = 0.f;        // qt_loss scalar
        if (z < (BB * TT) / 4) ((f32x4*)rmax)[z] = zero;
    }
}

// ---------------- K1: fused K,V + Q projection (single dispatch, 2-deep A prefetch) ----------------
__global__ __launch_bounds__(256, 4) void k_proj(
    const float* __restrict__ memory, const int* __restrict__ mbd,
    const int* __restrict__ bpl, const float* __restrict__ pos_table,
    const float* __restrict__ inp,
    const short* __restrict__ wk, const short* __restrict__ wv,
    const short* __restrict__ wq,
    short* __restrict__ kb, short* __restrict__ vT, short* __restrict__ qb)
{
    __shared__ __align__(16) short smA[64 * 64];           // 8KB
    __shared__ __align__(16) short smB[2][2][128 * 32];    // 32KB

    const int tid = threadIdx.x;
    const int b   = blockIdx.y;
    const int lane = tid & 63, wid = tid >> 6;
    const int wc = wid;
    const int fr = lane & 15, fq = lane >> 4;
    const int arow = tid >> 2;
    const int aq   = tid & 3;
    const int wh   = (tid >> 2);
    const int wk8  = (tid & 3) * 8;
    const int wdst = wid * 512;

    if (blockIdx.x < NKVBLK) {
        // ================= KV path =================
        const int s0 = blockIdx.x * 64;
        const bool reset = (bpl[b] == 0);
        int pix;
        const float* abase;
        {
            int s = s0 + arow;
            if (s < MM) {
                int d = reset ? 1 : (mbd[b * MM + s] + 1);
                pix = 31 - __clz(d);
                abase = reset ? nullptr : &memory[((size_t)b * MM + s) * EE];
            } else {
                pix = -1;
                abase = &inp[((size_t)b * TT + (s - MM)) * EE];
            }
        }

        f32x4 accK[4][2], accV[4][2];
#pragma unroll
        for (int m = 0; m < 4; ++m)
#pragma unroll
            for (int n = 0; n < 2; ++n) {
                accK[m][n] = (f32x4){0.f, 0.f, 0.f, 0.f};
                accV[m][n] = (f32x4){0.f, 0.f, 0.f, 0.f};
            }

        auto STAGEW = [&](int e0, int buf) {
#pragma unroll
            for (int p = 0; p < 2; ++p) {
                int h = p * 64 + wh;
                int ec = wk8 ^ ((h & 3) << 3);
                size_t g = (size_t)h * EE + e0 + ec;
                gload_lds16(&wk[g], &smB[buf][0][p * 2048 + wdst]);
                gload_lds16(&wv[g], &smB[buf][1][p * 2048 + wdst]);
            }
        };
        auto LOADP = [&](int p, f32x4 xa[4]) {
            int e0 = p * 64 + aq * 16;
#pragma unroll
            for (int j = 0; j < 4; ++j) {
                f32x4 v = (f32x4){0.f, 0.f, 0.f, 0.f};
                if (abase) v = *(const f32x4*)&abase[e0 + j * 4];
                if (pix >= 0) {
                    f32x4 pt = *(const f32x4*)&pos_table[(size_t)pix * EE + e0 + j * 4];
                    v[0] += pt[0]; v[1] += pt[1]; v[2] += pt[2]; v[3] += pt[3];
                }
                xa[j] = v;
            }
        };
        auto STOREP = [&](const f32x4 xa[4]) {
#pragma unroll
            for (int j = 0; j < 2; ++j) {
                bf16x8 h;
#pragma unroll
                for (int c = 0; c < 4; ++c) {
                    h[c]     = (short)f2bf(xa[2 * j][c]);
                    h[4 + c] = (short)f2bf(xa[2 * j + 1][c]);
                }
                int g = (aq * 2 + j) ^ (arow & 7);
                *(bf16x8*)&smA[arow * 64 + g * 8] = h;
            }
        };

        f32x4 xaA[4], xaB[4];
        LOADP(0, xaA);
        STOREP(xaA);
        STAGEW(0, 0);
        __syncthreads();
        LOADP(1, xaA);            // panel 1 (odd -> xaA)
        LOADP(2, xaB);            // panel 2 (even -> xaB)

        for (int step = 0; step < 32; ++step) {
            const int wbuf = step & 1;
            const int sseg = step & 1;
            if (step < 31) STAGEW((step + 1) * BK, wbuf ^ 1);

            bf16x8 ah[4];
#pragma unroll
            for (int m = 0; m < 4; ++m) {
                int r = m * 16 + fr;
                int g = (sseg * 4 + fq) ^ (r & 7);
                ah[m] = *(const bf16x8*)&smA[r * 64 + g * 8];
            }
#pragma unroll
            for (int n = 0; n < 2; ++n) {
                int c = wc * 32 + n * 16 + fr;
                int off = c * 32 + ((fq * 8) ^ ((c & 3) << 3));
                bf16x8 kh = *(const bf16x8*)&smB[wbuf][0][off];
                bf16x8 vh = *(const bf16x8*)&smB[wbuf][1][off];
#pragma unroll
                for (int m = 0; m < 4; ++m) {
                    accK[m][n] = __builtin_amdgcn_mfma_f32_16x16x32_bf16(ah[m], kh, accK[m][n], 0, 0, 0);
                    accV[m][n] = __builtin_amdgcn_mfma_f32_16x16x32_bf16(ah[m], vh, accV[m][n], 0, 0, 0);
                }
            }
            __syncthreads();
            if (sseg == 1 && step < 31) {
                if (((step >> 1) & 1) == 0) {   // p even: panel p+1 (odd) lives in xaA
                    STOREP(xaA);
                    __syncthreads();
                    if (step <= 25) LOADP((step >> 1) + 3, xaA);
                } else {                        // p odd: panel p+1 (even) lives in xaB
                    STOREP(xaB);
                    __syncthreads();
                    if (step <= 25) LOADP((step >> 1) + 3, xaB);
                }
            }
        }

        // K epilogue
#pragma unroll
        for (int m = 0; m < 4; ++m) {
            int row = s0 + m * 16 + fq * 4;
#pragma unroll
            for (int n = 0; n < 2; ++n) {
                int col = wc * 32 + n * 16 + fr;
#pragma unroll
                for (int i = 0; i < 4; ++i)
                    kb[((size_t)b * SS + row + i) * HH + col] = (short)f2bf(accK[m][n][i]);
            }
        }
        // V epilogue: transpose via LDS (aliasing smB)
        float* tpT = (float*)smB;
#pragma unroll
        for (int hp = 0; hp < 4; ++hp) {
            __syncthreads();
            if (wc == hp) {
#pragma unroll
                for (int m = 0; m < 4; ++m)
#pragma unroll
                    for (int n = 0; n < 2; ++n) {
                        int cl = n * 16 + fr;
                        int row = m * 16 + fq * 4;
                        *(f32x4*)&tpT[cl * 68 + row] = accV[m][n];
                    }
            }
            __syncthreads();
            for (int idx = tid; idx < 32 * 16; idx += 256) {
                int hcl = idx >> 4, s4 = (idx & 15) << 2;
                f32x4 v = *(const f32x4*)&tpT[hcl * 68 + s4];
                s16x4 hi;
#pragma unroll
                for (int j = 0; j < 4; ++j) hi[j] = (short)f2bf(v[j]);
                size_t o = ((size_t)b * HH + hp * 32 + hcl) * SS + s0 + s4;
                *(s16x4*)&vT[o] = hi;
            }
        }
    } else {
        // ================= Q path =================
        const int t0 = (blockIdx.x - NKVBLK) * 64;
        const float* abase = &inp[((size_t)b * TT + t0 + arow) * EE];

        f32x4 acc[4][2];
#pragma unroll
        for (int m = 0; m < 4; ++m)
#pragma unroll
            for (int n = 0; n < 2; ++n) acc[m][n] = (f32x4){0.f, 0.f, 0.f, 0.f};

        auto STAGEWQ = [&](int e0, int buf) {
#pragma unroll
            for (int p = 0; p < 2; ++p) {
                int h = p * 64 + wh;
                int ec = wk8 ^ ((h & 3) << 3);
                size_t g = (size_t)h * EE + e0 + ec;
                gload_lds16(&wq[g], &smB[buf][0][p * 2048 + wdst]);
            }
        };
        auto LOADPQ = [&](int p, f32x4 xa[4]) {
            int e0 = p * 64 + aq * 16;
#pragma unroll
            for (int j = 0; j < 4; ++j) xa[j] = *(const f32x4*)&abase[e0 + j * 4];
        };
        auto STOREPQ = [&](const f32x4 xa[4]) {
#pragma unroll
            for (int j = 0; j < 2; ++j) {
                bf16x8 h;
#pragma unroll
                for (int c = 0; c < 4; ++c) {
                    h[c]     = (short)f2bf(xa[2 * j][c]);
                    h[4 + c] = (short)f2bf(xa[2 * j + 1][c]);
                }
                int g = (aq * 2 + j) ^ (arow & 7);
                *(bf16x8*)&smA[arow * 64 + g * 8] = h;
            }
        };

        f32x4 xaA[4], xaB[4];
        LOADPQ(0, xaA);
        STOREPQ(xaA);
        STAGEWQ(0, 0);
        __syncthreads();
        LOADPQ(1, xaA);
        LOADPQ(2, xaB);

        for (int step = 0; step < 32; ++step) {
            const int wbuf = step & 1;
            const int sseg = step & 1;
            if (step < 31) STAGEWQ((step + 1) * BK, wbuf ^ 1);

            bf16x8 ah[4];
#pragma unroll
            for (int m = 0; m < 4; ++m) {
                int r = m * 16 + fr;
                int g = (sseg * 4 + fq) ^ (r & 7);
                ah[m] = *(const bf16x8*)&smA[r * 64 + g * 8];
            }
#pragma unroll
            for (int n = 0; n < 2; ++n) {
                int c = wc * 32 + n * 16 + fr;
                int off = c * 32 + ((fq * 8) ^ ((c & 3) << 3));
                bf16x8 bh = *(const bf16x8*)&smB[wbuf][0][off];
#pragma unroll
                for (int m = 0; m < 4; ++m)
                    acc[m][n] = __builtin_amdgcn_mfma_f32_16x16x32_bf16(ah[m], bh, acc[m][n], 0, 0, 0);
            }
            __syncthreads();
            if (sseg == 1 && step < 31) {
                if (((step >> 1) & 1) == 0) {
                    STOREPQ(xaA);
                    __syncthreads();
                    if (step <= 25) LOADPQ((step >> 1) + 3, xaA);
                } else {
                    STOREPQ(xaB);
                    __syncthreads();
                    if (step <= 25) LOADPQ((step >> 1) + 3, xaB);
                }
            }
        }
#pragma unroll
        for (int m = 0; m < 4; ++m) {
            int row = t0 + m * 16 + fq * 4;
#pragma unroll
            for (int n = 0; n < 2; ++n) {
                int col = wc * 32 + n * 16 + fr;
#pragma unroll
                for (int i = 0; i < 4; ++i)
                    qb[((size_t)b * TT + row + i) * HH + col] = (short)f2bf(acc[m][n][i]);
            }
        }
    }
}

// ---------------- shared attn helpers ----------------
__device__ __forceinline__ void stage_k64_async(const short* __restrict__ src,
                                                size_t rowBase, int tid, short* sh)
{
#pragma unroll
    for (int c2 = 0; c2 < 4; ++c2) {
        int srow = c2 * 16 + (tid >> 4);
        int scol = ((tid & 15) * 8) ^ ((srow & 7) << 3);
        size_t g = (rowBase + srow) * HH + scol;
        gload_lds16(&src[g], &sh[c2 * 2048 + (tid >> 6) * 512]);
    }
}

__device__ __forceinline__ void stage_v64_async(const short* __restrict__ vT,
                                                int b, int st, int tid, short* vs)
{
#pragma unroll
    for (int c2 = 0; c2 < 4; ++c2) {
        int h = c2 * 32 + (tid >> 3);
        int sc = ((tid & 7) * 8) ^ ((h & 7) << 3);
        size_t g = ((size_t)b * HH + h) * SS + st + sc;
        gload_lds16(&vT[g], &vs[c2 * 2048 + (tid >> 6) * 512]);
    }
}

__device__ __forceinline__ void load_qfrags(const short* __restrict__ qb,
                                            size_t rowIx, int fq, bf16x8 qh[4])
{
    size_t base = rowIx * HH + fq * 8;
#pragma unroll
    for (int k = 0; k < 4; ++k)
        qh[k] = *(const bf16x8*)&qb[base + k * 32];
}

__device__ __forceinline__ void qk_mfma4(const bf16x8 qh[4], const short* sh,
                                         int fr, int fq, f32x4 acc[4])
{
#pragma unroll
    for (int n = 0; n < 4; ++n) {
        int sc = n * 16 + fr;
        int ro = sc * 128, msk = (sc & 7) << 3;
#pragma unroll
        for (int k = 0; k < 4; ++k) {
            int off = ro + ((k * 32 + fq * 8) ^ msk);
            bf16x8 bh = *(const bf16x8*)&sh[off];
            acc[n] = __builtin_amdgcn_mfma_f32_16x16x32_bf16(qh[k], bh, acc[n], 0, 0, 0);
        }
    }
}

// XCD-aware remap: flat f -> (b, split, ttile) with all 16 ttile-members of a
// (b,split) group sharing f%8 (same XCD under round-robin dispatch).
__device__ __forceinline__ void xcd_remap(int f, int& b, int& split, int& ttile)
{
    int xcd = f & 7, slot = f >> 3;
    int g = (slot >> 4) * 8 + xcd;    // group id in [0,64)
    ttile = slot & 15;
    b = g >> 3;
    split = g & 7;
}

// ---------------- K3: rowmax of (qk*scale)^2 via MFMA (dbuf K, 32KB) ----------------
__global__ __launch_bounds__(256) void k_rowmax(
    const short* __restrict__ qb, const short* __restrict__ kb,
    float* __restrict__ rowmax)
{
    __shared__ short Ks[2][64 * 128];   // 32KB
    const int tid = threadIdx.x, lane = tid & 63, wloc = tid >> 6;
    const int fr = lane & 15, fq = lane >> 4;
    int b, split, ttile;
    xcd_remap(blockIdx.x, b, split, ttile);
    const int t0 = ttile * 64;

    bf16x8 qh[4];
    load_qfrags(qb, (size_t)b * TT + t0 + wloc * 16 + fr, fq, qh);

    float rm[4] = {0.f, 0.f, 0.f, 0.f};
    const int sBeg = split * SCHUNK;
    const size_t kbase = (size_t)b * SS;

    stage_k64_async(kb, kbase + sBeg, tid, Ks[0]);
    __syncthreads();
    for (int t = 0; t < NT; ++t) {
        const int bf = t & 1;
        if (t + 1 < NT)
            stage_k64_async(kb, kbase + sBeg + (t + 1) * 64, tid, Ks[bf ^ 1]);
        f32x4 acc[4];
#pragma unroll
        for (int n = 0; n < 4; ++n) acc[n] = (f32x4){0.f, 0.f, 0.f, 0.f};
        __builtin_amdgcn_s_setprio(1);
        qk_mfma4(qh, Ks[bf], fr, fq, acc);
        __builtin_amdgcn_s_setprio(0);
#pragma unroll
        for (int n = 0; n < 4; ++n)
#pragma unroll
            for (int i = 0; i < 4; ++i) {
                float w = acc[n][i] * SCALEF;
                rm[i] = fmaxf(rm[i], w * w);
            }
        __syncthreads();   // next tile staged (covered by QK)
    }
#pragma unroll
    for (int d = 1; d < 16; d <<= 1)
#pragma unroll
        for (int i = 0; i < 4; ++i)
            rm[i] = fmaxf(rm[i], __shfl_xor(rm[i], d, 64));
    if (fr == 0)
#pragma unroll
        for (int i = 0; i < 4; ++i)
            atomicMax((int*)&rowmax[b * TT + t0 + wloc * 16 + fq * 4 + i], __float_as_int(rm[i]));
}

// ---------------- K4: attention — stage issued early, mid barrier lgkm-only ----------------
__global__ __launch_bounds__(256) void k_attn(
    const short* __restrict__ qb, const short* __restrict__ kb,
    const short* __restrict__ vT,
    const float* __restrict__ rowmax,
    float* __restrict__ outAcc, float* __restrict__ cpart, float* __restrict__ qtloss)
{
    __shared__ short Ks[2][64 * 128];   // 32KB
    __shared__ short Vs[2][128 * 64];   // 32KB
    __shared__ short Ph[64 * 64];       // 8KB
    __shared__ float csLDS[SCHUNK];     // 4.6KB
    __shared__ float qred[256];
    const int tid = threadIdx.x, lane = tid & 63, wloc = tid >> 6;
    const int fr = lane & 15, fq = lane >> 4;
    int b, split, ttile;
    xcd_remap(blockIdx.x, b, split, ttile);
    const int t0 = ttile * 64;

    for (int i = tid; i < SCHUNK; i += 256) csLDS[i] = 0.f;

    bf16x8 qh[4];
    load_qfrags(qb, (size_t)b * TT + t0 + wloc * 16 + fr, fq, qh);

    float inv[4];
#pragma unroll
    for (int i = 0; i < 4; ++i)
        inv[i] = 1.0f / rowmax[b * TT + t0 + wloc * 16 + fq * 4 + i];

    f32x4 oacc[8];
#pragma unroll
    for (int n = 0; n < 8; ++n) oacc[n] = (f32x4){0.f, 0.f, 0.f, 0.f};
    float qtp = 0.f;

    const int sBeg = split * SCHUNK;
    const size_t kbase = (size_t)b * SS;

    stage_k64_async(kb, kbase + sBeg, tid, Ks[0]);
    stage_v64_async(vT, b, sBeg, tid, Vs[0]);

    for (int t = 0; t < NT; ++t) {
        const int bf = t & 1;
        __syncthreads();   // stage(t) landed; Ph + victim buffers free

        if (t + 1 < NT) {  // issue next-tile staging NOW — covered by QK+softmax+PV
            stage_k64_async(kb, kbase + sBeg + (t + 1) * 64, tid, Ks[bf ^ 1]);
            stage_v64_async(vT, b, sBeg + (t + 1) * 64, tid, Vs[bf ^ 1]);
        }

        f32x4 acc[4];
#pragma unroll
        for (int n = 0; n < 4; ++n) acc[n] = (f32x4){0.f, 0.f, 0.f, 0.f};
        __builtin_amdgcn_s_setprio(1);
        qk_mfma4(qh, Ks[bf], fr, fq, acc);
        __builtin_amdgcn_s_setprio(0);

#pragma unroll
        for (int n = 0; n < 4; ++n) {
            float cp = 0.f;
#pragma unroll
            for (int i = 0; i < 4; ++i) {
                float w = acc[n][i] * SCALEF;
                float w2 = w * w;
                float wei = w2 * inv[i];
                qtp += __logf(wei + 1e-4f);
                cp += wei;
                int r = wloc * 16 + fq * 4 + i;
                int sw = (n * 16 + fr) ^ ((r & 7) << 3);
                Ph[r * 64 + sw] = (short)f2bf(wei);
            }
            cp += __shfl_xor(cp, 16, 64);
            cp += __shfl_xor(cp, 32, 64);
            if (fq == 0) atomicAdd(&csLDS[t * 64 + n * 16 + fr], cp);
        }
        asm volatile("s_waitcnt lgkmcnt(0)" ::: "memory");
        SBAR(); SCB();   // Ph visible; staged loads NOT drained
        // PV
        {
            int rA = wloc * 16 + fr;
            __builtin_amdgcn_s_setprio(1);
#pragma unroll
            for (int k = 0; k < 2; ++k) {
                int offA = rA * 64 + ((k * 32 + fq * 8) ^ ((rA & 7) << 3));
                bf16x8 ph = *(const bf16x8*)&Ph[offA];
#pragma unroll
                for (int n = 0; n < 8; ++n) {
                    int hc = n * 16 + fr;
                    int offB = hc * 64 + ((k * 32 + fq * 8) ^ ((hc & 7) << 3));
                    bf16x8 vh = *(const bf16x8*)&Vs[bf][offB];
                    oacc[n] = __builtin_amdgcn_mfma_f32_16x16x32_bf16(ph, vh, oacc[n], 0, 0, 0);
                }
            }
            __builtin_amdgcn_s_setprio(0);
        }
    }

#pragma unroll
    for (int n = 0; n < 8; ++n)
#pragma unroll
        for (int i = 0; i < 4; ++i)
            atomicAdd(&outAcc[((size_t)b * TT + t0 + wloc * 16 + fq * 4 + i) * HH + n * 16 + fr],
                      oacc[n][i]);

    qred[tid] = qtp;
    __syncthreads();
    for (int off = 128; off; off >>= 1) {
        if (tid < off) qred[tid] += qred[tid + off];
        __syncthreads();
    }
    if (tid == 0) atomicAdd(qtloss, qred[0]);

    for (int s = tid; s < SCHUNK; s += 256)
        cpart[((size_t)(b * 16 + ttile)) * SS + sBeg + s] = csLDS[s];
}

// ---------------- K5: fused rank + in-LDS bitonic sort (8 blocks x 1024) ----------------
__global__ __launch_bounds__(1024) void k_ranksort(
    const float* __restrict__ cpart, const float* __restrict__ mrank,
    float* __restrict__ csum, unsigned long long* __restrict__ keys)
{
    __shared__ unsigned long long a[MM];   // 64KB
    __shared__ float red[1024];            // 4KB
    const int b = blockIdx.x, tid = threadIdx.x;

    // ---- rank phase ----
    float p = 0.f;
    for (int s = tid; s < SS; s += 1024) {
        float cs = 0.f;
#pragma unroll
        for (int tt = 0; tt < 16; ++tt) cs += cpart[((size_t)(b * 16 + tt)) * SS + s];
        csum[b * SS + s] = cs;
        p += cs;
    }
    red[tid] = p;
    __syncthreads();
    for (int off = 512; off; off >>= 1) {
        if (tid < off) red[tid] += red[tid + off];
        __syncthreads();
    }
    float mean = red[0] / (float)SS;
    for (int m = tid; m < MM; m += 1024) {
        float rank = ((mrank[b * MM + m] + csum[b * SS + m] / mean) - 1.0f) - 0.01f;
        a[m] = ((unsigned long long)(unsigned)(~f2ord(rank)) << 32) | (unsigned)m;
    }
    __syncthreads();

    // ---- bitonic sort phase (asc by key == desc by rank, idx tiebreak) ----
    for (int k = 2; k <= MM; k <<= 1) {
        for (int j = k >> 1; j > 0; j >>= 1) {
            for (int i = tid; i < MM; i += 1024) {
                int l = i ^ j;
                if (l > i) {
                    unsigned long long x = a[i], y = a[l];
                    bool up = ((i & k) == 0);
                    if ((x > y) == up) { a[i] = y; a[l] = x; }
                }
            }
            __syncthreads();
        }
    }
    for (int i = tid; i < MM; i += 1024) keys[(size_t)b * MM + i] = a[i];
}

// ---------------- K6: scatter sorted memory / dist / rank (prefetched) ----------------
__global__ __launch_bounds__(256) void k_scatter(
    const float* __restrict__ memory, const int* __restrict__ mbd,
    const int* __restrict__ bpl, const float* __restrict__ inp,
    const unsigned long long* __restrict__ keys,
    float* __restrict__ nmem, float* __restrict__ ndist, float* __restrict__ nrank)
{
    const int blk = blockIdx.x;
    const int b = blk >> 10;
    const int p0 = (blk & 1023) * 8;
    const bool reset = (bpl[b] == 0);
    const int tid = threadIdx.x;
    const f32x4 zero = (f32x4){0.f, 0.f, 0.f, 0.f};

    f32x4 vr[8];
    float dist[8], rankv[8];
#pragma unroll
    for (int r = 0; r < 8; ++r) {
        int p = p0 + r;
        if (p < RKEEP) {
            unsigned long long key = keys[(size_t)b * MM + p];
            int src = (int)(unsigned)(key & 0xFFFFFFFFu);
            vr[r] = reset ? zero
                          : *(const f32x4*)&memory[((size_t)b * MM + src) * EE + tid * 4];
            dist[r]  = reset ? 1.0f : (float)(mbd[b * MM + src] + 1);
            rankv[r] = ord2f(~(unsigned)(key >> 32));
        } else {
            int irow = p - RKEEP;
            vr[r] = *(const f32x4*)&inp[((size_t)b * TT + irow) * EE + tid * 4];
            dist[r] = 0.f; rankv[r] = 1.0f;
        }
    }
#pragma unroll
    for (int r = 0; r < 8; ++r) {
        int p = p0 + r;
        *(f32x4*)&nmem[((size_t)b * MM + p) * EE + tid * 4] = vr[r];
        if (tid == 0) { ndist[b * MM + p] = dist[r]; nrank[b * MM + p] = rankv[r]; }
    }
}

// ---------------- launcher ----------------
extern "C" void kernel_launch(void* const* d_in, const int* in_sizes, int n_in,
                              void* d_out, int out_size, void* d_ws, size_t ws_size,
                              hipStream_t stream)
{
    const int*   bpl    = (const int*)d_in[0];
    const float* inp    = (const float*)d_in[1];
    const float* memory = (const float*)d_in[2];
    const int*   mbd    = (const int*)d_in[3];
    const float* mrank  = (const float*)d_in[4];
    const float* pos    = (const float*)d_in[5];
    const float* Wk     = (const float*)d_in[6];
    const float* Wq     = (const float*)d_in[7];
    const float* Wv     = (const float*)d_in[8];

    float* out   = (float*)d_out;                    // [B,T,H]
    float* qtl   = out + (size_t)BB * TT * HH;       // scalar
    float* nmem  = qtl + 1;                          // [B,M,E]
    float* ndist = nmem + (size_t)BB * MM * EE;      // [B,M]
    float* nrank = ndist + (size_t)BB * MM;          // [B,M]

    char* w = (char*)d_ws;
    short* qb = (short*)w; w += (size_t)BB * TT * HH * 2;
    short* kb = (short*)w; w += (size_t)BB * SS * HH * 2;
    short* vT = (short*)w; w += (size_t)BB * HH * SS * 2;
    float* rmax = (float*)w; w += (size_t)BB * TT * 4;
    float* csum = (float*)w; w += (size_t)BB * SS * 4;
    float* cpart = (float*)w; w += (size_t)BB * 16 * SS * 4;
    unsigned long long* keys = (unsigned long long*)w; w += (size_t)BB * MM * 8;
    short* wk = (short*)w; w += (size_t)HH * EE * 2;
    short* wq = (short*)w; w += (size_t)HH * EE * 2;
    short* wv = (short*)w; w += (size_t)HH * EE * 2;
    if ((size_t)(w - (char*)d_ws) > ws_size) return;

    k_init   <<<512, 256, 0, stream>>>(Wk, Wq, Wv, wk, wq, wv, out, rmax);
    k_proj   <<<dim3(NKVBLK + TT / 64, BB), 256, 0, stream>>>(memory, mbd, bpl, pos, inp,
                                                              wk, wv, wq, kb, vT, qb);
    k_rowmax <<<NSPLIT * (TT / 64) * BB, 256, 0, stream>>>(qb, kb, rmax);
    k_attn   <<<NSPLIT * (TT / 64) * BB, 256, 0, stream>>>(qb, kb, vT,
                                                           rmax, out, cpart, qtl);
    k_ranksort<<<BB, 1024, 0, stream>>>(cpart, mrank, csum, keys);
    k_scatter<<<BB * (MM / 8), 256, 0, stream>>>(memory, mbd, bpl, inp, keys, nmem, ndist, nrank);
}

// Round 18
// 523.098 us; speedup vs baseline: 1.1638x; 1.1638x over previous
//
#include <hip/hip_runtime.h>
#include <hip/hip_bf16.h>
#include <stdint.h>

#define BB 8
#define TT 1024
#define MM 8192
#define EE 1024
#define HH 128
#define SS (MM + TT)          // 9216
#define RKEEP (MM - 1024)     // 7168 rows kept after eviction
#define NSPLIT 8
#define SCHUNK (SS / NSPLIT)  // 1152
#define NT (SCHUNK / 64)      // 18
#define BK 32
#define NKVBLK (SS / 64)      // 144

typedef __attribute__((ext_vector_type(8))) short bf16x8;
typedef __attribute__((ext_vector_type(4))) short s16x4;
typedef __attribute__((ext_vector_type(4))) float f32x4;

#define SBAR()   __builtin_amdgcn_s_barrier()
#define SCB()    __builtin_amdgcn_sched_barrier(0)

static __device__ __forceinline__ unsigned f2ord(float f) {
    unsigned u = __float_as_uint(f);
    return u ^ ((u & 0x80000000u) ? 0xFFFFFFFFu : 0x80000000u);
}
static __device__ __forceinline__ float ord2f(unsigned o) {
    unsigned u = (o & 0x80000000u) ? (o ^ 0x80000000u) : ~o;
    return __uint_as_float(u);
}
static __device__ __forceinline__ unsigned short f2bf(float x) {
    unsigned u = __float_as_uint(x);
    unsigned r = u + 0x7FFFu + ((u >> 16) & 1u);   // RNE
    return (unsigned short)(r >> 16);
}

// async global->LDS, 16B per lane; dest = wave-uniform base + lane*16
static __device__ __forceinline__ void gload_lds16(const short* g, short* l) {
    __builtin_amdgcn_global_load_lds(
        (const __attribute__((address_space(1))) void*)g,
        (__attribute__((address_space(3))) void*)l, 16, 0, 0);
}

__device__ const float SCALEF = (float)(1.0 / 96.0);  // (M+T)^-0.5

// ---------------- K0: weights->bf16 planes + zero out/qtl/rmax (fused init) ----------------
__global__ __launch_bounds__(256) void k_init(
    const float* __restrict__ Wk, const float* __restrict__ Wq, const float* __restrict__ Wv,
    short* __restrict__ wk, short* __restrict__ wq, short* __restrict__ wv,
    float* __restrict__ outZ, float* __restrict__ rmax)
{
    const int blk = blockIdx.x, tid = threadIdx.x;
    if (blk < 384) {
        int idx = blk * 256 + tid;
        int m = idx >> 15;
        int o4 = (idx & 32767) * 4;
        const float* W = m == 0 ? Wk : (m == 1 ? Wq : Wv);
        short* D = m == 0 ? wk : (m == 1 ? wq : wv);
        f32x4 v = *(const f32x4*)&W[o4];
        s16x4 h;
#pragma unroll
        for (int j = 0; j < 4; ++j) h[j] = (short)f2bf(v[j]);
        *(s16x4*)&D[o4] = h;
    } else {
        const int z = (blk - 384) * 256 + tid;       // 128 blocks
        const f32x4 zero = (f32x4){0.f, 0.f, 0.f, 0.f};
        for (int i = z; i < (BB * TT * HH) / 4; i += 128 * 256)
            ((f32x4*)outZ)[i] = zero;
        if (z == 0) outZ[BB * TT * HH] = 0.f;        // qt_loss scalar
        if (z < (BB * TT) / 4) ((f32x4*)rmax)[z] = zero;
    }
}

// ---------------- K1: fused K,V + Q projection (single dispatch) ----------------
__global__ __launch_bounds__(256, 4) void k_proj(
    const float* __restrict__ memory, const int* __restrict__ mbd,
    const int* __restrict__ bpl, const float* __restrict__ pos_table,
    const float* __restrict__ inp,
    const short* __restrict__ wk, const short* __restrict__ wv,
    const short* __restrict__ wq,
    short* __restrict__ kb, short* __restrict__ vT, short* __restrict__ qb)
{
    __shared__ __align__(16) short smA[64 * 64];           // 8KB
    __shared__ __align__(16) short smB[2][2][128 * 32];    // 32KB

    const int tid = threadIdx.x;
    const int b   = blockIdx.y;
    const int lane = tid & 63, wid = tid >> 6;
    const int wc = wid;
    const int fr = lane & 15, fq = lane >> 4;
    const int arow = tid >> 2;
    const int aq   = tid & 3;
    const int wh   = (tid >> 2);
    const int wk8  = (tid & 3) * 8;
    const int wdst = wid * 512;

    if (blockIdx.x < NKVBLK) {
        // ================= KV path =================
        const int s0 = blockIdx.x * 64;
        const bool reset = (bpl[b] == 0);
        int pix;
        const float* abase;
        {
            int s = s0 + arow;
            if (s < MM) {
                int d = reset ? 1 : (mbd[b * MM + s] + 1);
                pix = 31 - __clz(d);
                abase = reset ? nullptr : &memory[((size_t)b * MM + s) * EE];
            } else {
                pix = -1;
                abase = &inp[((size_t)b * TT + (s - MM)) * EE];
            }
        }

        f32x4 accK[4][2], accV[4][2];
#pragma unroll
        for (int m = 0; m < 4; ++m)
#pragma unroll
            for (int n = 0; n < 2; ++n) {
                accK[m][n] = (f32x4){0.f, 0.f, 0.f, 0.f};
                accV[m][n] = (f32x4){0.f, 0.f, 0.f, 0.f};
            }

        auto STAGEW = [&](int e0, int buf) {
#pragma unroll
            for (int p = 0; p < 2; ++p) {
                int h = p * 64 + wh;
                int ec = wk8 ^ ((h & 3) << 3);
                size_t g = (size_t)h * EE + e0 + ec;
                gload_lds16(&wk[g], &smB[buf][0][p * 2048 + wdst]);
                gload_lds16(&wv[g], &smB[buf][1][p * 2048 + wdst]);
            }
        };
        auto LOADP = [&](int p, f32x4 xa[4]) {
            int e0 = p * 64 + aq * 16;
#pragma unroll
            for (int j = 0; j < 4; ++j) {
                f32x4 v = (f32x4){0.f, 0.f, 0.f, 0.f};
                if (abase) v = *(const f32x4*)&abase[e0 + j * 4];
                if (pix >= 0) {
                    f32x4 pt = *(const f32x4*)&pos_table[(size_t)pix * EE + e0 + j * 4];
                    v[0] += pt[0]; v[1] += pt[1]; v[2] += pt[2]; v[3] += pt[3];
                }
                xa[j] = v;
            }
        };
        auto STOREP = [&](const f32x4 xa[4]) {
#pragma unroll
            for (int j = 0; j < 2; ++j) {
                bf16x8 h;
#pragma unroll
                for (int c = 0; c < 4; ++c) {
                    h[c]     = (short)f2bf(xa[2 * j][c]);
                    h[4 + c] = (short)f2bf(xa[2 * j + 1][c]);
                }
                int g = (aq * 2 + j) ^ (arow & 7);
                *(bf16x8*)&smA[arow * 64 + g * 8] = h;
            }
        };

        f32x4 xa[4];
        LOADP(0, xa);
        STOREP(xa);
        STAGEW(0, 0);
        __syncthreads();
        LOADP(1, xa);

        for (int step = 0; step < 32; ++step) {
            const int wbuf = step & 1;
            const int sseg = step & 1;
            if (step < 31) STAGEW((step + 1) * BK, wbuf ^ 1);

            bf16x8 ah[4];
#pragma unroll
            for (int m = 0; m < 4; ++m) {
                int r = m * 16 + fr;
                int g = (sseg * 4 + fq) ^ (r & 7);
                ah[m] = *(const bf16x8*)&smA[r * 64 + g * 8];
            }
#pragma unroll
            for (int n = 0; n < 2; ++n) {
                int c = wc * 32 + n * 16 + fr;
                int off = c * 32 + ((fq * 8) ^ ((c & 3) << 3));
                bf16x8 kh = *(const bf16x8*)&smB[wbuf][0][off];
                bf16x8 vh = *(const bf16x8*)&smB[wbuf][1][off];
#pragma unroll
                for (int m = 0; m < 4; ++m) {
                    accK[m][n] = __builtin_amdgcn_mfma_f32_16x16x32_bf16(ah[m], kh, accK[m][n], 0, 0, 0);
                    accV[m][n] = __builtin_amdgcn_mfma_f32_16x16x32_bf16(ah[m], vh, accV[m][n], 0, 0, 0);
                }
            }
            __syncthreads();
            if (sseg == 1 && step < 31) {
                STOREP(xa);
                __syncthreads();
                if (step < 29) LOADP((step >> 1) + 2, xa);
            }
        }

        // K epilogue
#pragma unroll
        for (int m = 0; m < 4; ++m) {
            int row = s0 + m * 16 + fq * 4;
#pragma unroll
            for (int n = 0; n < 2; ++n) {
                int col = wc * 32 + n * 16 + fr;
#pragma unroll
                for (int i = 0; i < 4; ++i)
                    kb[((size_t)b * SS + row + i) * HH + col] = (short)f2bf(accK[m][n][i]);
            }
        }
        // V epilogue: transpose via LDS (aliasing smB)
        float* tpT = (float*)smB;
#pragma unroll
        for (int hp = 0; hp < 4; ++hp) {
            __syncthreads();
            if (wc == hp) {
#pragma unroll
                for (int m = 0; m < 4; ++m)
#pragma unroll
                    for (int n = 0; n < 2; ++n) {
                        int cl = n * 16 + fr;
                        int row = m * 16 + fq * 4;
                        *(f32x4*)&tpT[cl * 68 + row] = accV[m][n];
                    }
            }
            __syncthreads();
            for (int idx = tid; idx < 32 * 16; idx += 256) {
                int hcl = idx >> 4, s4 = (idx & 15) << 2;
                f32x4 v = *(const f32x4*)&tpT[hcl * 68 + s4];
                s16x4 hi;
#pragma unroll
                for (int j = 0; j < 4; ++j) hi[j] = (short)f2bf(v[j]);
                size_t o = ((size_t)b * HH + hp * 32 + hcl) * SS + s0 + s4;
                *(s16x4*)&vT[o] = hi;
            }
        }
    } else {
        // ================= Q path =================
        const int t0 = (blockIdx.x - NKVBLK) * 64;
        const float* abase = &inp[((size_t)b * TT + t0 + arow) * EE];

        f32x4 acc[4][2];
#pragma unroll
        for (int m = 0; m < 4; ++m)
#pragma unroll
            for (int n = 0; n < 2; ++n) acc[m][n] = (f32x4){0.f, 0.f, 0.f, 0.f};

        auto STAGEWQ = [&](int e0, int buf) {
#pragma unroll
            for (int p = 0; p < 2; ++p) {
                int h = p * 64 + wh;
                int ec = wk8 ^ ((h & 3) << 3);
                size_t g = (size_t)h * EE + e0 + ec;
                gload_lds16(&wq[g], &smB[buf][0][p * 2048 + wdst]);
            }
        };
        auto LOADPQ = [&](int p, f32x4 xa[4]) {
            int e0 = p * 64 + aq * 16;
#pragma unroll
            for (int j = 0; j < 4; ++j) xa[j] = *(const f32x4*)&abase[e0 + j * 4];
        };
        auto STOREPQ = [&](const f32x4 xa[4]) {
#pragma unroll
            for (int j = 0; j < 2; ++j) {
                bf16x8 h;
#pragma unroll
                for (int c = 0; c < 4; ++c) {
                    h[c]     = (short)f2bf(xa[2 * j][c]);
                    h[4 + c] = (short)f2bf(xa[2 * j + 1][c]);
                }
                int g = (aq * 2 + j) ^ (arow & 7);
                *(bf16x8*)&smA[arow * 64 + g * 8] = h;
            }
        };

        f32x4 xa[4];
        LOADPQ(0, xa);
        STOREPQ(xa);
        STAGEWQ(0, 0);
        __syncthreads();
        LOADPQ(1, xa);

        for (int step = 0; step < 32; ++step) {
            const int wbuf = step & 1;
            const int sseg = step & 1;
            if (step < 31) STAGEWQ((step + 1) * BK, wbuf ^ 1);

            bf16x8 ah[4];
#pragma unroll
            for (int m = 0; m < 4; ++m) {
                int r = m * 16 + fr;
                int g = (sseg * 4 + fq) ^ (r & 7);
                ah[m] = *(const bf16x8*)&smA[r * 64 + g * 8];
            }
#pragma unroll
            for (int n = 0; n < 2; ++n) {
                int c = wc * 32 + n * 16 + fr;
                int off = c * 32 + ((fq * 8) ^ ((c & 3) << 3));
                bf16x8 bh = *(const bf16x8*)&smB[wbuf][0][off];
#pragma unroll
                for (int m = 0; m < 4; ++m)
                    acc[m][n] = __builtin_amdgcn_mfma_f32_16x16x32_bf16(ah[m], bh, acc[m][n], 0, 0, 0);
            }
            __syncthreads();
            if (sseg == 1 && step < 31) {
                STOREPQ(xa);
                __syncthreads();
                if (step < 29) LOADPQ((step >> 1) + 2, xa);
            }
        }
#pragma unroll
        for (int m = 0; m < 4; ++m) {
            int row = t0 + m * 16 + fq * 4;
#pragma unroll
            for (int n = 0; n < 2; ++n) {
                int col = wc * 32 + n * 16 + fr;
#pragma unroll
                for (int i = 0; i < 4; ++i)
                    qb[((size_t)b * TT + row + i) * HH + col] = (short)f2bf(acc[m][n][i]);
            }
        }
    }
}

// ---------------- shared attn helpers ----------------
__device__ __forceinline__ void stage_k64_async(const short* __restrict__ src,
                                                size_t rowBase, int tid, short* sh)
{
#pragma unroll
    for (int c2 = 0; c2 < 4; ++c2) {
        int srow = c2 * 16 + (tid >> 4);
        int scol = ((tid & 15) * 8) ^ ((srow & 7) << 3);
        size_t g = (rowBase + srow) * HH + scol;
        gload_lds16(&src[g], &sh[c2 * 2048 + (tid >> 6) * 512]);
    }
}

__device__ __forceinline__ void stage_v64_async(const short* __restrict__ vT,
                                                int b, int st, int tid, short* vs)
{
#pragma unroll
    for (int c2 = 0; c2 < 4; ++c2) {
        int h = c2 * 32 + (tid >> 3);
        int sc = ((tid & 7) * 8) ^ ((h & 7) << 3);
        size_t g = ((size_t)b * HH + h) * SS + st + sc;
        gload_lds16(&vT[g], &vs[c2 * 2048 + (tid >> 6) * 512]);
    }
}

__device__ __forceinline__ void load_qfrags(const short* __restrict__ qb,
                                            size_t rowIx, int fq, bf16x8 qh[4])
{
    size_t base = rowIx * HH + fq * 8;
#pragma unroll
    for (int k = 0; k < 4; ++k)
        qh[k] = *(const bf16x8*)&qb[base + k * 32];
}

__device__ __forceinline__ void qk_mfma4(const bf16x8 qh[4], const short* sh,
                                         int fr, int fq, f32x4 acc[4])
{
#pragma unroll
    for (int n = 0; n < 4; ++n) {
        int sc = n * 16 + fr;
        int ro = sc * 128, msk = (sc & 7) << 3;
#pragma unroll
        for (int k = 0; k < 4; ++k) {
            int off = ro + ((k * 32 + fq * 8) ^ msk);
            bf16x8 bh = *(const bf16x8*)&sh[off];
            acc[n] = __builtin_amdgcn_mfma_f32_16x16x32_bf16(qh[k], bh, acc[n], 0, 0, 0);
        }
    }
}

// XCD-aware remap: flat f -> (b, split, ttile) with all 16 ttile-members of a
// (b,split) group sharing f%8 (same XCD under round-robin dispatch).
__device__ __forceinline__ void xcd_remap(int f, int& b, int& split, int& ttile)
{
    int xcd = f & 7, slot = f >> 3;
    int g = (slot >> 4) * 8 + xcd;    // group id in [0,64)
    ttile = slot & 15;
    b = g >> 3;
    split = g & 7;
}

// ---------------- K3: rowmax of (qk*scale)^2 via MFMA (dbuf K, 32KB) ----------------
__global__ __launch_bounds__(256) void k_rowmax(
    const short* __restrict__ qb, const short* __restrict__ kb,
    float* __restrict__ rowmax)
{
    __shared__ short Ks[2][64 * 128];   // 32KB
    const int tid = threadIdx.x, lane = tid & 63, wloc = tid >> 6;
    const int fr = lane & 15, fq = lane >> 4;
    int b, split, ttile;
    xcd_remap(blockIdx.x, b, split, ttile);
    const int t0 = ttile * 64;

    bf16x8 qh[4];
    load_qfrags(qb, (size_t)b * TT + t0 + wloc * 16 + fr, fq, qh);

    float rm[4] = {0.f, 0.f, 0.f, 0.f};
    const int sBeg = split * SCHUNK;
    const size_t kbase = (size_t)b * SS;

    stage_k64_async(kb, kbase + sBeg, tid, Ks[0]);
    __syncthreads();
    for (int t = 0; t < NT; ++t) {
        const int bf = t & 1;
        if (t + 1 < NT)
            stage_k64_async(kb, kbase + sBeg + (t + 1) * 64, tid, Ks[bf ^ 1]);
        f32x4 acc[4];
#pragma unroll
        for (int n = 0; n < 4; ++n) acc[n] = (f32x4){0.f, 0.f, 0.f, 0.f};
        __builtin_amdgcn_s_setprio(1);
        qk_mfma4(qh, Ks[bf], fr, fq, acc);
        __builtin_amdgcn_s_setprio(0);
#pragma unroll
        for (int n = 0; n < 4; ++n)
#pragma unroll
            for (int i = 0; i < 4; ++i) {
                float w = acc[n][i] * SCALEF;
                rm[i] = fmaxf(rm[i], w * w);
            }
        __syncthreads();   // next tile staged (covered by QK)
    }
#pragma unroll
    for (int d = 1; d < 16; d <<= 1)
#pragma unroll
        for (int i = 0; i < 4; ++i)
            rm[i] = fmaxf(rm[i], __shfl_xor(rm[i], d, 64));
    if (fr == 0)
#pragma unroll
        for (int i = 0; i < 4; ++i)
            atomicMax((int*)&rowmax[b * TT + t0 + wloc * 16 + fq * 4 + i], __float_as_int(rm[i]));
}

// ---------------- K4: attention — stage issued early, mid barrier lgkm-only ----------------
__global__ __launch_bounds__(256) void k_attn(
    const short* __restrict__ qb, const short* __restrict__ kb,
    const short* __restrict__ vT,
    const float* __restrict__ rowmax,
    float* __restrict__ outAcc, float* __restrict__ cpart, float* __restrict__ qtloss)
{
    __shared__ short Ks[2][64 * 128];   // 32KB
    __shared__ short Vs[2][128 * 64];   // 32KB
    __shared__ short Ph[64 * 64];       // 8KB
    __shared__ float csLDS[SCHUNK];     // 4.6KB
    __shared__ float qred[256];
    const int tid = threadIdx.x, lane = tid & 63, wloc = tid >> 6;
    const int fr = lane & 15, fq = lane >> 4;
    int b, split, ttile;
    xcd_remap(blockIdx.x, b, split, ttile);
    const int t0 = ttile * 64;

    for (int i = tid; i < SCHUNK; i += 256) csLDS[i] = 0.f;

    bf16x8 qh[4];
    load_qfrags(qb, (size_t)b * TT + t0 + wloc * 16 + fr, fq, qh);

    float inv[4];
#pragma unroll
    for (int i = 0; i < 4; ++i)
        inv[i] = 1.0f / rowmax[b * TT + t0 + wloc * 16 + fq * 4 + i];

    f32x4 oacc[8];
#pragma unroll
    for (int n = 0; n < 8; ++n) oacc[n] = (f32x4){0.f, 0.f, 0.f, 0.f};
    float qtp = 0.f;

    const int sBeg = split * SCHUNK;
    const size_t kbase = (size_t)b * SS;

    stage_k64_async(kb, kbase + sBeg, tid, Ks[0]);
    stage_v64_async(vT, b, sBeg, tid, Vs[0]);

    for (int t = 0; t < NT; ++t) {
        const int bf = t & 1;
        __syncthreads();   // stage(t) landed; Ph + victim buffers free

        if (t + 1 < NT) {  // issue next-tile staging NOW — covered by QK+softmax+PV
            stage_k64_async(kb, kbase + sBeg + (t + 1) * 64, tid, Ks[bf ^ 1]);
            stage_v64_async(vT, b, sBeg + (t + 1) * 64, tid, Vs[bf ^ 1]);
        }

        f32x4 acc[4];
#pragma unroll
        for (int n = 0; n < 4; ++n) acc[n] = (f32x4){0.f, 0.f, 0.f, 0.f};
        __builtin_amdgcn_s_setprio(1);
        qk_mfma4(qh, Ks[bf], fr, fq, acc);
        __builtin_amdgcn_s_setprio(0);

#pragma unroll
        for (int n = 0; n < 4; ++n) {
            float cp = 0.f;
#pragma unroll
            for (int i = 0; i < 4; ++i) {
                float w = acc[n][i] * SCALEF;
                float w2 = w * w;
                float wei = w2 * inv[i];
                qtp += __logf(wei + 1e-4f);
                cp += wei;
                int r = wloc * 16 + fq * 4 + i;
                int sw = (n * 16 + fr) ^ ((r & 7) << 3);
                Ph[r * 64 + sw] = (short)f2bf(wei);
            }
            cp += __shfl_xor(cp, 16, 64);
            cp += __shfl_xor(cp, 32, 64);
            if (fq == 0) atomicAdd(&csLDS[t * 64 + n * 16 + fr], cp);
        }
        asm volatile("s_waitcnt lgkmcnt(0)" ::: "memory");
        SBAR(); SCB();   // Ph visible; staged loads NOT drained
        // PV
        {
            int rA = wloc * 16 + fr;
            __builtin_amdgcn_s_setprio(1);
#pragma unroll
            for (int k = 0; k < 2; ++k) {
                int offA = rA * 64 + ((k * 32 + fq * 8) ^ ((rA & 7) << 3));
                bf16x8 ph = *(const bf16x8*)&Ph[offA];
#pragma unroll
                for (int n = 0; n < 8; ++n) {
                    int hc = n * 16 + fr;
                    int offB = hc * 64 + ((k * 32 + fq * 8) ^ ((hc & 7) << 3));
                    bf16x8 vh = *(const bf16x8*)&Vs[bf][offB];
                    oacc[n] = __builtin_amdgcn_mfma_f32_16x16x32_bf16(ph, vh, oacc[n], 0, 0, 0);
                }
            }
            __builtin_amdgcn_s_setprio(0);
        }
    }

#pragma unroll
    for (int n = 0; n < 8; ++n)
#pragma unroll
        for (int i = 0; i < 4; ++i)
            atomicAdd(&outAcc[((size_t)b * TT + t0 + wloc * 16 + fq * 4 + i) * HH + n * 16 + fr],
                      oacc[n][i]);

    qred[tid] = qtp;
    __syncthreads();
    for (int off = 128; off; off >>= 1) {
        if (tid < off) qred[tid] += qred[tid + off];
        __syncthreads();
    }
    if (tid == 0) atomicAdd(qtloss, qred[0]);

    for (int s = tid; s < SCHUNK; s += 256)
        cpart[((size_t)(b * 16 + ttile)) * SS + sBeg + s] = csLDS[s];
}

// ---------------- K5: fused rank + in-LDS bitonic sort (8 blocks x 1024) ----------------
__global__ __launch_bounds__(1024) void k_ranksort(
    const float* __restrict__ cpart, const float* __restrict__ mrank,
    float* __restrict__ csum, unsigned long long* __restrict__ keys)
{
    __shared__ unsigned long long a[MM];   // 64KB
    __shared__ float red[1024];            // 4KB
    const int b = blockIdx.x, tid = threadIdx.x;

    // ---- rank phase ----
    float p = 0.f;
    for (int s = tid; s < SS; s += 1024) {
        float cs = 0.f;
#pragma unroll
        for (int tt = 0; tt < 16; ++tt) cs += cpart[((size_t)(b * 16 + tt)) * SS + s];
        csum[b * SS + s] = cs;
        p += cs;
    }
    red[tid] = p;
    __syncthreads();
    for (int off = 512; off; off >>= 1) {
        if (tid < off) red[tid] += red[tid + off];
        __syncthreads();
    }
    float mean = red[0] / (float)SS;
    for (int m = tid; m < MM; m += 1024) {
        float rank = ((mrank[b * MM + m] + csum[b * SS + m] / mean) - 1.0f) - 0.01f;
        a[m] = ((unsigned long long)(unsigned)(~f2ord(rank)) << 32) | (unsigned)m;
    }
    __syncthreads();

    // ---- bitonic sort phase (asc by key == desc by rank, idx tiebreak) ----
    for (int k = 2; k <= MM; k <<= 1) {
        for (int j = k >> 1; j > 0; j >>= 1) {
            for (int i = tid; i < MM; i += 1024) {
                int l = i ^ j;
                if (l > i) {
                    unsigned long long x = a[i], y = a[l];
                    bool up = ((i & k) == 0);
                    if ((x > y) == up) { a[i] = y; a[l] = x; }
                }
            }
            __syncthreads();
        }
    }
    for (int i = tid; i < MM; i += 1024) keys[(size_t)b * MM + i] = a[i];
}

// ---------------- K6: scatter sorted memory / dist / rank (prefetched) ----------------
__global__ __launch_bounds__(256) void k_scatter(
    const float* __restrict__ memory, const int* __restrict__ mbd,
    const int* __restrict__ bpl, const float* __restrict__ inp,
    const unsigned long long* __restrict__ keys,
    float* __restrict__ nmem, float* __restrict__ ndist, float* __restrict__ nrank)
{
    const int blk = blockIdx.x;
    const int b = blk >> 10;
    const int p0 = (blk & 1023) * 8;
    const bool reset = (bpl[b] == 0);
    const int tid = threadIdx.x;
    const f32x4 zero = (f32x4){0.f, 0.f, 0.f, 0.f};

    f32x4 vr[8];
    float dist[8], rankv[8];
#pragma unroll
    for (int r = 0; r < 8; ++r) {
        int p = p0 + r;
        if (p < RKEEP) {
            unsigned long long key = keys[(size_t)b * MM + p];
            int src = (int)(unsigned)(key & 0xFFFFFFFFu);
            vr[r] = reset ? zero
                          : *(const f32x4*)&memory[((size_t)b * MM + src) * EE + tid * 4];
            dist[r]  = reset ? 1.0f : (float)(mbd[b * MM + src] + 1);
            rankv[r] = ord2f(~(unsigned)(key >> 32));
        } else {
            int irow = p - RKEEP;
            vr[r] = *(const f32x4*)&inp[((size_t)b * TT + irow) * EE + tid * 4];
            dist[r] = 0.f; rankv[r] = 1.0f;
        }
    }
#pragma unroll
    for (int r = 0; r < 8; ++r) {
        int p = p0 + r;
        *(f32x4*)&nmem[((size_t)b * MM + p) * EE + tid * 4] = vr[r];
        if (tid == 0) { ndist[b * MM + p] = dist[r]; nrank[b * MM + p] = rankv[r]; }
    }
}

// ---------------- launcher ----------------
extern "C" void kernel_launch(void* const* d_in, const int* in_sizes, int n_in,
                              void* d_out, int out_size, void* d_ws, size_t ws_size,
                              hipStream_t stream)
{
    const int*   bpl    = (const int*)d_in[0];
    const float* inp    = (const float*)d_in[1];
    const float* memory = (const float*)d_in[2];
    const int*   mbd    = (const int*)d_in[3];
    const float* mrank  = (const float*)d_in[4];
    const float* pos    = (const float*)d_in[5];
    const float* Wk     = (const float*)d_in[6];
    const float* Wq     = (const float*)d_in[7];
    const float* Wv     = (const float*)d_in[8];

    float* out   = (float*)d_out;                    // [B,T,H]
    float* qtl   = out + (size_t)BB * TT * HH;       // scalar
    float* nmem  = qtl + 1;                          // [B,M,E]
    float* ndist = nmem + (size_t)BB * MM * EE;      // [B,M]
    float* nrank = ndist + (size_t)BB * MM;          // [B,M]

    char* w = (char*)d_ws;
    short* qb = (short*)w; w += (size_t)BB * TT * HH * 2;
    short* kb = (short*)w; w += (size_t)BB * SS * HH * 2;
    short* vT = (short*)w; w += (size_t)BB * HH * SS * 2;
    float* rmax = (float*)w; w += (size_t)BB * TT * 4;
    float* csum = (float*)w; w += (size_t)BB * SS * 4;
    float* cpart = (float*)w; w += (size_t)BB * 16 * SS * 4;
    unsigned long long* keys = (unsigned long long*)w; w += (size_t)BB * MM * 8;
    short* wk = (short*)w; w += (size_t)HH * EE * 2;
    short* wq = (short*)w; w += (size_t)HH * EE * 2;
    short* wv = (short*)w; w += (size_t)HH * EE * 2;
    if ((size_t)(w - (char*)d_ws) > ws_size) return;

    k_init   <<<512, 256, 0, stream>>>(Wk, Wq, Wv, wk, wq, wv, out, rmax);
    k_proj   <<<dim3(NKVBLK + TT / 64, BB), 256, 0, stream>>>(memory, mbd, bpl, pos, inp,
                                                              wk, wv, wq, kb, vT, qb);
    k_rowmax <<<NSPLIT * (TT / 64) * BB, 256, 0, stream>>>(qb, kb, rmax);
    k_attn   <<<NSPLIT * (TT / 64) * BB, 256, 0, stream>>>(qb, kb, vT,
                                                           rmax, out, cpart, qtl);
    k_ranksort<<<BB, 1024, 0, stream>>>(cpart, mrank, csum, keys);
    k_scatter<<<BB * (MM / 8), 256, 0, stream>>>(memory, mbd, bpl, inp, keys, nmem, ndist, nrank);
}

// Round 19
// 507.806 us; speedup vs baseline: 1.1989x; 1.0301x over previous
//
#include <hip/hip_runtime.h>
#include <hip/hip_bf16.h>
#include <stdint.h>

#define BB 8
#define TT 1024
#define MM 8192
#define EE 1024
#define HH 128
#define SS (MM + TT)          // 9216
#define RKEEP (MM - 1024)     // 7168 rows kept after eviction
#define NSPLIT 8
#define SCHUNK (SS / NSPLIT)  // 1152
#define NT (SCHUNK / 64)      // 18
#define BK 32
#define NKVBLK (SS / 64)      // 144

typedef __attribute__((ext_vector_type(8))) short bf16x8;
typedef __attribute__((ext_vector_type(4))) short s16x4;
typedef __attribute__((ext_vector_type(4))) float f32x4;

#define SBAR()   __builtin_amdgcn_s_barrier()
#define SCB()    __builtin_amdgcn_sched_barrier(0)

static __device__ __forceinline__ unsigned f2ord(float f) {
    unsigned u = __float_as_uint(f);
    return u ^ ((u & 0x80000000u) ? 0xFFFFFFFFu : 0x80000000u);
}
static __device__ __forceinline__ float ord2f(unsigned o) {
    unsigned u = (o & 0x80000000u) ? (o ^ 0x80000000u) : ~o;
    return __uint_as_float(u);
}
static __device__ __forceinline__ unsigned short f2bf(float x) {
    unsigned u = __float_as_uint(x);
    unsigned r = u + 0x7FFFu + ((u >> 16) & 1u);   // RNE
    return (unsigned short)(r >> 16);
}

// async global->LDS, 16B per lane; dest = wave-uniform base + lane*16
static __device__ __forceinline__ void gload_lds16(const short* g, short* l) {
    __builtin_amdgcn_global_load_lds(
        (const __attribute__((address_space(1))) void*)g,
        (__attribute__((address_space(3))) void*)l, 16, 0, 0);
}

__device__ const float SCALEF = (float)(1.0 / 96.0);  // (M+T)^-0.5

// ---------------- K0: weights->bf16 planes + zero out/qtl/rmax (fused init) ----------------
__global__ __launch_bounds__(256) void k_init(
    const float* __restrict__ Wk, const float* __restrict__ Wq, const float* __restrict__ Wv,
    short* __restrict__ wk, short* __restrict__ wq, short* __restrict__ wv,
    float* __restrict__ outZ, float* __restrict__ rmax)
{
    const int blk = blockIdx.x, tid = threadIdx.x;
    if (blk < 384) {
        int idx = blk * 256 + tid;
        int m = idx >> 15;
        int o4 = (idx & 32767) * 4;
        const float* W = m == 0 ? Wk : (m == 1 ? Wq : Wv);
        short* D = m == 0 ? wk : (m == 1 ? wq : wv);
        f32x4 v = *(const f32x4*)&W[o4];
        s16x4 h;
#pragma unroll
        for (int j = 0; j < 4; ++j) h[j] = (short)f2bf(v[j]);
        *(s16x4*)&D[o4] = h;
    } else {
        const int z = (blk - 384) * 256 + tid;       // 128 blocks
        const f32x4 zero = (f32x4){0.f, 0.f, 0.f, 0.f};
        for (int i = z; i < (BB * TT * HH) / 4; i += 128 * 256)
            ((f32x4*)outZ)[i] = zero;
        if (z == 0) outZ[BB * TT * HH] = 0.f;        // qt_loss scalar
        if (z < (BB * TT) / 4) ((f32x4*)rmax)[z] = zero;
    }
}

// ---------------- K1: fused K,V + Q projection (single dispatch, smA dbuf, 1 barrier/step) ----
__global__ __launch_bounds__(256, 3) void k_proj(
    const float* __restrict__ memory, const int* __restrict__ mbd,
    const int* __restrict__ bpl, const float* __restrict__ pos_table,
    const float* __restrict__ inp,
    const short* __restrict__ wk, const short* __restrict__ wv,
    const short* __restrict__ wq,
    short* __restrict__ kb, short* __restrict__ vT, short* __restrict__ qb)
{
    __shared__ __align__(16) short smA[2][64 * 64];        // 16KB (A panel dbuf)
    __shared__ __align__(16) short smB[2][2][128 * 32];    // 32KB

    const int tid = threadIdx.x;
    const int b   = blockIdx.y;
    const int lane = tid & 63, wid = tid >> 6;
    const int wc = wid;
    const int fr = lane & 15, fq = lane >> 4;
    const int arow = tid >> 2;
    const int aq   = tid & 3;
    const int wh   = (tid >> 2);
    const int wk8  = (tid & 3) * 8;
    const int wdst = wid * 512;

    if (blockIdx.x < NKVBLK) {
        // ================= KV path =================
        const int s0 = blockIdx.x * 64;
        const bool reset = (bpl[b] == 0);
        int pix;
        const float* abase;
        {
            int s = s0 + arow;
            if (s < MM) {
                int d = reset ? 1 : (mbd[b * MM + s] + 1);
                pix = 31 - __clz(d);
                abase = reset ? nullptr : &memory[((size_t)b * MM + s) * EE];
            } else {
                pix = -1;
                abase = &inp[((size_t)b * TT + (s - MM)) * EE];
            }
        }

        f32x4 accK[4][2], accV[4][2];
#pragma unroll
        for (int m = 0; m < 4; ++m)
#pragma unroll
            for (int n = 0; n < 2; ++n) {
                accK[m][n] = (f32x4){0.f, 0.f, 0.f, 0.f};
                accV[m][n] = (f32x4){0.f, 0.f, 0.f, 0.f};
            }

        auto STAGEW = [&](int e0, int buf) {
#pragma unroll
            for (int p = 0; p < 2; ++p) {
                int h = p * 64 + wh;
                int ec = wk8 ^ ((h & 3) << 3);
                size_t g = (size_t)h * EE + e0 + ec;
                gload_lds16(&wk[g], &smB[buf][0][p * 2048 + wdst]);
                gload_lds16(&wv[g], &smB[buf][1][p * 2048 + wdst]);
            }
        };
        auto LOADP = [&](int p, f32x4 xa[4]) {
            int e0 = p * 64 + aq * 16;
#pragma unroll
            for (int j = 0; j < 4; ++j) {
                f32x4 v = (f32x4){0.f, 0.f, 0.f, 0.f};
                if (abase) v = *(const f32x4*)&abase[e0 + j * 4];
                if (pix >= 0) {
                    f32x4 pt = *(const f32x4*)&pos_table[(size_t)pix * EE + e0 + j * 4];
                    v[0] += pt[0]; v[1] += pt[1]; v[2] += pt[2]; v[3] += pt[3];
                }
                xa[j] = v;
            }
        };
        auto STOREP = [&](const f32x4 xa[4], int abuf) {
#pragma unroll
            for (int j = 0; j < 2; ++j) {
                bf16x8 h;
#pragma unroll
                for (int c = 0; c < 4; ++c) {
                    h[c]     = (short)f2bf(xa[2 * j][c]);
                    h[4 + c] = (short)f2bf(xa[2 * j + 1][c]);
                }
                int g = (aq * 2 + j) ^ (arow & 7);
                *(bf16x8*)&smA[abuf][arow * 64 + g * 8] = h;
            }
        };

        f32x4 xa[4];
        LOADP(0, xa);
        STOREP(xa, 0);
        STAGEW(0, 0);
        __syncthreads();
        LOADP(1, xa);

        for (int step = 0; step < 32; ++step) {
            const int wbuf = step & 1;
            const int sseg = step & 1;
            const int pbuf = (step >> 1) & 1;
            if (step < 31) STAGEW((step + 1) * BK, wbuf ^ 1);

            bf16x8 ah[4];
#pragma unroll
            for (int m = 0; m < 4; ++m) {
                int r = m * 16 + fr;
                int g = (sseg * 4 + fq) ^ (r & 7);
                ah[m] = *(const bf16x8*)&smA[pbuf][r * 64 + g * 8];
            }
#pragma unroll
            for (int n = 0; n < 2; ++n) {
                int c = wc * 32 + n * 16 + fr;
                int off = c * 32 + ((fq * 8) ^ ((c & 3) << 3));
                bf16x8 kh = *(const bf16x8*)&smB[wbuf][0][off];
                bf16x8 vh = *(const bf16x8*)&smB[wbuf][1][off];
#pragma unroll
                for (int m = 0; m < 4; ++m) {
                    accK[m][n] = __builtin_amdgcn_mfma_f32_16x16x32_bf16(ah[m], kh, accK[m][n], 0, 0, 0);
                    accV[m][n] = __builtin_amdgcn_mfma_f32_16x16x32_bf16(ah[m], vh, accV[m][n], 0, 0, 0);
                }
            }
            if (sseg == 1 && step < 31) STOREP(xa, pbuf ^ 1);   // writes OTHER buffer, pre-barrier
            __syncthreads();                                     // single barrier per step
            if (sseg == 1 && step < 29) LOADP((step >> 1) + 2, xa);
        }

        // K epilogue
#pragma unroll
        for (int m = 0; m < 4; ++m) {
            int row = s0 + m * 16 + fq * 4;
#pragma unroll
            for (int n = 0; n < 2; ++n) {
                int col = wc * 32 + n * 16 + fr;
#pragma unroll
                for (int i = 0; i < 4; ++i)
                    kb[((size_t)b * SS + row + i) * HH + col] = (short)f2bf(accK[m][n][i]);
            }
        }
        // V epilogue: transpose via LDS (aliasing smB)
        float* tpT = (float*)smB;
#pragma unroll
        for (int hp = 0; hp < 4; ++hp) {
            __syncthreads();
            if (wc == hp) {
#pragma unroll
                for (int m = 0; m < 4; ++m)
#pragma unroll
                    for (int n = 0; n < 2; ++n) {
                        int cl = n * 16 + fr;
                        int row = m * 16 + fq * 4;
                        *(f32x4*)&tpT[cl * 68 + row] = accV[m][n];
                    }
            }
            __syncthreads();
            for (int idx = tid; idx < 32 * 16; idx += 256) {
                int hcl = idx >> 4, s4 = (idx & 15) << 2;
                f32x4 v = *(const f32x4*)&tpT[hcl * 68 + s4];
                s16x4 hi;
#pragma unroll
                for (int j = 0; j < 4; ++j) hi[j] = (short)f2bf(v[j]);
                size_t o = ((size_t)b * HH + hp * 32 + hcl) * SS + s0 + s4;
                *(s16x4*)&vT[o] = hi;
            }
        }
    } else {
        // ================= Q path =================
        const int t0 = (blockIdx.x - NKVBLK) * 64;
        const float* abase = &inp[((size_t)b * TT + t0 + arow) * EE];

        f32x4 acc[4][2];
#pragma unroll
        for (int m = 0; m < 4; ++m)
#pragma unroll
            for (int n = 0; n < 2; ++n) acc[m][n] = (f32x4){0.f, 0.f, 0.f, 0.f};

        auto STAGEWQ = [&](int e0, int buf) {
#pragma unroll
            for (int p = 0; p < 2; ++p) {
                int h = p * 64 + wh;
                int ec = wk8 ^ ((h & 3) << 3);
                size_t g = (size_t)h * EE + e0 + ec;
                gload_lds16(&wq[g], &smB[buf][0][p * 2048 + wdst]);
            }
        };
        auto LOADPQ = [&](int p, f32x4 xa[4]) {
            int e0 = p * 64 + aq * 16;
#pragma unroll
            for (int j = 0; j < 4; ++j) xa[j] = *(const f32x4*)&abase[e0 + j * 4];
        };
        auto STOREPQ = [&](const f32x4 xa[4], int abuf) {
#pragma unroll
            for (int j = 0; j < 2; ++j) {
                bf16x8 h;
#pragma unroll
                for (int c = 0; c < 4; ++c) {
                    h[c]     = (short)f2bf(xa[2 * j][c]);
                    h[4 + c] = (short)f2bf(xa[2 * j + 1][c]);
                }
                int g = (aq * 2 + j) ^ (arow & 7);
                *(bf16x8*)&smA[abuf][arow * 64 + g * 8] = h;
            }
        };

        f32x4 xa[4];
        LOADPQ(0, xa);
        STOREPQ(xa, 0);
        STAGEWQ(0, 0);
        __syncthreads();
        LOADPQ(1, xa);

        for (int step = 0; step < 32; ++step) {
            const int wbuf = step & 1;
            const int sseg = step & 1;
            const int pbuf = (step >> 1) & 1;
            if (step < 31) STAGEWQ((step + 1) * BK, wbuf ^ 1);

            bf16x8 ah[4];
#pragma unroll
            for (int m = 0; m < 4; ++m) {
                int r = m * 16 + fr;
                int g = (sseg * 4 + fq) ^ (r & 7);
                ah[m] = *(const bf16x8*)&smA[pbuf][r * 64 + g * 8];
            }
#pragma unroll
            for (int n = 0; n < 2; ++n) {
                int c = wc * 32 + n * 16 + fr;
                int off = c * 32 + ((fq * 8) ^ ((c & 3) << 3));
                bf16x8 bh = *(const bf16x8*)&smB[wbuf][0][off];
#pragma unroll
                for (int m = 0; m < 4; ++m)
                    acc[m][n] = __builtin_amdgcn_mfma_f32_16x16x32_bf16(ah[m], bh, acc[m][n], 0, 0, 0);
            }
            if (sseg == 1 && step < 31) STOREPQ(xa, pbuf ^ 1);
            __syncthreads();
            if (sseg == 1 && step < 29) LOADPQ((step >> 1) + 2, xa);
        }
#pragma unroll
        for (int m = 0; m < 4; ++m) {
            int row = t0 + m * 16 + fq * 4;
#pragma unroll
            for (int n = 0; n < 2; ++n) {
                int col = wc * 32 + n * 16 + fr;
#pragma unroll
                for (int i = 0; i < 4; ++i)
                    qb[((size_t)b * TT + row + i) * HH + col] = (short)f2bf(acc[m][n][i]);
            }
        }
    }
}

// ---------------- shared attn helpers ----------------
__device__ __forceinline__ void stage_k64_async(const short* __restrict__ src,
                                                size_t rowBase, int tid, short* sh)
{
#pragma unroll
    for (int c2 = 0; c2 < 4; ++c2) {
        int srow = c2 * 16 + (tid >> 4);
        int scol = ((tid & 15) * 8) ^ ((srow & 7) << 3);
        size_t g = (rowBase + srow) * HH + scol;
        gload_lds16(&src[g], &sh[c2 * 2048 + (tid >> 6) * 512]);
    }
}

__device__ __forceinline__ void stage_v64_async(const short* __restrict__ vT,
                                                int b, int st, int tid, short* vs)
{
#pragma unroll
    for (int c2 = 0; c2 < 4; ++c2) {
        int h = c2 * 32 + (tid >> 3);
        int sc = ((tid & 7) * 8) ^ ((h & 7) << 3);
        size_t g = ((size_t)b * HH + h) * SS + st + sc;
        gload_lds16(&vT[g], &vs[c2 * 2048 + (tid >> 6) * 512]);
    }
}

__device__ __forceinline__ void load_qfrags(const short* __restrict__ qb,
                                            size_t rowIx, int fq, bf16x8 qh[4])
{
    size_t base = rowIx * HH + fq * 8;
#pragma unroll
    for (int k = 0; k < 4; ++k)
        qh[k] = *(const bf16x8*)&qb[base + k * 32];
}

__device__ __forceinline__ void qk_mfma4(const bf16x8 qh[4], const short* sh,
                                         int fr, int fq, f32x4 acc[4])
{
#pragma unroll
    for (int n = 0; n < 4; ++n) {
        int sc = n * 16 + fr;
        int ro = sc * 128, msk = (sc & 7) << 3;
#pragma unroll
        for (int k = 0; k < 4; ++k) {
            int off = ro + ((k * 32 + fq * 8) ^ msk);
            bf16x8 bh = *(const bf16x8*)&sh[off];
            acc[n] = __builtin_amdgcn_mfma_f32_16x16x32_bf16(qh[k], bh, acc[n], 0, 0, 0);
        }
    }
}

// XCD-aware remap: flat f -> (b, split, ttile) with all 16 ttile-members of a
// (b,split) group sharing f%8 (same XCD under round-robin dispatch).
__device__ __forceinline__ void xcd_remap(int f, int& b, int& split, int& ttile)
{
    int xcd = f & 7, slot = f >> 3;
    int g = (slot >> 4) * 8 + xcd;    // group id in [0,64)
    ttile = slot & 15;
    b = g >> 3;
    split = g & 7;
}

// ---------------- K3: rowmax of (qk*scale)^2 via MFMA (dbuf K, 32KB) ----------------
__global__ __launch_bounds__(256) void k_rowmax(
    const short* __restrict__ qb, const short* __restrict__ kb,
    float* __restrict__ rowmax)
{
    __shared__ short Ks[2][64 * 128];   // 32KB
    const int tid = threadIdx.x, lane = tid & 63, wloc = tid >> 6;
    const int fr = lane & 15, fq = lane >> 4;
    int b, split, ttile;
    xcd_remap(blockIdx.x, b, split, ttile);
    const int t0 = ttile * 64;

    bf16x8 qh[4];
    load_qfrags(qb, (size_t)b * TT + t0 + wloc * 16 + fr, fq, qh);

    float rm[4] = {0.f, 0.f, 0.f, 0.f};
    const int sBeg = split * SCHUNK;
    const size_t kbase = (size_t)b * SS;

    stage_k64_async(kb, kbase + sBeg, tid, Ks[0]);
    __syncthreads();
    for (int t = 0; t < NT; ++t) {
        const int bf = t & 1;
        if (t + 1 < NT)
            stage_k64_async(kb, kbase + sBeg + (t + 1) * 64, tid, Ks[bf ^ 1]);
        f32x4 acc[4];
#pragma unroll
        for (int n = 0; n < 4; ++n) acc[n] = (f32x4){0.f, 0.f, 0.f, 0.f};
        __builtin_amdgcn_s_setprio(1);
        qk_mfma4(qh, Ks[bf], fr, fq, acc);
        __builtin_amdgcn_s_setprio(0);
#pragma unroll
        for (int n = 0; n < 4; ++n)
#pragma unroll
            for (int i = 0; i < 4; ++i) {
                float w = acc[n][i] * SCALEF;
                rm[i] = fmaxf(rm[i], w * w);
            }
        __syncthreads();   // next tile staged (covered by QK)
    }
#pragma unroll
    for (int d = 1; d < 16; d <<= 1)
#pragma unroll
        for (int i = 0; i < 4; ++i)
            rm[i] = fmaxf(rm[i], __shfl_xor(rm[i], d, 64));
    if (fr == 0)
#pragma unroll
        for (int i = 0; i < 4; ++i)
            atomicMax((int*)&rowmax[b * TT + t0 + wloc * 16 + fq * 4 + i], __float_as_int(rm[i]));
}

// ---------------- K4: attention — stage issued early, mid barrier lgkm-only ----------------
__global__ __launch_bounds__(256) void k_attn(
    const short* __restrict__ qb, const short* __restrict__ kb,
    const short* __restrict__ vT,
    const float* __restrict__ rowmax,
    float* __restrict__ outAcc, float* __restrict__ cpart, float* __restrict__ qtloss)
{
    __shared__ short Ks[2][64 * 128];   // 32KB
    __shared__ short Vs[2][128 * 64];   // 32KB
    __shared__ short Ph[64 * 64];       // 8KB
    __shared__ float csLDS[SCHUNK];     // 4.6KB
    __shared__ float qred[256];
    const int tid = threadIdx.x, lane = tid & 63, wloc = tid >> 6;
    const int fr = lane & 15, fq = lane >> 4;
    int b, split, ttile;
    xcd_remap(blockIdx.x, b, split, ttile);
    const int t0 = ttile * 64;

    for (int i = tid; i < SCHUNK; i += 256) csLDS[i] = 0.f;

    bf16x8 qh[4];
    load_qfrags(qb, (size_t)b * TT + t0 + wloc * 16 + fr, fq, qh);

    float inv[4];
#pragma unroll
    for (int i = 0; i < 4; ++i)
        inv[i] = 1.0f / rowmax[b * TT + t0 + wloc * 16 + fq * 4 + i];

    f32x4 oacc[8];
#pragma unroll
    for (int n = 0; n < 8; ++n) oacc[n] = (f32x4){0.f, 0.f, 0.f, 0.f};
    float qtp = 0.f;

    const int sBeg = split * SCHUNK;
    const size_t kbase = (size_t)b * SS;

    stage_k64_async(kb, kbase + sBeg, tid, Ks[0]);
    stage_v64_async(vT, b, sBeg, tid, Vs[0]);

    for (int t = 0; t < NT; ++t) {
        const int bf = t & 1;
        __syncthreads();   // stage(t) landed; Ph + victim buffers free

        if (t + 1 < NT) {  // issue next-tile staging NOW — covered by QK+softmax+PV
            stage_k64_async(kb, kbase + sBeg + (t + 1) * 64, tid, Ks[bf ^ 1]);
            stage_v64_async(vT, b, sBeg + (t + 1) * 64, tid, Vs[bf ^ 1]);
        }

        f32x4 acc[4];
#pragma unroll
        for (int n = 0; n < 4; ++n) acc[n] = (f32x4){0.f, 0.f, 0.f, 0.f};
        __builtin_amdgcn_s_setprio(1);
        qk_mfma4(qh, Ks[bf], fr, fq, acc);
        __builtin_amdgcn_s_setprio(0);

#pragma unroll
        for (int n = 0; n < 4; ++n) {
            float cp = 0.f;
#pragma unroll
            for (int i = 0; i < 4; ++i) {
                float w = acc[n][i] * SCALEF;
                float w2 = w * w;
                float wei = w2 * inv[i];
                qtp += __logf(wei + 1e-4f);
                cp += wei;
                int r = wloc * 16 + fq * 4 + i;
                int sw = (n * 16 + fr) ^ ((r & 7) << 3);
                Ph[r * 64 + sw] = (short)f2bf(wei);
            }
            cp += __shfl_xor(cp, 16, 64);
            cp += __shfl_xor(cp, 32, 64);
            if (fq == 0) atomicAdd(&csLDS[t * 64 + n * 16 + fr], cp);
        }
        asm volatile("s_waitcnt lgkmcnt(0)" ::: "memory");
        SBAR(); SCB();   // Ph visible; staged loads NOT drained
        // PV
        {
            int rA = wloc * 16 + fr;
            __builtin_amdgcn_s_setprio(1);
#pragma unroll
            for (int k = 0; k < 2; ++k) {
                int offA = rA * 64 + ((k * 32 + fq * 8) ^ ((rA & 7) << 3));
                bf16x8 ph = *(const bf16x8*)&Ph[offA];
#pragma unroll
                for (int n = 0; n < 8; ++n) {
                    int hc = n * 16 + fr;
                    int offB = hc * 64 + ((k * 32 + fq * 8) ^ ((hc & 7) << 3));
                    bf16x8 vh = *(const bf16x8*)&Vs[bf][offB];
                    oacc[n] = __builtin_amdgcn_mfma_f32_16x16x32_bf16(ph, vh, oacc[n], 0, 0, 0);
                }
            }
            __builtin_amdgcn_s_setprio(0);
        }
    }

#pragma unroll
    for (int n = 0; n < 8; ++n)
#pragma unroll
        for (int i = 0; i < 4; ++i)
            atomicAdd(&outAcc[((size_t)b * TT + t0 + wloc * 16 + fq * 4 + i) * HH + n * 16 + fr],
                      oacc[n][i]);

    qred[tid] = qtp;
    __syncthreads();
    for (int off = 128; off; off >>= 1) {
        if (tid < off) qred[tid] += qred[tid + off];
        __syncthreads();
    }
    if (tid == 0) atomicAdd(qtloss, qred[0]);

    for (int s = tid; s < SCHUNK; s += 256)
        cpart[((size_t)(b * 16 + ttile)) * SS + sBeg + s] = csLDS[s];
}

// ---------------- K5: fused rank + bitonic sort (blocks 0..7) + eviction-tail copy (blocks 8..1031) ----
__global__ __launch_bounds__(1024) void k_ranksort(
    const float* __restrict__ cpart, const float* __restrict__ mrank,
    float* __restrict__ csum, unsigned long long* __restrict__ keys,
    const float* __restrict__ inp, float* __restrict__ nmem,
    float* __restrict__ ndist, float* __restrict__ nrank)
{
    __shared__ unsigned long long a[MM];   // 64KB
    __shared__ float red[1024];            // 4KB
    const int blk = blockIdx.x, tid = threadIdx.x;

    if (blk >= BB) {
        // ---- tail copy: new_memory[RKEEP..MM) = inp tail; dist=0, rank=1 ----
        const int idx = blk - BB;            // 0..1023, 128 blocks per batch
        const int b = idx >> 7;
        const int r0 = RKEEP + (idx & 127) * 8;
#pragma unroll
        for (int rr = 0; rr < 2; ++rr) {
            int row = r0 + rr * 4 + (tid >> 8);     // 4 rows per pass
            int irow = row - RKEEP;
            int c4 = (tid & 255) * 4;
            *(f32x4*)&nmem[((size_t)b * MM + row) * EE + c4] =
                *(const f32x4*)&inp[((size_t)b * TT + irow) * EE + c4];
        }
        if (tid < 8) {
            int p = r0 + tid;
            ndist[b * MM + p] = 0.f;
            nrank[b * MM + p] = 1.0f;
        }
        return;
    }

    const int b = blk;
    // ---- rank phase ----
    float p = 0.f;
    for (int s = tid; s < SS; s += 1024) {
        float cs = 0.f;
#pragma unroll
        for (int tt = 0; tt < 16; ++tt) cs += cpart[((size_t)(b * 16 + tt)) * SS + s];
        csum[b * SS + s] = cs;
        p += cs;
    }
    red[tid] = p;
    __syncthreads();
    for (int off = 512; off; off >>= 1) {
        if (tid < off) red[tid] += red[tid + off];
        __syncthreads();
    }
    float mean = red[0] / (float)SS;
    for (int m = tid; m < MM; m += 1024) {
        float rank = ((mrank[b * MM + m] + csum[b * SS + m] / mean) - 1.0f) - 0.01f;
        a[m] = ((unsigned long long)(unsigned)(~f2ord(rank)) << 32) | (unsigned)m;
    }
    __syncthreads();

    // ---- bitonic sort phase (asc by key == desc by rank, idx tiebreak) ----
    for (int k = 2; k <= MM; k <<= 1) {
        for (int j = k >> 1; j > 0; j >>= 1) {
            for (int i = tid; i < MM; i += 1024) {
                int l = i ^ j;
                if (l > i) {
                    unsigned long long x = a[i], y = a[l];
                    bool up = ((i & k) == 0);
                    if ((x > y) == up) { a[i] = y; a[l] = x; }
                }
            }
            __syncthreads();
        }
    }
    for (int i = tid; i < MM; i += 1024) keys[(size_t)b * MM + i] = a[i];
}

// ---------------- K6: scatter kept rows only (p < RKEEP), prefetched ----------------
__global__ __launch_bounds__(256) void k_scatter(
    const float* __restrict__ memory, const int* __restrict__ mbd,
    const int* __restrict__ bpl, const unsigned long long* __restrict__ keys,
    float* __restrict__ nmem, float* __restrict__ ndist, float* __restrict__ nrank)
{
    const int blk = blockIdx.x;
    const int b = blk / (RKEEP / 8);           // 896 blocks per batch
    const int p0 = (blk % (RKEEP / 8)) * 8;
    const bool reset = (bpl[b] == 0);
    const int tid = threadIdx.x;
    const f32x4 zero = (f32x4){0.f, 0.f, 0.f, 0.f};

    f32x4 vr[8];
    float dist[8], rankv[8];
#pragma unroll
    for (int r = 0; r < 8; ++r) {
        int p = p0 + r;
        unsigned long long key = keys[(size_t)b * MM + p];
        int src = (int)(unsigned)(key & 0xFFFFFFFFu);
        vr[r] = reset ? zero
                      : *(const f32x4*)&memory[((size_t)b * MM + src) * EE + tid * 4];
        dist[r]  = reset ? 1.0f : (float)(mbd[b * MM + src] + 1);
        rankv[r] = ord2f(~(unsigned)(key >> 32));
    }
#pragma unroll
    for (int r = 0; r < 8; ++r) {
        int p = p0 + r;
        *(f32x4*)&nmem[((size_t)b * MM + p) * EE + tid * 4] = vr[r];
        if (tid == 0) { ndist[b * MM + p] = dist[r]; nrank[b * MM + p] = rankv[r]; }
    }
}

// ---------------- launcher ----------------
extern "C" void kernel_launch(void* const* d_in, const int* in_sizes, int n_in,
                              void* d_out, int out_size, void* d_ws, size_t ws_size,
                              hipStream_t stream)
{
    const int*   bpl    = (const int*)d_in[0];
    const float* inp    = (const float*)d_in[1];
    const float* memory = (const float*)d_in[2];
    const int*   mbd    = (const int*)d_in[3];
    const float* mrank  = (const float*)d_in[4];
    const float* pos    = (const float*)d_in[5];
    const float* Wk     = (const float*)d_in[6];
    const float* Wq     = (const float*)d_in[7];
    const float* Wv     = (const float*)d_in[8];

    float* out   = (float*)d_out;                    // [B,T,H]
    float* qtl   = out + (size_t)BB * TT * HH;       // scalar
    float* nmem  = qtl + 1;                          // [B,M,E]
    float* ndist = nmem + (size_t)BB * MM * EE;      // [B,M]
    float* nrank = ndist + (size_t)BB * MM;          // [B,M]

    char* w = (char*)d_ws;
    short* qb = (short*)w; w += (size_t)BB * TT * HH * 2;
    short* kb = (short*)w; w += (size_t)BB * SS * HH * 2;
    short* vT = (short*)w; w += (size_t)BB * HH * SS * 2;
    float* rmax = (float*)w; w += (size_t)BB * TT * 4;
    float* csum = (float*)w; w += (size_t)BB * SS * 4;
    float* cpart = (float*)w; w += (size_t)BB * 16 * SS * 4;
    unsigned long long* keys = (unsigned long long*)w; w += (size_t)BB * MM * 8;
    short* wk = (short*)w; w += (size_t)HH * EE * 2;
    short* wq = (short*)w; w += (size_t)HH * EE * 2;
    short* wv = (short*)w; w += (size_t)HH * EE * 2;
    if ((size_t)(w - (char*)d_ws) > ws_size) return;

    k_init   <<<512, 256, 0, stream>>>(Wk, Wq, Wv, wk, wq, wv, out, rmax);
    k_proj   <<<dim3(NKVBLK + TT / 64, BB), 256, 0, stream>>>(memory, mbd, bpl, pos, inp,
                                                              wk, wv, wq, kb, vT, qb);
    k_rowmax <<<NSPLIT * (TT / 64) * BB, 256, 0, stream>>>(qb, kb, rmax);
    k_attn   <<<NSPLIT * (TT / 64) * BB, 256, 0, stream>>>(qb, kb, vT,
                                                           rmax, out, cpart, qtl);
    k_ranksort<<<BB + BB * 128, 1024, 0, stream>>>(cpart, mrank, csum, keys,
                                                   inp, nmem, ndist, nrank);
    k_scatter<<<BB * (RKEEP / 8), 256, 0, stream>>>(memory, mbd, bpl, keys,
                                                    nmem, ndist, nrank);
}

// Round 20
// 502.811 us; speedup vs baseline: 1.2108x; 1.0099x over previous
//
#include <hip/hip_runtime.h>
#include <hip/hip_bf16.h>
#include <stdint.h>

#define BB 8
#define TT 1024
#define MM 8192
#define EE 1024
#define HH 128
#define SS (MM + TT)          // 9216
#define RKEEP (MM - 1024)     // 7168 rows kept after eviction
#define NSPLIT 4
#define SCHUNK (SS / NSPLIT)  // 2304
#define NT (SCHUNK / 64)      // 36
#define BK 32
#define NKVBLK (SS / 64)      // 144

typedef __attribute__((ext_vector_type(8))) short bf16x8;
typedef __attribute__((ext_vector_type(4))) short s16x4;
typedef __attribute__((ext_vector_type(4))) float f32x4;

#define SBAR()   __builtin_amdgcn_s_barrier()
#define SCB()    __builtin_amdgcn_sched_barrier(0)

static __device__ __forceinline__ unsigned f2ord(float f) {
    unsigned u = __float_as_uint(f);
    return u ^ ((u & 0x80000000u) ? 0xFFFFFFFFu : 0x80000000u);
}
static __device__ __forceinline__ float ord2f(unsigned o) {
    unsigned u = (o & 0x80000000u) ? (o ^ 0x80000000u) : ~o;
    return __uint_as_float(u);
}
static __device__ __forceinline__ unsigned short f2bf(float x) {
    unsigned u = __float_as_uint(x);
    unsigned r = u + 0x7FFFu + ((u >> 16) & 1u);   // RNE
    return (unsigned short)(r >> 16);
}

// async global->LDS, 16B per lane; dest = wave-uniform base + lane*16
static __device__ __forceinline__ void gload_lds16(const short* g, short* l) {
    __builtin_amdgcn_global_load_lds(
        (const __attribute__((address_space(1))) void*)g,
        (__attribute__((address_space(3))) void*)l, 16, 0, 0);
}

__device__ const float SCALEF = (float)(1.0 / 96.0);  // (M+T)^-0.5

// ---------------- K0: weights->bf16 planes + zero out/qtl/rmax (fused init) ----------------
__global__ __launch_bounds__(256) void k_init(
    const float* __restrict__ Wk, const float* __restrict__ Wq, const float* __restrict__ Wv,
    short* __restrict__ wk, short* __restrict__ wq, short* __restrict__ wv,
    float* __restrict__ outZ, float* __restrict__ rmax)
{
    const int blk = blockIdx.x, tid = threadIdx.x;
    if (blk < 384) {
        int idx = blk * 256 + tid;
        int m = idx >> 15;
        int o4 = (idx & 32767) * 4;
        const float* W = m == 0 ? Wk : (m == 1 ? Wq : Wv);
        short* D = m == 0 ? wk : (m == 1 ? wq : wv);
        f32x4 v = *(const f32x4*)&W[o4];
        s16x4 h;
#pragma unroll
        for (int j = 0; j < 4; ++j) h[j] = (short)f2bf(v[j]);
        *(s16x4*)&D[o4] = h;
    } else {
        const int z = (blk - 384) * 256 + tid;       // 128 blocks
        const f32x4 zero = (f32x4){0.f, 0.f, 0.f, 0.f};
        for (int i = z; i < (BB * TT * HH) / 4; i += 128 * 256)
            ((f32x4*)outZ)[i] = zero;
        if (z == 0) outZ[BB * TT * HH] = 0.f;        // qt_loss scalar
        if (z < (BB * TT) / 4) ((f32x4*)rmax)[z] = zero;
    }
}

// ---------------- K1: fused K,V + Q projection (single dispatch, smA dbuf, 1 barrier/step) ----
__global__ __launch_bounds__(256, 3) void k_proj(
    const float* __restrict__ memory, const int* __restrict__ mbd,
    const int* __restrict__ bpl, const float* __restrict__ pos_table,
    const float* __restrict__ inp,
    const short* __restrict__ wk, const short* __restrict__ wv,
    const short* __restrict__ wq,
    short* __restrict__ kb, short* __restrict__ vT, short* __restrict__ qb)
{
    __shared__ __align__(16) short smA[2][64 * 64];        // 16KB (A panel dbuf)
    __shared__ __align__(16) short smB[2][2][128 * 32];    // 32KB

    const int tid = threadIdx.x;
    const int b   = blockIdx.y;
    const int lane = tid & 63, wid = tid >> 6;
    const int wc = wid;
    const int fr = lane & 15, fq = lane >> 4;
    const int arow = tid >> 2;
    const int aq   = tid & 3;
    const int wh   = (tid >> 2);
    const int wk8  = (tid & 3) * 8;
    const int wdst = wid * 512;

    if (blockIdx.x < NKVBLK) {
        // ================= KV path =================
        const int s0 = blockIdx.x * 64;
        const bool reset = (bpl[b] == 0);
        int pix;
        const float* abase;
        {
            int s = s0 + arow;
            if (s < MM) {
                int d = reset ? 1 : (mbd[b * MM + s] + 1);
                pix = 31 - __clz(d);
                abase = reset ? nullptr : &memory[((size_t)b * MM + s) * EE];
            } else {
                pix = -1;
                abase = &inp[((size_t)b * TT + (s - MM)) * EE];
            }
        }

        f32x4 accK[4][2], accV[4][2];
#pragma unroll
        for (int m = 0; m < 4; ++m)
#pragma unroll
            for (int n = 0; n < 2; ++n) {
                accK[m][n] = (f32x4){0.f, 0.f, 0.f, 0.f};
                accV[m][n] = (f32x4){0.f, 0.f, 0.f, 0.f};
            }

        auto STAGEW = [&](int e0, int buf) {
#pragma unroll
            for (int p = 0; p < 2; ++p) {
                int h = p * 64 + wh;
                int ec = wk8 ^ ((h & 3) << 3);
                size_t g = (size_t)h * EE + e0 + ec;
                gload_lds16(&wk[g], &smB[buf][0][p * 2048 + wdst]);
                gload_lds16(&wv[g], &smB[buf][1][p * 2048 + wdst]);
            }
        };
        auto LOADP = [&](int p, f32x4 xa[4]) {
            int e0 = p * 64 + aq * 16;
#pragma unroll
            for (int j = 0; j < 4; ++j) {
                f32x4 v = (f32x4){0.f, 0.f, 0.f, 0.f};
                if (abase) v = *(const f32x4*)&abase[e0 + j * 4];
                if (pix >= 0) {
                    f32x4 pt = *(const f32x4*)&pos_table[(size_t)pix * EE + e0 + j * 4];
                    v[0] += pt[0]; v[1] += pt[1]; v[2] += pt[2]; v[3] += pt[3];
                }
                xa[j] = v;
            }
        };
        auto STOREP = [&](const f32x4 xa[4], int abuf) {
#pragma unroll
            for (int j = 0; j < 2; ++j) {
                bf16x8 h;
#pragma unroll
                for (int c = 0; c < 4; ++c) {
                    h[c]     = (short)f2bf(xa[2 * j][c]);
                    h[4 + c] = (short)f2bf(xa[2 * j + 1][c]);
                }
                int g = (aq * 2 + j) ^ (arow & 7);
                *(bf16x8*)&smA[abuf][arow * 64 + g * 8] = h;
            }
        };

        f32x4 xa[4];
        LOADP(0, xa);
        STOREP(xa, 0);
        STAGEW(0, 0);
        __syncthreads();
        LOADP(1, xa);

        for (int step = 0; step < 32; ++step) {
            const int wbuf = step & 1;
            const int sseg = step & 1;
            const int pbuf = (step >> 1) & 1;
            if (step < 31) STAGEW((step + 1) * BK, wbuf ^ 1);

            bf16x8 ah[4];
#pragma unroll
            for (int m = 0; m < 4; ++m) {
                int r = m * 16 + fr;
                int g = (sseg * 4 + fq) ^ (r & 7);
                ah[m] = *(const bf16x8*)&smA[pbuf][r * 64 + g * 8];
            }
#pragma unroll
            for (int n = 0; n < 2; ++n) {
                int c = wc * 32 + n * 16 + fr;
                int off = c * 32 + ((fq * 8) ^ ((c & 3) << 3));
                bf16x8 kh = *(const bf16x8*)&smB[wbuf][0][off];
                bf16x8 vh = *(const bf16x8*)&smB[wbuf][1][off];
#pragma unroll
                for (int m = 0; m < 4; ++m) {
                    accK[m][n] = __builtin_amdgcn_mfma_f32_16x16x32_bf16(ah[m], kh, accK[m][n], 0, 0, 0);
                    accV[m][n] = __builtin_amdgcn_mfma_f32_16x16x32_bf16(ah[m], vh, accV[m][n], 0, 0, 0);
                }
            }
            if (sseg == 1 && step < 31) STOREP(xa, pbuf ^ 1);   // writes OTHER buffer, pre-barrier
            __syncthreads();                                     // single barrier per step
            if (sseg == 1 && step < 29) LOADP((step >> 1) + 2, xa);
        }

        // K epilogue
#pragma unroll
        for (int m = 0; m < 4; ++m) {
            int row = s0 + m * 16 + fq * 4;
#pragma unroll
            for (int n = 0; n < 2; ++n) {
                int col = wc * 32 + n * 16 + fr;
#pragma unroll
                for (int i = 0; i < 4; ++i)
                    kb[((size_t)b * SS + row + i) * HH + col] = (short)f2bf(accK[m][n][i]);
            }
        }
        // V epilogue: transpose via LDS (aliasing smB)
        float* tpT = (float*)smB;
#pragma unroll
        for (int hp = 0; hp < 4; ++hp) {
            __syncthreads();
            if (wc == hp) {
#pragma unroll
                for (int m = 0; m < 4; ++m)
#pragma unroll
                    for (int n = 0; n < 2; ++n) {
                        int cl = n * 16 + fr;
                        int row = m * 16 + fq * 4;
                        *(f32x4*)&tpT[cl * 68 + row] = accV[m][n];
                    }
            }
            __syncthreads();
            for (int idx = tid; idx < 32 * 16; idx += 256) {
                int hcl = idx >> 4, s4 = (idx & 15) << 2;
                f32x4 v = *(const f32x4*)&tpT[hcl * 68 + s4];
                s16x4 hi;
#pragma unroll
                for (int j = 0; j < 4; ++j) hi[j] = (short)f2bf(v[j]);
                size_t o = ((size_t)b * HH + hp * 32 + hcl) * SS + s0 + s4;
                *(s16x4*)&vT[o] = hi;
            }
        }
    } else {
        // ================= Q path =================
        const int t0 = (blockIdx.x - NKVBLK) * 64;
        const float* abase = &inp[((size_t)b * TT + t0 + arow) * EE];

        f32x4 acc[4][2];
#pragma unroll
        for (int m = 0; m < 4; ++m)
#pragma unroll
            for (int n = 0; n < 2; ++n) acc[m][n] = (f32x4){0.f, 0.f, 0.f, 0.f};

        auto STAGEWQ = [&](int e0, int buf) {
#pragma unroll
            for (int p = 0; p < 2; ++p) {
                int h = p * 64 + wh;
                int ec = wk8 ^ ((h & 3) << 3);
                size_t g = (size_t)h * EE + e0 + ec;
                gload_lds16(&wq[g], &smB[buf][0][p * 2048 + wdst]);
            }
        };
        auto LOADPQ = [&](int p, f32x4 xa[4]) {
            int e0 = p * 64 + aq * 16;
#pragma unroll
            for (int j = 0; j < 4; ++j) xa[j] = *(const f32x4*)&abase[e0 + j * 4];
        };
        auto STOREPQ = [&](const f32x4 xa[4], int abuf) {
#pragma unroll
            for (int j = 0; j < 2; ++j) {
                bf16x8 h;
#pragma unroll
                for (int c = 0; c < 4; ++c) {
                    h[c]     = (short)f2bf(xa[2 * j][c]);
                    h[4 + c] = (short)f2bf(xa[2 * j + 1][c]);
                }
                int g = (aq * 2 + j) ^ (arow & 7);
                *(bf16x8*)&smA[abuf][arow * 64 + g * 8] = h;
            }
        };

        f32x4 xa[4];
        LOADPQ(0, xa);
        STOREPQ(xa, 0);
        STAGEWQ(0, 0);
        __syncthreads();
        LOADPQ(1, xa);

        for (int step = 0; step < 32; ++step) {
            const int wbuf = step & 1;
            const int sseg = step & 1;
            const int pbuf = (step >> 1) & 1;
            if (step < 31) STAGEWQ((step + 1) * BK, wbuf ^ 1);

            bf16x8 ah[4];
#pragma unroll
            for (int m = 0; m < 4; ++m) {
                int r = m * 16 + fr;
                int g = (sseg * 4 + fq) ^ (r & 7);
                ah[m] = *(const bf16x8*)&smA[pbuf][r * 64 + g * 8];
            }
#pragma unroll
            for (int n = 0; n < 2; ++n) {
                int c = wc * 32 + n * 16 + fr;
                int off = c * 32 + ((fq * 8) ^ ((c & 3) << 3));
                bf16x8 bh = *(const bf16x8*)&smB[wbuf][0][off];
#pragma unroll
                for (int m = 0; m < 4; ++m)
                    acc[m][n] = __builtin_amdgcn_mfma_f32_16x16x32_bf16(ah[m], bh, acc[m][n], 0, 0, 0);
            }
            if (sseg == 1 && step < 31) STOREPQ(xa, pbuf ^ 1);
            __syncthreads();
            if (sseg == 1 && step < 29) LOADPQ((step >> 1) + 2, xa);
        }
#pragma unroll
        for (int m = 0; m < 4; ++m) {
            int row = t0 + m * 16 + fq * 4;
#pragma unroll
            for (int n = 0; n < 2; ++n) {
                int col = wc * 32 + n * 16 + fr;
#pragma unroll
                for (int i = 0; i < 4; ++i)
                    qb[((size_t)b * TT + row + i) * HH + col] = (short)f2bf(acc[m][n][i]);
            }
        }
    }
}

// ---------------- shared attn helpers ----------------
__device__ __forceinline__ void stage_k64_async(const short* __restrict__ src,
                                                size_t rowBase, int tid, short* sh)
{
#pragma unroll
    for (int c2 = 0; c2 < 4; ++c2) {
        int srow = c2 * 16 + (tid >> 4);
        int scol = ((tid & 15) * 8) ^ ((srow & 7) << 3);
        size_t g = (rowBase + srow) * HH + scol;
        gload_lds16(&src[g], &sh[c2 * 2048 + (tid >> 6) * 512]);
    }
}

__device__ __forceinline__ void stage_v64_async(const short* __restrict__ vT,
                                                int b, int st, int tid, short* vs)
{
#pragma unroll
    for (int c2 = 0; c2 < 4; ++c2) {
        int h = c2 * 32 + (tid >> 3);
        int sc = ((tid & 7) * 8) ^ ((h & 7) << 3);
        size_t g = ((size_t)b * HH + h) * SS + st + sc;
        gload_lds16(&vT[g], &vs[c2 * 2048 + (tid >> 6) * 512]);
    }
}

__device__ __forceinline__ void load_qfrags(const short* __restrict__ qb,
                                            size_t rowIx, int fq, bf16x8 qh[4])
{
    size_t base = rowIx * HH + fq * 8;
#pragma unroll
    for (int k = 0; k < 4; ++k)
        qh[k] = *(const bf16x8*)&qb[base + k * 32];
}

__device__ __forceinline__ void qk_mfma4(const bf16x8 qh[4], const short* sh,
                                         int fr, int fq, f32x4 acc[4])
{
#pragma unroll
    for (int n = 0; n < 4; ++n) {
        int sc = n * 16 + fr;
        int ro = sc * 128, msk = (sc & 7) << 3;
#pragma unroll
        for (int k = 0; k < 4; ++k) {
            int off = ro + ((k * 32 + fq * 8) ^ msk);
            bf16x8 bh = *(const bf16x8*)&sh[off];
            acc[n] = __builtin_amdgcn_mfma_f32_16x16x32_bf16(qh[k], bh, acc[n], 0, 0, 0);
        }
    }
}

// XCD-aware remap: flat f in [0,512) -> (b, split, ttile); all 16 ttile-members of
// a (b,split) group share f%8 (same XCD under round-robin dispatch).
__device__ __forceinline__ void xcd_remap(int f, int& b, int& split, int& ttile)
{
    int xcd = f & 7, slot = f >> 3;
    int g = (slot >> 4) * 8 + xcd;    // group id in [0,32)
    ttile = slot & 15;
    b = g >> 2;
    split = g & 3;
}

// ---------------- K3: rowmax of (qk*scale)^2 via MFMA (dbuf K, 32KB) ----------------
__global__ __launch_bounds__(256) void k_rowmax(
    const short* __restrict__ qb, const short* __restrict__ kb,
    float* __restrict__ rowmax)
{
    __shared__ short Ks[2][64 * 128];   // 32KB
    const int tid = threadIdx.x, lane = tid & 63, wloc = tid >> 6;
    const int fr = lane & 15, fq = lane >> 4;
    int b, split, ttile;
    xcd_remap(blockIdx.x, b, split, ttile);
    const int t0 = ttile * 64;

    bf16x8 qh[4];
    load_qfrags(qb, (size_t)b * TT + t0 + wloc * 16 + fr, fq, qh);

    float rm[4] = {0.f, 0.f, 0.f, 0.f};
    const int sBeg = split * SCHUNK;
    const size_t kbase = (size_t)b * SS;

    stage_k64_async(kb, kbase + sBeg, tid, Ks[0]);
    __syncthreads();
    for (int t = 0; t < NT; ++t) {
        const int bf = t & 1;
        if (t + 1 < NT)
            stage_k64_async(kb, kbase + sBeg + (t + 1) * 64, tid, Ks[bf ^ 1]);
        f32x4 acc[4];
#pragma unroll
        for (int n = 0; n < 4; ++n) acc[n] = (f32x4){0.f, 0.f, 0.f, 0.f};
        __builtin_amdgcn_s_setprio(1);
        qk_mfma4(qh, Ks[bf], fr, fq, acc);
        __builtin_amdgcn_s_setprio(0);
#pragma unroll
        for (int n = 0; n < 4; ++n)
#pragma unroll
            for (int i = 0; i < 4; ++i) {
                float w = acc[n][i] * SCALEF;
                rm[i] = fmaxf(rm[i], w * w);
            }
        __syncthreads();   // next tile staged (covered by QK)
    }
#pragma unroll
    for (int d = 1; d < 16; d <<= 1)
#pragma unroll
        for (int i = 0; i < 4; ++i)
            rm[i] = fmaxf(rm[i], __shfl_xor(rm[i], d, 64));
    if (fr == 0)
#pragma unroll
        for (int i = 0; i < 4; ++i)
            atomicMax((int*)&rowmax[b * TT + t0 + wloc * 16 + fq * 4 + i], __float_as_int(rm[i]));
}

// ---------------- K4: attention — per-tile colsum, stage issued early ----------------
__global__ __launch_bounds__(256) void k_attn(
    const short* __restrict__ qb, const short* __restrict__ kb,
    const short* __restrict__ vT,
    const float* __restrict__ rowmax,
    float* __restrict__ outAcc, float* __restrict__ cpart, float* __restrict__ qtloss)
{
    __shared__ short Ks[2][64 * 128];   // 32KB
    __shared__ short Vs[2][128 * 64];   // 32KB
    __shared__ short Ph[64 * 64];       // 8KB
    __shared__ float csT[2][64];        // 512B (per-tile colsum, dbuf)
    __shared__ float qred[256];
    const int tid = threadIdx.x, lane = tid & 63, wloc = tid >> 6;
    const int fr = lane & 15, fq = lane >> 4;
    int b, split, ttile;
    xcd_remap(blockIdx.x, b, split, ttile);
    const int t0 = ttile * 64;

    if (tid < 128) ((float*)csT)[tid] = 0.f;

    bf16x8 qh[4];
    load_qfrags(qb, (size_t)b * TT + t0 + wloc * 16 + fr, fq, qh);

    float inv[4];
#pragma unroll
    for (int i = 0; i < 4; ++i)
        inv[i] = 1.0f / rowmax[b * TT + t0 + wloc * 16 + fq * 4 + i];

    f32x4 oacc[8];
#pragma unroll
    for (int n = 0; n < 8; ++n) oacc[n] = (f32x4){0.f, 0.f, 0.f, 0.f};
    float qtp = 0.f;

    const int sBeg = split * SCHUNK;
    const size_t kbase = (size_t)b * SS;
    float* cprow = &cpart[((size_t)(b * 16 + ttile)) * SS + sBeg];

    stage_k64_async(kb, kbase + sBeg, tid, Ks[0]);
    stage_v64_async(vT, b, sBeg, tid, Vs[0]);

    for (int t = 0; t < NT; ++t) {
        const int bf = t & 1;
        __syncthreads();   // stage(t) landed; Ph + victim buffers free

        if (t + 1 < NT) {  // issue next-tile staging NOW — covered by QK+softmax+PV
            stage_k64_async(kb, kbase + sBeg + (t + 1) * 64, tid, Ks[bf ^ 1]);
            stage_v64_async(vT, b, sBeg + (t + 1) * 64, tid, Vs[bf ^ 1]);
        }

        f32x4 acc[4];
#pragma unroll
        for (int n = 0; n < 4; ++n) acc[n] = (f32x4){0.f, 0.f, 0.f, 0.f};
        __builtin_amdgcn_s_setprio(1);
        qk_mfma4(qh, Ks[bf], fr, fq, acc);
        __builtin_amdgcn_s_setprio(0);

#pragma unroll
        for (int n = 0; n < 4; ++n) {
            float cp = 0.f;
#pragma unroll
            for (int i = 0; i < 4; ++i) {
                float w = acc[n][i] * SCALEF;
                float w2 = w * w;
                float wei = w2 * inv[i];
                qtp += __logf(wei + 1e-4f);
                cp += wei;
                int r = wloc * 16 + fq * 4 + i;
                int sw = (n * 16 + fr) ^ ((r & 7) << 3);
                Ph[r * 64 + sw] = (short)f2bf(wei);
            }
            cp += __shfl_xor(cp, 16, 64);
            cp += __shfl_xor(cp, 32, 64);
            if (fq == 0) atomicAdd(&csT[bf][n * 16 + fr], cp);
        }
        asm volatile("s_waitcnt lgkmcnt(0)" ::: "memory");
        SBAR(); SCB();   // Ph + csT[bf] visible; staged loads NOT drained
        // write per-tile colsum + reset buffer for tile t+2 (next use after 2 barriers)
        if (tid < 64) {
            cprow[t * 64 + tid] = csT[bf][tid];
            csT[bf][tid] = 0.f;
        }
        // PV
        {
            int rA = wloc * 16 + fr;
            __builtin_amdgcn_s_setprio(1);
#pragma unroll
            for (int k = 0; k < 2; ++k) {
                int offA = rA * 64 + ((k * 32 + fq * 8) ^ ((rA & 7) << 3));
                bf16x8 ph = *(const bf16x8*)&Ph[offA];
#pragma unroll
                for (int n = 0; n < 8; ++n) {
                    int hc = n * 16 + fr;
                    int offB = hc * 64 + ((k * 32 + fq * 8) ^ ((hc & 7) << 3));
                    bf16x8 vh = *(const bf16x8*)&Vs[bf][offB];
                    oacc[n] = __builtin_amdgcn_mfma_f32_16x16x32_bf16(ph, vh, oacc[n], 0, 0, 0);
                }
            }
            __builtin_amdgcn_s_setprio(0);
        }
    }

#pragma unroll
    for (int n = 0; n < 8; ++n)
#pragma unroll
        for (int i = 0; i < 4; ++i)
            atomicAdd(&outAcc[((size_t)b * TT + t0 + wloc * 16 + fq * 4 + i) * HH + n * 16 + fr],
                      oacc[n][i]);

    qred[tid] = qtp;
    __syncthreads();
    for (int off = 128; off; off >>= 1) {
        if (tid < off) qred[tid] += qred[tid + off];
        __syncthreads();
    }
    if (tid == 0) atomicAdd(qtloss, qred[0]);
}

// ---------------- K5: fused rank + bitonic sort (blocks 0..7) + eviction-tail copy (blocks 8..1031) ----
__global__ __launch_bounds__(1024) void k_ranksort(
    const float* __restrict__ cpart, const float* __restrict__ mrank,
    float* __restrict__ csum, unsigned long long* __restrict__ keys,
    const float* __restrict__ inp, float* __restrict__ nmem,
    float* __restrict__ ndist, float* __restrict__ nrank)
{
    __shared__ unsigned long long a[MM];   // 64KB
    __shared__ float red[1024];            // 4KB
    const int blk = blockIdx.x, tid = threadIdx.x;

    if (blk >= BB) {
        // ---- tail copy: new_memory[RKEEP..MM) = inp tail; dist=0, rank=1 ----
        const int idx = blk - BB;            // 0..1023, 128 blocks per batch
        const int b = idx >> 7;
        const int r0 = RKEEP + (idx & 127) * 8;
#pragma unroll
        for (int rr = 0; rr < 2; ++rr) {
            int row = r0 + rr * 4 + (tid >> 8);     // 4 rows per pass
            int irow = row - RKEEP;
            int c4 = (tid & 255) * 4;
            *(f32x4*)&nmem[((size_t)b * MM + row) * EE + c4] =
                *(const f32x4*)&inp[((size_t)b * TT + irow) * EE + c4];
        }
        if (tid < 8) {
            int p = r0 + tid;
            ndist[b * MM + p] = 0.f;
            nrank[b * MM + p] = 1.0f;
        }
        return;
    }

    const int b = blk;
    // ---- rank phase ----
    float p = 0.f;
    for (int s = tid; s < SS; s += 1024) {
        float cs = 0.f;
#pragma unroll
        for (int tt = 0; tt < 16; ++tt) cs += cpart[((size_t)(b * 16 + tt)) * SS + s];
        csum[b * SS + s] = cs;
        p += cs;
    }
    red[tid] = p;
    __syncthreads();
    for (int off = 512; off; off >>= 1) {
        if (tid < off) red[tid] += red[tid + off];
        __syncthreads();
    }
    float mean = red[0] / (float)SS;
    for (int m = tid; m < MM; m += 1024) {
        float rank = ((mrank[b * MM + m] + csum[b * SS + m] / mean) - 1.0f) - 0.01f;
        a[m] = ((unsigned long long)(unsigned)(~f2ord(rank)) << 32) | (unsigned)m;
    }
    __syncthreads();

    // ---- bitonic sort phase (asc by key == desc by rank, idx tiebreak) ----
    for (int k = 2; k <= MM; k <<= 1) {
        for (int j = k >> 1; j > 0; j >>= 1) {
            for (int i = tid; i < MM; i += 1024) {
                int l = i ^ j;
                if (l > i) {
                    unsigned long long x = a[i], y = a[l];
                    bool up = ((i & k) == 0);
                    if ((x > y) == up) { a[i] = y; a[l] = x; }
                }
            }
            __syncthreads();
        }
    }
    for (int i = tid; i < MM; i += 1024) keys[(size_t)b * MM + i] = a[i];
}

// ---------------- K6: scatter kept rows only (p < RKEEP), prefetched ----------------
__global__ __launch_bounds__(256) void k_scatter(
    const float* __restrict__ memory, const int* __restrict__ mbd,
    const int* __restrict__ bpl, const unsigned long long* __restrict__ keys,
    float* __restrict__ nmem, float* __restrict__ ndist, float* __restrict__ nrank)
{
    const int blk = blockIdx.x;
    const int b = blk / (RKEEP / 8);           // 896 blocks per batch
    const int p0 = (blk % (RKEEP / 8)) * 8;
    const bool reset = (bpl[b] == 0);
    const int tid = threadIdx.x;
    const f32x4 zero = (f32x4){0.f, 0.f, 0.f, 0.f};

    f32x4 vr[8];
    float dist[8], rankv[8];
#pragma unroll
    for (int r = 0; r < 8; ++r) {
        int p = p0 + r;
        unsigned long long key = keys[(size_t)b * MM + p];
        int src = (int)(unsigned)(key & 0xFFFFFFFFu);
        vr[r] = reset ? zero
                      : *(const f32x4*)&memory[((size_t)b * MM + src) * EE + tid * 4];
        dist[r]  = reset ? 1.0f : (float)(mbd[b * MM + src] + 1);
        rankv[r] = ord2f(~(unsigned)(key >> 32));
    }
#pragma unroll
    for (int r = 0; r < 8; ++r) {
        int p = p0 + r;
        *(f32x4*)&nmem[((size_t)b * MM + p) * EE + tid * 4] = vr[r];
        if (tid == 0) { ndist[b * MM + p] = dist[r]; nrank[b * MM + p] = rankv[r]; }
    }
}

// ---------------- launcher ----------------
extern "C" void kernel_launch(void* const* d_in, const int* in_sizes, int n_in,
                              void* d_out, int out_size, void* d_ws, size_t ws_size,
                              hipStream_t stream)
{
    const int*   bpl    = (const int*)d_in[0];
    const float* inp    = (const float*)d_in[1];
    const float* memory = (const float*)d_in[2];
    const int*   mbd    = (const int*)d_in[3];
    const float* mrank  = (const float*)d_in[4];
    const float* pos    = (const float*)d_in[5];
    const float* Wk     = (const float*)d_in[6];
    const float* Wq     = (const float*)d_in[7];
    const float* Wv     = (const float*)d_in[8];

    float* out   = (float*)d_out;                    // [B,T,H]
    float* qtl   = out + (size_t)BB * TT * HH;       // scalar
    float* nmem  = qtl + 1;                          // [B,M,E]
    float* ndist = nmem + (size_t)BB * MM * EE;      // [B,M]
    float* nrank = ndist + (size_t)BB * MM;          // [B,M]

    char* w = (char*)d_ws;
    short* qb = (short*)w; w += (size_t)BB * TT * HH * 2;
    short* kb = (short*)w; w += (size_t)BB * SS * HH * 2;
    short* vT = (short*)w; w += (size_t)BB * HH * SS * 2;
    float* rmax = (float*)w; w += (size_t)BB * TT * 4;
    float* csum = (float*)w; w += (size_t)BB * SS * 4;
    float* cpart = (float*)w; w += (size_t)BB * 16 * SS * 4;
    unsigned long long* keys = (unsigned long long*)w; w += (size_t)BB * MM * 8;
    short* wk = (short*)w; w += (size_t)HH * EE * 2;
    short* wq = (short*)w; w += (size_t)HH * EE * 2;
    short* wv = (short*)w; w += (size_t)HH * EE * 2;
    if ((size_t)(w - (char*)d_ws) > ws_size) return;

    k_init   <<<512, 256, 0, stream>>>(Wk, Wq, Wv, wk, wq, wv, out, rmax);
    k_proj   <<<dim3(NKVBLK + TT / 64, BB), 256, 0, stream>>>(memory, mbd, bpl, pos, inp,
                                                              wk, wv, wq, kb, vT, qb);
    k_rowmax <<<NSPLIT * (TT / 64) * BB, 256, 0, stream>>>(qb, kb, rmax);
    k_attn   <<<NSPLIT * (TT / 64) * BB, 256, 0, stream>>>(qb, kb, vT,
                                                           rmax, out, cpart, qtl);
    k_ranksort<<<BB + BB * 128, 1024, 0, stream>>>(cpart, mrank, csum, keys,
                                                   inp, nmem, ndist, nrank);
    k_scatter<<<BB * (RKEEP / 8), 256, 0, stream>>>(memory, mbd, bpl, keys,
                                                    nmem, ndist, nrank);
}

// Round 21
// 490.516 us; speedup vs baseline: 1.2411x; 1.0251x over previous
//
#include <hip/hip_runtime.h>
#include <hip/hip_bf16.h>
#include <stdint.h>

#define BB 8
#define TT 1024
#define MM 8192
#define EE 1024
#define HH 128
#define SS (MM + TT)          // 9216
#define RKEEP (MM - 1024)     // 7168 rows kept after eviction
#define NSPLIT 4
#define SCHUNK (SS / NSPLIT)  // 2304
#define NT (SCHUNK / 64)      // 36
#define BK 32
#define NKVBLK (SS / 64)      // 144

typedef __attribute__((ext_vector_type(8))) short bf16x8;
typedef __attribute__((ext_vector_type(4))) short s16x4;
typedef __attribute__((ext_vector_type(4))) float f32x4;

#define SBAR()   __builtin_amdgcn_s_barrier()
#define SCB()    __builtin_amdgcn_sched_barrier(0)

static __device__ __forceinline__ unsigned f2ord(float f) {
    unsigned u = __float_as_uint(f);
    return u ^ ((u & 0x80000000u) ? 0xFFFFFFFFu : 0x80000000u);
}
static __device__ __forceinline__ float ord2f(unsigned o) {
    unsigned u = (o & 0x80000000u) ? (o ^ 0x80000000u) : ~o;
    return __uint_as_float(u);
}
static __device__ __forceinline__ unsigned short f2bf(float x) {
    unsigned u = __float_as_uint(x);
    unsigned r = u + 0x7FFFu + ((u >> 16) & 1u);   // RNE
    return (unsigned short)(r >> 16);
}

// async global->LDS, 16B per lane; dest = wave-uniform base + lane*16
static __device__ __forceinline__ void gload_lds16(const short* g, short* l) {
    __builtin_amdgcn_global_load_lds(
        (const __attribute__((address_space(1))) void*)g,
        (__attribute__((address_space(3))) void*)l, 16, 0, 0);
}

__device__ const float SCALEF = (float)(1.0 / 96.0);  // (M+T)^-0.5

// ---------------- K0: weights->bf16 planes + zero out/qtl/rmax (fused init) ----------------
__global__ __launch_bounds__(256) void k_init(
    const float* __restrict__ Wk, const float* __restrict__ Wq, const float* __restrict__ Wv,
    short* __restrict__ wk, short* __restrict__ wq, short* __restrict__ wv,
    float* __restrict__ outZ, float* __restrict__ rmax)
{
    const int blk = blockIdx.x, tid = threadIdx.x;
    if (blk < 384) {
        int idx = blk * 256 + tid;
        int m = idx >> 15;
        int o4 = (idx & 32767) * 4;
        const float* W = m == 0 ? Wk : (m == 1 ? Wq : Wv);
        short* D = m == 0 ? wk : (m == 1 ? wq : wv);
        f32x4 v = *(const f32x4*)&W[o4];
        s16x4 h;
#pragma unroll
        for (int j = 0; j < 4; ++j) h[j] = (short)f2bf(v[j]);
        *(s16x4*)&D[o4] = h;
    } else {
        const int z = (blk - 384) * 256 + tid;       // 128 blocks
        const f32x4 zero = (f32x4){0.f, 0.f, 0.f, 0.f};
        for (int i = z; i < (BB * TT * HH) / 4; i += 128 * 256)
            ((f32x4*)outZ)[i] = zero;
        if (z == 0) outZ[BB * TT * HH] = 0.f;        // qt_loss scalar
        if (z < (BB * TT) / 4) ((f32x4*)rmax)[z] = zero;
    }
}

// ---------------- K1: fused K,V + Q projection (single dispatch, smA dbuf, 1 barrier/step) ----
__global__ __launch_bounds__(256, 3) void k_proj(
    const float* __restrict__ memory, const int* __restrict__ mbd,
    const int* __restrict__ bpl, const float* __restrict__ pos_table,
    const float* __restrict__ inp,
    const short* __restrict__ wk, const short* __restrict__ wv,
    const short* __restrict__ wq,
    short* __restrict__ kb, short* __restrict__ vT, short* __restrict__ qb)
{
    __shared__ __align__(16) short smA[2][64 * 64];        // 16KB (A panel dbuf)
    __shared__ __align__(16) short smB[2][2][128 * 32];    // 32KB

    const int tid = threadIdx.x;
    const int b   = blockIdx.y;
    const int lane = tid & 63, wid = tid >> 6;
    const int wc = wid;
    const int fr = lane & 15, fq = lane >> 4;
    const int arow = tid >> 2;
    const int aq   = tid & 3;
    const int wh   = (tid >> 2);
    const int wk8  = (tid & 3) * 8;
    const int wdst = wid * 512;

    if (blockIdx.x < NKVBLK) {
        // ================= KV path =================
        const int s0 = blockIdx.x * 64;
        const bool reset = (bpl[b] == 0);
        int pix;
        const float* abase;
        {
            int s = s0 + arow;
            if (s < MM) {
                int d = reset ? 1 : (mbd[b * MM + s] + 1);
                pix = 31 - __clz(d);
                abase = reset ? nullptr : &memory[((size_t)b * MM + s) * EE];
            } else {
                pix = -1;
                abase = &inp[((size_t)b * TT + (s - MM)) * EE];
            }
        }

        f32x4 accK[4][2], accV[4][2];
#pragma unroll
        for (int m = 0; m < 4; ++m)
#pragma unroll
            for (int n = 0; n < 2; ++n) {
                accK[m][n] = (f32x4){0.f, 0.f, 0.f, 0.f};
                accV[m][n] = (f32x4){0.f, 0.f, 0.f, 0.f};
            }

        auto STAGEW = [&](int e0, int buf) {
#pragma unroll
            for (int p = 0; p < 2; ++p) {
                int h = p * 64 + wh;
                int ec = wk8 ^ ((h & 3) << 3);
                size_t g = (size_t)h * EE + e0 + ec;
                gload_lds16(&wk[g], &smB[buf][0][p * 2048 + wdst]);
                gload_lds16(&wv[g], &smB[buf][1][p * 2048 + wdst]);
            }
        };
        auto LOADP = [&](int p, f32x4 xa[4]) {
            int e0 = p * 64 + aq * 16;
#pragma unroll
            for (int j = 0; j < 4; ++j) {
                f32x4 v = (f32x4){0.f, 0.f, 0.f, 0.f};
                if (abase) v = *(const f32x4*)&abase[e0 + j * 4];
                if (pix >= 0) {
                    f32x4 pt = *(const f32x4*)&pos_table[(size_t)pix * EE + e0 + j * 4];
                    v[0] += pt[0]; v[1] += pt[1]; v[2] += pt[2]; v[3] += pt[3];
                }
                xa[j] = v;
            }
        };
        auto STOREP = [&](const f32x4 xa[4], int abuf) {
#pragma unroll
            for (int j = 0; j < 2; ++j) {
                bf16x8 h;
#pragma unroll
                for (int c = 0; c < 4; ++c) {
                    h[c]     = (short)f2bf(xa[2 * j][c]);
                    h[4 + c] = (short)f2bf(xa[2 * j + 1][c]);
                }
                int g = (aq * 2 + j) ^ (arow & 7);
                *(bf16x8*)&smA[abuf][arow * 64 + g * 8] = h;
            }
        };

        f32x4 xa[4];
        LOADP(0, xa);
        STOREP(xa, 0);
        STAGEW(0, 0);
        __syncthreads();
        LOADP(1, xa);

        for (int step = 0; step < 32; ++step) {
            const int wbuf = step & 1;
            const int sseg = step & 1;
            const int pbuf = (step >> 1) & 1;
            if (step < 31) STAGEW((step + 1) * BK, wbuf ^ 1);

            bf16x8 ah[4];
#pragma unroll
            for (int m = 0; m < 4; ++m) {
                int r = m * 16 + fr;
                int g = (sseg * 4 + fq) ^ (r & 7);
                ah[m] = *(const bf16x8*)&smA[pbuf][r * 64 + g * 8];
            }
#pragma unroll
            for (int n = 0; n < 2; ++n) {
                int c = wc * 32 + n * 16 + fr;
                int off = c * 32 + ((fq * 8) ^ ((c & 3) << 3));
                bf16x8 kh = *(const bf16x8*)&smB[wbuf][0][off];
                bf16x8 vh = *(const bf16x8*)&smB[wbuf][1][off];
#pragma unroll
                for (int m = 0; m < 4; ++m) {
                    accK[m][n] = __builtin_amdgcn_mfma_f32_16x16x32_bf16(ah[m], kh, accK[m][n], 0, 0, 0);
                    accV[m][n] = __builtin_amdgcn_mfma_f32_16x16x32_bf16(ah[m], vh, accV[m][n], 0, 0, 0);
                }
            }
            if (sseg == 1 && step < 31) STOREP(xa, pbuf ^ 1);   // writes OTHER buffer, pre-barrier
            __syncthreads();                                     // single barrier per step
            if (sseg == 1 && step < 29) LOADP((step >> 1) + 2, xa);
        }

        // K epilogue
#pragma unroll
        for (int m = 0; m < 4; ++m) {
            int row = s0 + m * 16 + fq * 4;
#pragma unroll
            for (int n = 0; n < 2; ++n) {
                int col = wc * 32 + n * 16 + fr;
#pragma unroll
                for (int i = 0; i < 4; ++i)
                    kb[((size_t)b * SS + row + i) * HH + col] = (short)f2bf(accK[m][n][i]);
            }
        }
        // V epilogue: transpose via LDS (aliasing smB)
        float* tpT = (float*)smB;
#pragma unroll
        for (int hp = 0; hp < 4; ++hp) {
            __syncthreads();
            if (wc == hp) {
#pragma unroll
                for (int m = 0; m < 4; ++m)
#pragma unroll
                    for (int n = 0; n < 2; ++n) {
                        int cl = n * 16 + fr;
                        int row = m * 16 + fq * 4;
                        *(f32x4*)&tpT[cl * 68 + row] = accV[m][n];
                    }
            }
            __syncthreads();
            for (int idx = tid; idx < 32 * 16; idx += 256) {
                int hcl = idx >> 4, s4 = (idx & 15) << 2;
                f32x4 v = *(const f32x4*)&tpT[hcl * 68 + s4];
                s16x4 hi;
#pragma unroll
                for (int j = 0; j < 4; ++j) hi[j] = (short)f2bf(v[j]);
                size_t o = ((size_t)b * HH + hp * 32 + hcl) * SS + s0 + s4;
                *(s16x4*)&vT[o] = hi;
            }
        }
    } else {
        // ================= Q path =================
        const int t0 = (blockIdx.x - NKVBLK) * 64;
        const float* abase = &inp[((size_t)b * TT + t0 + arow) * EE];

        f32x4 acc[4][2];
#pragma unroll
        for (int m = 0; m < 4; ++m)
#pragma unroll
            for (int n = 0; n < 2; ++n) acc[m][n] = (f32x4){0.f, 0.f, 0.f, 0.f};

        auto STAGEWQ = [&](int e0, int buf) {
#pragma unroll
            for (int p = 0; p < 2; ++p) {
                int h = p * 64 + wh;
                int ec = wk8 ^ ((h & 3) << 3);
                size_t g = (size_t)h * EE + e0 + ec;
                gload_lds16(&wq[g], &smB[buf][0][p * 2048 + wdst]);
            }
        };
        auto LOADPQ = [&](int p, f32x4 xa[4]) {
            int e0 = p * 64 + aq * 16;
#pragma unroll
            for (int j = 0; j < 4; ++j) xa[j] = *(const f32x4*)&abase[e0 + j * 4];
        };
        auto STOREPQ = [&](const f32x4 xa[4], int abuf) {
#pragma unroll
            for (int j = 0; j < 2; ++j) {
                bf16x8 h;
#pragma unroll
                for (int c = 0; c < 4; ++c) {
                    h[c]     = (short)f2bf(xa[2 * j][c]);
                    h[4 + c] = (short)f2bf(xa[2 * j + 1][c]);
                }
                int g = (aq * 2 + j) ^ (arow & 7);
                *(bf16x8*)&smA[abuf][arow * 64 + g * 8] = h;
            }
        };

        f32x4 xa[4];
        LOADPQ(0, xa);
        STOREPQ(xa, 0);
        STAGEWQ(0, 0);
        __syncthreads();
        LOADPQ(1, xa);

        for (int step = 0; step < 32; ++step) {
            const int wbuf = step & 1;
            const int sseg = step & 1;
            const int pbuf = (step >> 1) & 1;
            if (step < 31) STAGEWQ((step + 1) * BK, wbuf ^ 1);

            bf16x8 ah[4];
#pragma unroll
            for (int m = 0; m < 4; ++m) {
                int r = m * 16 + fr;
                int g = (sseg * 4 + fq) ^ (r & 7);
                ah[m] = *(const bf16x8*)&smA[pbuf][r * 64 + g * 8];
            }
#pragma unroll
            for (int n = 0; n < 2; ++n) {
                int c = wc * 32 + n * 16 + fr;
                int off = c * 32 + ((fq * 8) ^ ((c & 3) << 3));
                bf16x8 bh = *(const bf16x8*)&smB[wbuf][0][off];
#pragma unroll
                for (int m = 0; m < 4; ++m)
                    acc[m][n] = __builtin_amdgcn_mfma_f32_16x16x32_bf16(ah[m], bh, acc[m][n], 0, 0, 0);
            }
            if (sseg == 1 && step < 31) STOREPQ(xa, pbuf ^ 1);
            __syncthreads();
            if (sseg == 1 && step < 29) LOADPQ((step >> 1) + 2, xa);
        }
#pragma unroll
        for (int m = 0; m < 4; ++m) {
            int row = t0 + m * 16 + fq * 4;
#pragma unroll
            for (int n = 0; n < 2; ++n) {
                int col = wc * 32 + n * 16 + fr;
#pragma unroll
                for (int i = 0; i < 4; ++i)
                    qb[((size_t)b * TT + row + i) * HH + col] = (short)f2bf(acc[m][n][i]);
            }
        }
    }
}

// ---------------- shared attn helpers ----------------
__device__ __forceinline__ void stage_k64_async(const short* __restrict__ src,
                                                size_t rowBase, int tid, short* sh)
{
#pragma unroll
    for (int c2 = 0; c2 < 4; ++c2) {
        int srow = c2 * 16 + (tid >> 4);
        int scol = ((tid & 15) * 8) ^ ((srow & 7) << 3);
        size_t g = (rowBase + srow) * HH + scol;
        gload_lds16(&src[g], &sh[c2 * 2048 + (tid >> 6) * 512]);
    }
}

__device__ __forceinline__ void stage_v64_async(const short* __restrict__ vT,
                                                int b, int st, int tid, short* vs)
{
#pragma unroll
    for (int c2 = 0; c2 < 4; ++c2) {
        int h = c2 * 32 + (tid >> 3);
        int sc = ((tid & 7) * 8) ^ ((h & 7) << 3);
        size_t g = ((size_t)b * HH + h) * SS + st + sc;
        gload_lds16(&vT[g], &vs[c2 * 2048 + (tid >> 6) * 512]);
    }
}

__device__ __forceinline__ void load_qfrags(const short* __restrict__ qb,
                                            size_t rowIx, int fq, bf16x8 qh[4])
{
    size_t base = rowIx * HH + fq * 8;
#pragma unroll
    for (int k = 0; k < 4; ++k)
        qh[k] = *(const bf16x8*)&qb[base + k * 32];
}

__device__ __forceinline__ void qk_mfma4(const bf16x8 qh[4], const short* sh,
                                         int fr, int fq, f32x4 acc[4])
{
#pragma unroll
    for (int n = 0; n < 4; ++n) {
        int sc = n * 16 + fr;
        int ro = sc * 128, msk = (sc & 7) << 3;
#pragma unroll
        for (int k = 0; k < 4; ++k) {
            int off = ro + ((k * 32 + fq * 8) ^ msk);
            bf16x8 bh = *(const bf16x8*)&sh[off];
            acc[n] = __builtin_amdgcn_mfma_f32_16x16x32_bf16(qh[k], bh, acc[n], 0, 0, 0);
        }
    }
}

// XCD-aware remap: flat f in [0,512) -> (b, split, ttile); all 16 ttile-members of
// a (b,split) group share f%8 (same XCD under round-robin dispatch).
__device__ __forceinline__ void xcd_remap(int f, int& b, int& split, int& ttile)
{
    int xcd = f & 7, slot = f >> 3;
    int g = (slot >> 4) * 8 + xcd;    // group id in [0,32)
    ttile = slot & 15;
    b = g >> 2;
    split = g & 3;
}

// ---------------- K3: rowmax of (qk*scale)^2 via MFMA (dbuf K, 32KB) ----------------
__global__ __launch_bounds__(256) void k_rowmax(
    const short* __restrict__ qb, const short* __restrict__ kb,
    float* __restrict__ rowmax)
{
    __shared__ short Ks[2][64 * 128];   // 32KB
    const int tid = threadIdx.x, lane = tid & 63, wloc = tid >> 6;
    const int fr = lane & 15, fq = lane >> 4;
    int b, split, ttile;
    xcd_remap(blockIdx.x, b, split, ttile);
    const int t0 = ttile * 64;

    bf16x8 qh[4];
    load_qfrags(qb, (size_t)b * TT + t0 + wloc * 16 + fr, fq, qh);

    float rm[4] = {0.f, 0.f, 0.f, 0.f};
    const int sBeg = split * SCHUNK;
    const size_t kbase = (size_t)b * SS;

    stage_k64_async(kb, kbase + sBeg, tid, Ks[0]);
    __syncthreads();
    for (int t = 0; t < NT; ++t) {
        const int bf = t & 1;
        if (t + 1 < NT)
            stage_k64_async(kb, kbase + sBeg + (t + 1) * 64, tid, Ks[bf ^ 1]);
        f32x4 acc[4];
#pragma unroll
        for (int n = 0; n < 4; ++n) acc[n] = (f32x4){0.f, 0.f, 0.f, 0.f};
        __builtin_amdgcn_s_setprio(1);
        qk_mfma4(qh, Ks[bf], fr, fq, acc);
        __builtin_amdgcn_s_setprio(0);
#pragma unroll
        for (int n = 0; n < 4; ++n)
#pragma unroll
            for (int i = 0; i < 4; ++i) {
                float w = acc[n][i] * SCALEF;
                rm[i] = fmaxf(rm[i], w * w);
            }
        __syncthreads();   // next tile staged (covered by QK)
    }
#pragma unroll
    for (int d = 1; d < 16; d <<= 1)
#pragma unroll
        for (int i = 0; i < 4; ++i)
            rm[i] = fmaxf(rm[i], __shfl_xor(rm[i], d, 64));
    if (fr == 0)
#pragma unroll
        for (int i = 0; i < 4; ++i)
            atomicMax((int*)&rowmax[b * TT + t0 + wloc * 16 + fq * 4 + i], __float_as_int(rm[i]));
}

// ---------------- K4: attention — per-tile colsum, grouped qt_loss logs ----------------
__global__ __launch_bounds__(256) void k_attn(
    const short* __restrict__ qb, const short* __restrict__ kb,
    const short* __restrict__ vT,
    const float* __restrict__ rowmax,
    float* __restrict__ outAcc, float* __restrict__ cpart, float* __restrict__ qtloss)
{
    __shared__ short Ks[2][64 * 128];   // 32KB
    __shared__ short Vs[2][128 * 64];   // 32KB
    __shared__ short Ph[64 * 64];       // 8KB
    __shared__ float csT[2][64];        // 512B (per-tile colsum, dbuf)
    __shared__ float qred[256];
    const int tid = threadIdx.x, lane = tid & 63, wloc = tid >> 6;
    const int fr = lane & 15, fq = lane >> 4;
    int b, split, ttile;
    xcd_remap(blockIdx.x, b, split, ttile);
    const int t0 = ttile * 64;

    if (tid < 128) ((float*)csT)[tid] = 0.f;

    bf16x8 qh[4];
    load_qfrags(qb, (size_t)b * TT + t0 + wloc * 16 + fr, fq, qh);

    float inv[4];
#pragma unroll
    for (int i = 0; i < 4; ++i)
        inv[i] = 1.0f / rowmax[b * TT + t0 + wloc * 16 + fq * 4 + i];

    f32x4 oacc[8];
#pragma unroll
    for (int n = 0; n < 8; ++n) oacc[n] = (f32x4){0.f, 0.f, 0.f, 0.f};
    float qtp = 0.f;

    const int sBeg = split * SCHUNK;
    const size_t kbase = (size_t)b * SS;
    float* cprow = &cpart[((size_t)(b * 16 + ttile)) * SS + sBeg];

    stage_k64_async(kb, kbase + sBeg, tid, Ks[0]);
    stage_v64_async(vT, b, sBeg, tid, Vs[0]);

    for (int t = 0; t < NT; ++t) {
        const int bf = t & 1;
        __syncthreads();   // stage(t) landed; Ph + victim buffers free

        if (t + 1 < NT) {  // issue next-tile staging NOW — covered by QK+softmax+PV
            stage_k64_async(kb, kbase + sBeg + (t + 1) * 64, tid, Ks[bf ^ 1]);
            stage_v64_async(vT, b, sBeg + (t + 1) * 64, tid, Vs[bf ^ 1]);
        }

        f32x4 acc[4];
#pragma unroll
        for (int n = 0; n < 4; ++n) acc[n] = (f32x4){0.f, 0.f, 0.f, 0.f};
        __builtin_amdgcn_s_setprio(1);
        qk_mfma4(qh, Ks[bf], fr, fq, acc);
        __builtin_amdgcn_s_setprio(0);

        // softmax: wei bits unchanged; qt_loss logs grouped 8-to-1
        // (prod of 8 values in [1e-4, ~1.0001] >= 1e-32 — no underflow)
        float prod = 1.f;
#pragma unroll
        for (int n = 0; n < 4; ++n) {
            float cp = 0.f;
#pragma unroll
            for (int i = 0; i < 4; ++i) {
                float w = acc[n][i] * SCALEF;
                float w2 = w * w;
                float wei = w2 * inv[i];
                prod *= (wei + 1e-4f);
                cp += wei;
                int r = wloc * 16 + fq * 4 + i;
                int sw = (n * 16 + fr) ^ ((r & 7) << 3);
                Ph[r * 64 + sw] = (short)f2bf(wei);
            }
            cp += __shfl_xor(cp, 16, 64);
            cp += __shfl_xor(cp, 32, 64);
            if (fq == 0) atomicAdd(&csT[bf][n * 16 + fr], cp);
            if (n == 1) { qtp += __logf(prod); prod = 1.f; }
        }
        qtp += __logf(prod);

        asm volatile("s_waitcnt lgkmcnt(0)" ::: "memory");
        SBAR(); SCB();   // Ph + csT[bf] visible; staged loads NOT drained
        // write per-tile colsum + reset buffer for tile t+2 (next use after 2 barriers)
        if (tid < 64) {
            cprow[t * 64 + tid] = csT[bf][tid];
            csT[bf][tid] = 0.f;
        }
        // PV
        {
            int rA = wloc * 16 + fr;
            __builtin_amdgcn_s_setprio(1);
#pragma unroll
            for (int k = 0; k < 2; ++k) {
                int offA = rA * 64 + ((k * 32 + fq * 8) ^ ((rA & 7) << 3));
                bf16x8 ph = *(const bf16x8*)&Ph[offA];
#pragma unroll
                for (int n = 0; n < 8; ++n) {
                    int hc = n * 16 + fr;
                    int offB = hc * 64 + ((k * 32 + fq * 8) ^ ((hc & 7) << 3));
                    bf16x8 vh = *(const bf16x8*)&Vs[bf][offB];
                    oacc[n] = __builtin_amdgcn_mfma_f32_16x16x32_bf16(ph, vh, oacc[n], 0, 0, 0);
                }
            }
            __builtin_amdgcn_s_setprio(0);
        }
    }

#pragma unroll
    for (int n = 0; n < 8; ++n)
#pragma unroll
        for (int i = 0; i < 4; ++i)
            atomicAdd(&outAcc[((size_t)b * TT + t0 + wloc * 16 + fq * 4 + i) * HH + n * 16 + fr],
                      oacc[n][i]);

    qred[tid] = qtp;
    __syncthreads();
    for (int off = 128; off; off >>= 1) {
        if (tid < off) qred[tid] += qred[tid + off];
        __syncthreads();
    }
    if (tid == 0) atomicAdd(qtloss, qred[0]);
}

// ---------------- K5: fused rank + bitonic sort (blocks 0..7) + eviction-tail copy (blocks 8..1031) ----
__global__ __launch_bounds__(1024) void k_ranksort(
    const float* __restrict__ cpart, const float* __restrict__ mrank,
    float* __restrict__ csum, unsigned long long* __restrict__ keys,
    const float* __restrict__ inp, float* __restrict__ nmem,
    float* __restrict__ ndist, float* __restrict__ nrank)
{
    __shared__ unsigned long long a[MM];   // 64KB
    __shared__ float red[1024];            // 4KB
    const int blk = blockIdx.x, tid = threadIdx.x;

    if (blk >= BB) {
        // ---- tail copy: new_memory[RKEEP..MM) = inp tail; dist=0, rank=1 ----
        const int idx = blk - BB;            // 0..1023, 128 blocks per batch
        const int b = idx >> 7;
        const int r0 = RKEEP + (idx & 127) * 8;
#pragma unroll
        for (int rr = 0; rr < 2; ++rr) {
            int row = r0 + rr * 4 + (tid >> 8);     // 4 rows per pass
            int irow = row - RKEEP;
            int c4 = (tid & 255) * 4;
            *(f32x4*)&nmem[((size_t)b * MM + row) * EE + c4] =
                *(const f32x4*)&inp[((size_t)b * TT + irow) * EE + c4];
        }
        if (tid < 8) {
            int p = r0 + tid;
            ndist[b * MM + p] = 0.f;
            nrank[b * MM + p] = 1.0f;
        }
        return;
    }

    const int b = blk;
    // ---- rank phase ----
    float p = 0.f;
    for (int s = tid; s < SS; s += 1024) {
        float cs = 0.f;
#pragma unroll
        for (int tt = 0; tt < 16; ++tt) cs += cpart[((size_t)(b * 16 + tt)) * SS + s];
        csum[b * SS + s] = cs;
        p += cs;
    }
    red[tid] = p;
    __syncthreads();
    for (int off = 512; off; off >>= 1) {
        if (tid < off) red[tid] += red[tid + off];
        __syncthreads();
    }
    float mean = red[0] / (float)SS;
    for (int m = tid; m < MM; m += 1024) {
        float rank = ((mrank[b * MM + m] + csum[b * SS + m] / mean) - 1.0f) - 0.01f;
        a[m] = ((unsigned long long)(unsigned)(~f2ord(rank)) << 32) | (unsigned)m;
    }
    __syncthreads();

    // ---- bitonic sort phase (asc by key == desc by rank, idx tiebreak) ----
    for (int k = 2; k <= MM; k <<= 1) {
        for (int j = k >> 1; j > 0; j >>= 1) {
            for (int i = tid; i < MM; i += 1024) {
                int l = i ^ j;
                if (l > i) {
                    unsigned long long x = a[i], y = a[l];
                    bool up = ((i & k) == 0);
                    if ((x > y) == up) { a[i] = y; a[l] = x; }
                }
            }
            __syncthreads();
        }
    }
    for (int i = tid; i < MM; i += 1024) keys[(size_t)b * MM + i] = a[i];
}

// ---------------- K6: scatter kept rows only (p < RKEEP), prefetched ----------------
__global__ __launch_bounds__(256) void k_scatter(
    const float* __restrict__ memory, const int* __restrict__ mbd,
    const int* __restrict__ bpl, const unsigned long long* __restrict__ keys,
    float* __restrict__ nmem, float* __restrict__ ndist, float* __restrict__ nrank)
{
    const int blk = blockIdx.x;
    const int b = blk / (RKEEP / 8);           // 896 blocks per batch
    const int p0 = (blk % (RKEEP / 8)) * 8;
    const bool reset = (bpl[b] == 0);
    const int tid = threadIdx.x;
    const f32x4 zero = (f32x4){0.f, 0.f, 0.f, 0.f};

    f32x4 vr[8];
    float dist[8], rankv[8];
#pragma unroll
    for (int r = 0; r < 8; ++r) {
        int p = p0 + r;
        unsigned long long key = keys[(size_t)b * MM + p];
        int src = (int)(unsigned)(key & 0xFFFFFFFFu);
        vr[r] = reset ? zero
                      : *(const f32x4*)&memory[((size_t)b * MM + src) * EE + tid * 4];
        dist[r]  = reset ? 1.0f : (float)(mbd[b * MM + src] + 1);
        rankv[r] = ord2f(~(unsigned)(key >> 32));
    }
#pragma unroll
    for (int r = 0; r < 8; ++r) {
        int p = p0 + r;
        *(f32x4*)&nmem[((size_t)b * MM + p) * EE + tid * 4] = vr[r];
        if (tid == 0) { ndist[b * MM + p] = dist[r]; nrank[b * MM + p] = rankv[r]; }
    }
}

// ---------------- launcher ----------------
extern "C" void kernel_launch(void* const* d_in, const int* in_sizes, int n_in,
                              void* d_out, int out_size, void* d_ws, size_t ws_size,
                              hipStream_t stream)
{
    const int*   bpl    = (const int*)d_in[0];
    const float* inp    = (const float*)d_in[1];
    const float* memory = (const float*)d_in[2];
    const int*   mbd    = (const int*)d_in[3];
    const float* mrank  = (const float*)d_in[4];
    const float* pos    = (const float*)d_in[5];
    const float* Wk     = (const float*)d_in[6];
    const float* Wq     = (const float*)d_in[7];
    const float* Wv     = (const float*)d_in[8];

    float* out   = (float*)d_out;                    // [B,T,H]
    float* qtl   = out + (size_t)BB * TT * HH;       // scalar
    float* nmem  = qtl + 1;                          // [B,M,E]
    float* ndist = nmem + (size_t)BB * MM * EE;      // [B,M]
    float* nrank = ndist + (size_t)BB * MM;          // [B,M]

    char* w = (char*)d_ws;
    short* qb = (short*)w; w += (size_t)BB * TT * HH * 2;
    short* kb = (short*)w; w += (size_t)BB * SS * HH * 2;
    short* vT = (short*)w; w += (size_t)BB * HH * SS * 2;
    float* rmax = (float*)w; w += (size_t)BB * TT * 4;
    float* csum = (float*)w; w += (size_t)BB * SS * 4;
    float* cpart = (float*)w; w += (size_t)BB * 16 * SS * 4;
    unsigned long long* keys = (unsigned long long*)w; w += (size_t)BB * MM * 8;
    short* wk = (short*)w; w += (size_t)HH * EE * 2;
    short* wq = (short*)w; w += (size_t)HH * EE * 2;
    short* wv = (short*)w; w += (size_t)HH * EE * 2;
    if ((size_t)(w - (char*)d_ws) > ws_size) return;

    k_init   <<<512, 256, 0, stream>>>(Wk, Wq, Wv, wk, wq, wv, out, rmax);
    k_proj   <<<dim3(NKVBLK + TT / 64, BB), 256, 0, stream>>>(memory, mbd, bpl, pos, inp,
                                                              wk, wv, wq, kb, vT, qb);
    k_rowmax <<<NSPLIT * (TT / 64) * BB, 256, 0, stream>>>(qb, kb, rmax);
    k_attn   <<<NSPLIT * (TT / 64) * BB, 256, 0, stream>>>(qb, kb, vT,
                                                           rmax, out, cpart, qtl);
    k_ranksort<<<BB + BB * 128, 1024, 0, stream>>>(cpart, mrank, csum, keys,
                                                   inp, nmem, ndist, nrank);
    k_scatter<<<BB * (RKEEP / 8), 256, 0, stream>>>(memory, mbd, bpl, keys,
                                                    nmem, ndist, nrank);
}

// Round 22
// 489.195 us; speedup vs baseline: 1.2445x; 1.0027x over previous
//
#include <hip/hip_runtime.h>
#include <hip/hip_bf16.h>
#include <stdint.h>

#define BB 8
#define TT 1024
#define MM 8192
#define EE 1024
#define HH 128
#define SS (MM + TT)          // 9216
#define RKEEP (MM - 1024)     // 7168 rows kept after eviction
#define NSPLIT 4
#define SCHUNK (SS / NSPLIT)  // 2304
#define NT (SCHUNK / 64)      // 36
#define BK 32
#define NKVBLK (SS / 64)      // 144

typedef __attribute__((ext_vector_type(8))) short bf16x8;
typedef __attribute__((ext_vector_type(4))) short s16x4;
typedef __attribute__((ext_vector_type(4))) float f32x4;

#define VMCNT(n) asm volatile("s_waitcnt vmcnt(" #n ")" ::: "memory")
#define LGKM0()  asm volatile("s_waitcnt lgkmcnt(0)" ::: "memory")
#define SBAR()   __builtin_amdgcn_s_barrier()
#define SCB()    __builtin_amdgcn_sched_barrier(0)

static __device__ __forceinline__ unsigned f2ord(float f) {
    unsigned u = __float_as_uint(f);
    return u ^ ((u & 0x80000000u) ? 0xFFFFFFFFu : 0x80000000u);
}
static __device__ __forceinline__ float ord2f(unsigned o) {
    unsigned u = (o & 0x80000000u) ? (o ^ 0x80000000u) : ~o;
    return __uint_as_float(u);
}
static __device__ __forceinline__ unsigned short f2bf(float x) {
    unsigned u = __float_as_uint(x);
    unsigned r = u + 0x7FFFu + ((u >> 16) & 1u);   // RNE
    return (unsigned short)(r >> 16);
}

// async global->LDS, 16B per lane; dest = wave-uniform base + lane*16
static __device__ __forceinline__ void gload_lds16(const short* g, short* l) {
    __builtin_amdgcn_global_load_lds(
        (const __attribute__((address_space(1))) void*)g,
        (__attribute__((address_space(3))) void*)l, 16, 0, 0);
}

__device__ const float SCALEF = (float)(1.0 / 96.0);  // (M+T)^-0.5

// ---------------- K0: weights->bf16 planes + zero out/qtl/rmax (fused init) ----------------
__global__ __launch_bounds__(256) void k_init(
    const float* __restrict__ Wk, const float* __restrict__ Wq, const float* __restrict__ Wv,
    short* __restrict__ wk, short* __restrict__ wq, short* __restrict__ wv,
    float* __restrict__ outZ, float* __restrict__ rmax)
{
    const int blk = blockIdx.x, tid = threadIdx.x;
    if (blk < 384) {
        int idx = blk * 256 + tid;
        int m = idx >> 15;
        int o4 = (idx & 32767) * 4;
        const float* W = m == 0 ? Wk : (m == 1 ? Wq : Wv);
        short* D = m == 0 ? wk : (m == 1 ? wq : wv);
        f32x4 v = *(const f32x4*)&W[o4];
        s16x4 h;
#pragma unroll
        for (int j = 0; j < 4; ++j) h[j] = (short)f2bf(v[j]);
        *(s16x4*)&D[o4] = h;
    } else {
        const int z = (blk - 384) * 256 + tid;       // 128 blocks
        const f32x4 zero = (f32x4){0.f, 0.f, 0.f, 0.f};
        for (int i = z; i < (BB * TT * HH) / 4; i += 128 * 256)
            ((f32x4*)outZ)[i] = zero;
        if (z == 0) outZ[BB * TT * HH] = 0.f;        // qt_loss scalar
        if (z < (BB * TT) / 4) ((f32x4*)rmax)[z] = zero;
    }
}

// ---------------- K1: fused K,V + Q projection — wave-private W staging ----------------
// W slices are wave-disjoint (wave wc uses h-cols wc*32..+32), staged into per-wave LDS
// and synchronized by counted vmcnt only. Cross-wave barriers remain only for the shared
// A panel (dbuf): one lgkm-only barrier per 2 K-steps.
__global__ __launch_bounds__(256, 3) void k_proj(
    const float* __restrict__ memory, const int* __restrict__ mbd,
    const int* __restrict__ bpl, const float* __restrict__ pos_table,
    const float* __restrict__ inp,
    const short* __restrict__ wk, const short* __restrict__ wv,
    const short* __restrict__ wq,
    short* __restrict__ kb, short* __restrict__ vT, short* __restrict__ qb)
{
    __shared__ __align__(16) short smA[2][64 * 64];        // 16KB (A panel dbuf)
    __shared__ __align__(16) short smB[2][2][4][1024];     // 32KB: [buf][plane][wave][32x32 slice]

    const int tid = threadIdx.x;
    const int b   = blockIdx.y;
    const int lane = tid & 63, wid = tid >> 6;
    const int wc = wid;
    const int fr = lane & 15, fq = lane >> 4;
    const int arow = tid >> 2;
    const int aq   = tid & 3;
    // wave-private W slice addressing: issue c2 covers h_local = c2*16 + (lane>>2),
    // source chunk = (lane&3) ^ (h_local&3) (source-swizzled; LDS dest linear)
    const int hl0 = (lane >> 2);
    const int sch = (lane & 3);

    if (blockIdx.x < NKVBLK) {
        // ================= KV path =================
        const int s0 = blockIdx.x * 64;
        const bool reset = (bpl[b] == 0);
        int pix;
        const float* abase;
        {
            int s = s0 + arow;
            if (s < MM) {
                int d = reset ? 1 : (mbd[b * MM + s] + 1);
                pix = 31 - __clz(d);
                abase = reset ? nullptr : &memory[((size_t)b * MM + s) * EE];
            } else {
                pix = -1;
                abase = &inp[((size_t)b * TT + (s - MM)) * EE];
            }
        }

        f32x4 accK[4][2], accV[4][2];
#pragma unroll
        for (int m = 0; m < 4; ++m)
#pragma unroll
            for (int n = 0; n < 2; ++n) {
                accK[m][n] = (f32x4){0.f, 0.f, 0.f, 0.f};
                accV[m][n] = (f32x4){0.f, 0.f, 0.f, 0.f};
            }

        auto STAGEW = [&](int e0, int buf) {   // 4 gload_lds, wave-private dest
#pragma unroll
            for (int c2 = 0; c2 < 2; ++c2) {
                int hlocal = c2 * 16 + hl0;
                int h = wc * 32 + hlocal;
                int ec = ((sch ^ (hlocal & 3)) << 3);
                size_t g = (size_t)h * EE + e0 + ec;
                gload_lds16(&wk[g], &smB[buf][0][wid][c2 * 512]);
                gload_lds16(&wv[g], &smB[buf][1][wid][c2 * 512]);
            }
        };
        auto LOADP = [&](int p, f32x4 xa[4]) {
            int e0 = p * 64 + aq * 16;
#pragma unroll
            for (int j = 0; j < 4; ++j) {
                f32x4 v = (f32x4){0.f, 0.f, 0.f, 0.f};
                if (abase) v = *(const f32x4*)&abase[e0 + j * 4];
                if (pix >= 0) {
                    f32x4 pt = *(const f32x4*)&pos_table[(size_t)pix * EE + e0 + j * 4];
                    v[0] += pt[0]; v[1] += pt[1]; v[2] += pt[2]; v[3] += pt[3];
                }
                xa[j] = v;
            }
        };
        auto STOREP = [&](const f32x4 xa[4], int abuf) {
#pragma unroll
            for (int j = 0; j < 2; ++j) {
                bf16x8 h;
#pragma unroll
                for (int c = 0; c < 4; ++c) {
                    h[c]     = (short)f2bf(xa[2 * j][c]);
                    h[4 + c] = (short)f2bf(xa[2 * j + 1][c]);
                }
                int g = (aq * 2 + j) ^ (arow & 7);
                *(bf16x8*)&smA[abuf][arow * 64 + g * 8] = h;
            }
        };

        f32x4 xa[4];
        LOADP(0, xa);
        STOREP(xa, 0);
        STAGEW(0, 0);
        __syncthreads();          // prologue: full drain (STAGEW(0) + smA visible)
        LOADP(1, xa);

        for (int step = 0; step < 32; ++step) {
            const int wbuf = step & 1;
            const int pbuf = (step >> 1) & 1;
            if (step < 31) STAGEW((step + 1) * BK, wbuf ^ 1);
            SCB();
            // wait for STAGEW(step): newer = STAGEW(step+1)[4] + LOADP[4 iff step even<=28]
            if (step == 31)           { VMCNT(0); }
            else if (step & 1)        { VMCNT(4); }
            else if (step <= 28)      { VMCNT(8); }
            else                      { VMCNT(4); }
            SCB();

            const int sseg = step & 1;
            bf16x8 ah[4];
#pragma unroll
            for (int m = 0; m < 4; ++m) {
                int r = m * 16 + fr;
                int g = (sseg * 4 + fq) ^ (r & 7);
                ah[m] = *(const bf16x8*)&smA[pbuf][r * 64 + g * 8];
            }
#pragma unroll
            for (int n = 0; n < 2; ++n) {
                int off = n * 512 + fr * 32 + ((fq ^ (fr & 3)) << 3);
                bf16x8 kh = *(const bf16x8*)&smB[wbuf][0][wid][off];
                bf16x8 vh = *(const bf16x8*)&smB[wbuf][1][wid][off];
#pragma unroll
                for (int m = 0; m < 4; ++m) {
                    accK[m][n] = __builtin_amdgcn_mfma_f32_16x16x32_bf16(ah[m], kh, accK[m][n], 0, 0, 0);
                    accV[m][n] = __builtin_amdgcn_mfma_f32_16x16x32_bf16(ah[m], vh, accV[m][n], 0, 0, 0);
                }
            }
            if ((step & 1) && step < 31) {      // A-panel swap: lgkm-only barrier
                STOREP(xa, pbuf ^ 1);
                LGKM0(); SBAR(); SCB();
                if (step < 29) LOADP((step >> 1) + 2, xa);
            }
        }

        // K epilogue
#pragma unroll
        for (int m = 0; m < 4; ++m) {
            int row = s0 + m * 16 + fq * 4;
#pragma unroll
            for (int n = 0; n < 2; ++n) {
                int col = wc * 32 + n * 16 + fr;
#pragma unroll
                for (int i = 0; i < 4; ++i)
                    kb[((size_t)b * SS + row + i) * HH + col] = (short)f2bf(accK[m][n][i]);
            }
        }
        // V epilogue: transpose via LDS (aliasing smB)
        float* tpT = (float*)smB;
#pragma unroll
        for (int hp = 0; hp < 4; ++hp) {
            __syncthreads();
            if (wc == hp) {
#pragma unroll
                for (int m = 0; m < 4; ++m)
#pragma unroll
                    for (int n = 0; n < 2; ++n) {
                        int cl = n * 16 + fr;
                        int row = m * 16 + fq * 4;
                        *(f32x4*)&tpT[cl * 68 + row] = accV[m][n];
                    }
            }
            __syncthreads();
            for (int idx = tid; idx < 32 * 16; idx += 256) {
                int hcl = idx >> 4, s4 = (idx & 15) << 2;
                f32x4 v = *(const f32x4*)&tpT[hcl * 68 + s4];
                s16x4 hi;
#pragma unroll
                for (int j = 0; j < 4; ++j) hi[j] = (short)f2bf(v[j]);
                size_t o = ((size_t)b * HH + hp * 32 + hcl) * SS + s0 + s4;
                *(s16x4*)&vT[o] = hi;
            }
        }
    } else {
        // ================= Q path =================
        const int t0 = (blockIdx.x - NKVBLK) * 64;
        const float* abase = &inp[((size_t)b * TT + t0 + arow) * EE];

        f32x4 acc[4][2];
#pragma unroll
        for (int m = 0; m < 4; ++m)
#pragma unroll
            for (int n = 0; n < 2; ++n) acc[m][n] = (f32x4){0.f, 0.f, 0.f, 0.f};

        auto STAGEWQ = [&](int e0, int buf) {   // 2 gload_lds, wave-private dest
#pragma unroll
            for (int c2 = 0; c2 < 2; ++c2) {
                int hlocal = c2 * 16 + hl0;
                int h = wc * 32 + hlocal;
                int ec = ((sch ^ (hlocal & 3)) << 3);
                size_t g = (size_t)h * EE + e0 + ec;
                gload_lds16(&wq[g], &smB[buf][0][wid][c2 * 512]);
            }
        };
        auto LOADPQ = [&](int p, f32x4 xa[4]) {
            int e0 = p * 64 + aq * 16;
#pragma unroll
            for (int j = 0; j < 4; ++j) xa[j] = *(const f32x4*)&abase[e0 + j * 4];
        };
        auto STOREPQ = [&](const f32x4 xa[4], int abuf) {
#pragma unroll
            for (int j = 0; j < 2; ++j) {
                bf16x8 h;
#pragma unroll
                for (int c = 0; c < 4; ++c) {
                    h[c]     = (short)f2bf(xa[2 * j][c]);
                    h[4 + c] = (short)f2bf(xa[2 * j + 1][c]);
                }
                int g = (aq * 2 + j) ^ (arow & 7);
                *(bf16x8*)&smA[abuf][arow * 64 + g * 8] = h;
            }
        };

        f32x4 xa[4];
        LOADPQ(0, xa);
        STOREPQ(xa, 0);
        STAGEWQ(0, 0);
        __syncthreads();
        LOADPQ(1, xa);

        for (int step = 0; step < 32; ++step) {
            const int wbuf = step & 1;
            const int pbuf = (step >> 1) & 1;
            if (step < 31) STAGEWQ((step + 1) * BK, wbuf ^ 1);
            SCB();
            if (step == 31)           { VMCNT(0); }
            else if (step & 1)        { VMCNT(2); }
            else if (step <= 28)      { VMCNT(6); }
            else                      { VMCNT(2); }
            SCB();

            const int sseg = step & 1;
            bf16x8 ah[4];
#pragma unroll
            for (int m = 0; m < 4; ++m) {
                int r = m * 16 + fr;
                int g = (sseg * 4 + fq) ^ (r & 7);
                ah[m] = *(const bf16x8*)&smA[pbuf][r * 64 + g * 8];
            }
#pragma unroll
            for (int n = 0; n < 2; ++n) {
                int off = n * 512 + fr * 32 + ((fq ^ (fr & 3)) << 3);
                bf16x8 bh = *(const bf16x8*)&smB[wbuf][0][wid][off];
#pragma unroll
                for (int m = 0; m < 4; ++m)
                    acc[m][n] = __builtin_amdgcn_mfma_f32_16x16x32_bf16(ah[m], bh, acc[m][n], 0, 0, 0);
            }
            if ((step & 1) && step < 31) {
                STOREPQ(xa, pbuf ^ 1);
                LGKM0(); SBAR(); SCB();
                if (step < 29) LOADPQ((step >> 1) + 2, xa);
            }
        }
#pragma unroll
        for (int m = 0; m < 4; ++m) {
            int row = t0 + m * 16 + fq * 4;
#pragma unroll
            for (int n = 0; n < 2; ++n) {
                int col = wc * 32 + n * 16 + fr;
#pragma unroll
                for (int i = 0; i < 4; ++i)
                    qb[((size_t)b * TT + row + i) * HH + col] = (short)f2bf(acc[m][n][i]);
            }
        }
    }
}

// ---------------- shared attn helpers ----------------
__device__ __forceinline__ void stage_k64_async(const short* __restrict__ src,
                                                size_t rowBase, int tid, short* sh)
{
#pragma unroll
    for (int c2 = 0; c2 < 4; ++c2) {
        int srow = c2 * 16 + (tid >> 4);
        int scol = ((tid & 15) * 8) ^ ((srow & 7) << 3);
        size_t g = (rowBase + srow) * HH + scol;
        gload_lds16(&src[g], &sh[c2 * 2048 + (tid >> 6) * 512]);
    }
}

__device__ __forceinline__ void stage_v64_async(const short* __restrict__ vT,
                                                int b, int st, int tid, short* vs)
{
#pragma unroll
    for (int c2 = 0; c2 < 4; ++c2) {
        int h = c2 * 32 + (tid >> 3);
        int sc = ((tid & 7) * 8) ^ ((h & 7) << 3);
        size_t g = ((size_t)b * HH + h) * SS + st + sc;
        gload_lds16(&vT[g], &vs[c2 * 2048 + (tid >> 6) * 512]);
    }
}

__device__ __forceinline__ void load_qfrags(const short* __restrict__ qb,
                                            size_t rowIx, int fq, bf16x8 qh[4])
{
    size_t base = rowIx * HH + fq * 8;
#pragma unroll
    for (int k = 0; k < 4; ++k)
        qh[k] = *(const bf16x8*)&qb[base + k * 32];
}

__device__ __forceinline__ void qk_mfma4(const bf16x8 qh[4], const short* sh,
                                         int fr, int fq, f32x4 acc[4])
{
#pragma unroll
    for (int n = 0; n < 4; ++n) {
        int sc = n * 16 + fr;
        int ro = sc * 128, msk = (sc & 7) << 3;
#pragma unroll
        for (int k = 0; k < 4; ++k) {
            int off = ro + ((k * 32 + fq * 8) ^ msk);
            bf16x8 bh = *(const bf16x8*)&sh[off];
            acc[n] = __builtin_amdgcn_mfma_f32_16x16x32_bf16(qh[k], bh, acc[n], 0, 0, 0);
        }
    }
}

// XCD-aware remap: flat f in [0,512) -> (b, split, ttile); all 16 ttile-members of
// a (b,split) group share f%8 (same XCD under round-robin dispatch).
__device__ __forceinline__ void xcd_remap(int f, int& b, int& split, int& ttile)
{
    int xcd = f & 7, slot = f >> 3;
    int g = (slot >> 4) * 8 + xcd;    // group id in [0,32)
    ttile = slot & 15;
    b = g >> 2;
    split = g & 3;
}

// ---------------- K3: rowmax of (qk*scale)^2 via MFMA (dbuf K, 32KB) ----------------
__global__ __launch_bounds__(256) void k_rowmax(
    const short* __restrict__ qb, const short* __restrict__ kb,
    float* __restrict__ rowmax)
{
    __shared__ short Ks[2][64 * 128];   // 32KB
    const int tid = threadIdx.x, lane = tid & 63, wloc = tid >> 6;
    const int fr = lane & 15, fq = lane >> 4;
    int b, split, ttile;
    xcd_remap(blockIdx.x, b, split, ttile);
    const int t0 = ttile * 64;

    bf16x8 qh[4];
    load_qfrags(qb, (size_t)b * TT + t0 + wloc * 16 + fr, fq, qh);

    float rm[4] = {0.f, 0.f, 0.f, 0.f};
    const int sBeg = split * SCHUNK;
    const size_t kbase = (size_t)b * SS;

    stage_k64_async(kb, kbase + sBeg, tid, Ks[0]);
    __syncthreads();
    for (int t = 0; t < NT; ++t) {
        const int bf = t & 1;
        if (t + 1 < NT)
            stage_k64_async(kb, kbase + sBeg + (t + 1) * 64, tid, Ks[bf ^ 1]);
        f32x4 acc[4];
#pragma unroll
        for (int n = 0; n < 4; ++n) acc[n] = (f32x4){0.f, 0.f, 0.f, 0.f};
        __builtin_amdgcn_s_setprio(1);
        qk_mfma4(qh, Ks[bf], fr, fq, acc);
        __builtin_amdgcn_s_setprio(0);
#pragma unroll
        for (int n = 0; n < 4; ++n)
#pragma unroll
            for (int i = 0; i < 4; ++i) {
                float w = acc[n][i] * SCALEF;
                rm[i] = fmaxf(rm[i], w * w);
            }
        __syncthreads();   // next tile staged (covered by QK)
    }
#pragma unroll
    for (int d = 1; d < 16; d <<= 1)
#pragma unroll
        for (int i = 0; i < 4; ++i)
            rm[i] = fmaxf(rm[i], __shfl_xor(rm[i], d, 64));
    if (fr == 0)
#pragma unroll
        for (int i = 0; i < 4; ++i)
            atomicMax((int*)&rowmax[b * TT + t0 + wloc * 16 + fq * 4 + i], __float_as_int(rm[i]));
}

// ---------------- K4: attention — per-tile colsum, grouped qt_loss logs ----------------
__global__ __launch_bounds__(256) void k_attn(
    const short* __restrict__ qb, const short* __restrict__ kb,
    const short* __restrict__ vT,
    const float* __restrict__ rowmax,
    float* __restrict__ outAcc, float* __restrict__ cpart, float* __restrict__ qtloss)
{
    __shared__ short Ks[2][64 * 128];   // 32KB
    __shared__ short Vs[2][128 * 64];   // 32KB
    __shared__ short Ph[64 * 64];       // 8KB
    __shared__ float csT[2][64];        // 512B (per-tile colsum, dbuf)
    __shared__ float qred[256];
    const int tid = threadIdx.x, lane = tid & 63, wloc = tid >> 6;
    const int fr = lane & 15, fq = lane >> 4;
    int b, split, ttile;
    xcd_remap(blockIdx.x, b, split, ttile);
    const int t0 = ttile * 64;

    if (tid < 128) ((float*)csT)[tid] = 0.f;

    bf16x8 qh[4];
    load_qfrags(qb, (size_t)b * TT + t0 + wloc * 16 + fr, fq, qh);

    float inv[4];
#pragma unroll
    for (int i = 0; i < 4; ++i)
        inv[i] = 1.0f / rowmax[b * TT + t0 + wloc * 16 + fq * 4 + i];

    f32x4 oacc[8];
#pragma unroll
    for (int n = 0; n < 8; ++n) oacc[n] = (f32x4){0.f, 0.f, 0.f, 0.f};
    float qtp = 0.f;

    const int sBeg = split * SCHUNK;
    const size_t kbase = (size_t)b * SS;
    float* cprow = &cpart[((size_t)(b * 16 + ttile)) * SS + sBeg];

    stage_k64_async(kb, kbase + sBeg, tid, Ks[0]);
    stage_v64_async(vT, b, sBeg, tid, Vs[0]);

    for (int t = 0; t < NT; ++t) {
        const int bf = t & 1;
        __syncthreads();   // stage(t) landed; Ph + victim buffers free

        if (t + 1 < NT) {  // issue next-tile staging NOW — covered by QK+softmax+PV
            stage_k64_async(kb, kbase + sBeg + (t + 1) * 64, tid, Ks[bf ^ 1]);
            stage_v64_async(vT, b, sBeg + (t + 1) * 64, tid, Vs[bf ^ 1]);
        }

        f32x4 acc[4];
#pragma unroll
        for (int n = 0; n < 4; ++n) acc[n] = (f32x4){0.f, 0.f, 0.f, 0.f};
        __builtin_amdgcn_s_setprio(1);
        qk_mfma4(qh, Ks[bf], fr, fq, acc);
        __builtin_amdgcn_s_setprio(0);

        // softmax: wei bits unchanged; qt_loss logs grouped 8-to-1
        // (prod of 8 values in [1e-4, ~1.0001] >= 1e-32 — no underflow)
        float prod = 1.f;
#pragma unroll
        for (int n = 0; n < 4; ++n) {
            float cp = 0.f;
#pragma unroll
            for (int i = 0; i < 4; ++i) {
                float w = acc[n][i] * SCALEF;
                float w2 = w * w;
                float wei = w2 * inv[i];
                prod *= (wei + 1e-4f);
                cp += wei;
                int r = wloc * 16 + fq * 4 + i;
                int sw = (n * 16 + fr) ^ ((r & 7) << 3);
                Ph[r * 64 + sw] = (short)f2bf(wei);
            }
            cp += __shfl_xor(cp, 16, 64);
            cp += __shfl_xor(cp, 32, 64);
            if (fq == 0) atomicAdd(&csT[bf][n * 16 + fr], cp);
            if (n == 1) { qtp += __logf(prod); prod = 1.f; }
        }
        qtp += __logf(prod);

        LGKM0();
        SBAR(); SCB();   // Ph + csT[bf] visible; staged loads NOT drained
        // write per-tile colsum + reset buffer for tile t+2 (next use after 2 barriers)
        if (tid < 64) {
            cprow[t * 64 + tid] = csT[bf][tid];
            csT[bf][tid] = 0.f;
        }
        // PV
        {
            int rA = wloc * 16 + fr;
            __builtin_amdgcn_s_setprio(1);
#pragma unroll
            for (int k = 0; k < 2; ++k) {
                int offA = rA * 64 + ((k * 32 + fq * 8) ^ ((rA & 7) << 3));
                bf16x8 ph = *(const bf16x8*)&Ph[offA];
#pragma unroll
                for (int n = 0; n < 8; ++n) {
                    int hc = n * 16 + fr;
                    int offB = hc * 64 + ((k * 32 + fq * 8) ^ ((hc & 7) << 3));
                    bf16x8 vh = *(const bf16x8*)&Vs[bf][offB];
                    oacc[n] = __builtin_amdgcn_mfma_f32_16x16x32_bf16(ph, vh, oacc[n], 0, 0, 0);
                }
            }
            __builtin_amdgcn_s_setprio(0);
        }
    }

#pragma unroll
    for (int n = 0; n < 8; ++n)
#pragma unroll
        for (int i = 0; i < 4; ++i)
            atomicAdd(&outAcc[((size_t)b * TT + t0 + wloc * 16 + fq * 4 + i) * HH + n * 16 + fr],
                      oacc[n][i]);

    qred[tid] = qtp;
    __syncthreads();
    for (int off = 128; off; off >>= 1) {
        if (tid < off) qred[tid] += qred[tid + off];
        __syncthreads();
    }
    if (tid == 0) atomicAdd(qtloss, qred[0]);
}

// ---------------- K5: fused rank + bitonic sort (blocks 0..7) + eviction-tail copy (blocks 8..1031) ----
__global__ __launch_bounds__(1024) void k_ranksort(
    const float* __restrict__ cpart, const float* __restrict__ mrank,
    float* __restrict__ csum, unsigned long long* __restrict__ keys,
    const float* __restrict__ inp, float* __restrict__ nmem,
    float* __restrict__ ndist, float* __restrict__ nrank)
{
    __shared__ unsigned long long a[MM];   // 64KB
    __shared__ float red[1024];            // 4KB
    const int blk = blockIdx.x, tid = threadIdx.x;

    if (blk >= BB) {
        // ---- tail copy: new_memory[RKEEP..MM) = inp tail; dist=0, rank=1 ----
        const int idx = blk - BB;            // 0..1023, 128 blocks per batch
        const int b = idx >> 7;
        const int r0 = RKEEP + (idx & 127) * 8;
#pragma unroll
        for (int rr = 0; rr < 2; ++rr) {
            int row = r0 + rr * 4 + (tid >> 8);     // 4 rows per pass
            int irow = row - RKEEP;
            int c4 = (tid & 255) * 4;
            *(f32x4*)&nmem[((size_t)b * MM + row) * EE + c4] =
                *(const f32x4*)&inp[((size_t)b * TT + irow) * EE + c4];
        }
        if (tid < 8) {
            int p = r0 + tid;
            ndist[b * MM + p] = 0.f;
            nrank[b * MM + p] = 1.0f;
        }
        return;
    }

    const int b = blk;
    // ---- rank phase ----
    float p = 0.f;
    for (int s = tid; s < SS; s += 1024) {
        float cs = 0.f;
#pragma unroll
        for (int tt = 0; tt < 16; ++tt) cs += cpart[((size_t)(b * 16 + tt)) * SS + s];
        csum[b * SS + s] = cs;
        p += cs;
    }
    red[tid] = p;
    __syncthreads();
    for (int off = 512; off; off >>= 1) {
        if (tid < off) red[tid] += red[tid + off];
        __syncthreads();
    }
    float mean = red[0] / (float)SS;
    for (int m = tid; m < MM; m += 1024) {
        float rank = ((mrank[b * MM + m] + csum[b * SS + m] / mean) - 1.0f) - 0.01f;
        a[m] = ((unsigned long long)(unsigned)(~f2ord(rank)) << 32) | (unsigned)m;
    }
    __syncthreads();

    // ---- bitonic sort phase (asc by key == desc by rank, idx tiebreak) ----
    for (int k = 2; k <= MM; k <<= 1) {
        for (int j = k >> 1; j > 0; j >>= 1) {
            for (int i = tid; i < MM; i += 1024) {
                int l = i ^ j;
                if (l > i) {
                    unsigned long long x = a[i], y = a[l];
                    bool up = ((i & k) == 0);
                    if ((x > y) == up) { a[i] = y; a[l] = x; }
                }
            }
            __syncthreads();
        }
    }
    for (int i = tid; i < MM; i += 1024) keys[(size_t)b * MM + i] = a[i];
}

// ---------------- K6: scatter kept rows only (p < RKEEP), prefetched ----------------
__global__ __launch_bounds__(256) void k_scatter(
    const float* __restrict__ memory, const int* __restrict__ mbd,
    const int* __restrict__ bpl, const unsigned long long* __restrict__ keys,
    float* __restrict__ nmem, float* __restrict__ ndist, float* __restrict__ nrank)
{
    const int blk = blockIdx.x;
    const int b = blk / (RKEEP / 8);           // 896 blocks per batch
    const int p0 = (blk % (RKEEP / 8)) * 8;
    const bool reset = (bpl[b] == 0);
    const int tid = threadIdx.x;
    const f32x4 zero = (f32x4){0.f, 0.f, 0.f, 0.f};

    f32x4 vr[8];
    float dist[8], rankv[8];
#pragma unroll
    for (int r = 0; r < 8; ++r) {
        int p = p0 + r;
        unsigned long long key = keys[(size_t)b * MM + p];
        int src = (int)(unsigned)(key & 0xFFFFFFFFu);
        vr[r] = reset ? zero
                      : *(const f32x4*)&memory[((size_t)b * MM + src) * EE + tid * 4];
        dist[r]  = reset ? 1.0f : (float)(mbd[b * MM + src] + 1);
        rankv[r] = ord2f(~(unsigned)(key >> 32));
    }
#pragma unroll
    for (int r = 0; r < 8; ++r) {
        int p = p0 + r;
        *(f32x4*)&nmem[((size_t)b * MM + p) * EE + tid * 4] = vr[r];
        if (tid == 0) { ndist[b * MM + p] = dist[r]; nrank[b * MM + p] = rankv[r]; }
    }
}

// ---------------- launcher ----------------
extern "C" void kernel_launch(void* const* d_in, const int* in_sizes, int n_in,
                              void* d_out, int out_size, void* d_ws, size_t ws_size,
                              hipStream_t stream)
{
    const int*   bpl    = (const int*)d_in[0];
    const float* inp    = (const float*)d_in[1];
    const float* memory = (const float*)d_in[2];
    const int*   mbd    = (const int*)d_in[3];
    const float* mrank  = (const float*)d_in[4];
    const float* pos    = (const float*)d_in[5];
    const float* Wk     = (const float*)d_in[6];
    const float* Wq     = (const float*)d_in[7];
    const float* Wv     = (const float*)d_in[8];

    float* out   = (float*)d_out;                    // [B,T,H]
    float* qtl   = out + (size_t)BB * TT * HH;       // scalar
    float* nmem  = qtl + 1;                          // [B,M,E]
    float* ndist = nmem + (size_t)BB * MM * EE;      // [B,M]
    float* nrank = ndist + (size_t)BB * MM;          // [B,M]

    char* w = (char*)d_ws;
    short* qb = (short*)w; w += (size_t)BB * TT * HH * 2;
    short* kb = (short*)w; w += (size_t)BB * SS * HH * 2;
    short* vT = (short*)w; w += (size_t)BB * HH * SS * 2;
    float* rmax = (float*)w; w += (size_t)BB * TT * 4;
    float* csum = (float*)w; w += (size_t)BB * SS * 4;
    float* cpart = (float*)w; w += (size_t)BB * 16 * SS * 4;
    unsigned long long* keys = (unsigned long long*)w; w += (size_t)BB * MM * 8;
    short* wk = (short*)w; w += (size_t)HH * EE * 2;
    short* wq = (short*)w; w += (size_t)HH * EE * 2;
    short* wv = (short*)w; w += (size_t)HH * EE * 2;
    if ((size_t)(w - (char*)d_ws) > ws_size) return;

    k_init   <<<512, 256, 0, stream>>>(Wk, Wq, Wv, wk, wq, wv, out, rmax);
    k_proj   <<<dim3(NKVBLK + TT / 64, BB), 256, 0, stream>>>(memory, mbd, bpl, pos, inp,
                                                              wk, wv, wq, kb, vT, qb);
    k_rowmax <<<NSPLIT * (TT / 64) * BB, 256, 0, stream>>>(qb, kb, rmax);
    k_attn   <<<NSPLIT * (TT / 64) * BB, 256, 0, stream>>>(qb, kb, vT,
                                                           rmax, out, cpart, qtl);
    k_ranksort<<<BB + BB * 128, 1024, 0, stream>>>(cpart, mrank, csum, keys,
                                                   inp, nmem, ndist, nrank);
    k_scatter<<<BB * (RKEEP / 8), 256, 0, stream>>>(memory, mbd, bpl, keys,
                                                    nmem, ndist, nrank);
}

// Round 23
// 487.848 us; speedup vs baseline: 1.2479x; 1.0028x over previous
//
#include <hip/hip_runtime.h>
#include <hip/hip_bf16.h>
#include <stdint.h>

#define BB 8
#define TT 1024
#define MM 8192
#define EE 1024
#define HH 128
#define SS (MM + TT)          // 9216
#define RKEEP (MM - 1024)     // 7168 rows kept after eviction
#define NSPLIT 4
#define SCHUNK (SS / NSPLIT)  // 2304
#define NT (SCHUNK / 64)      // 36
#define BK 32
#define NKVBLK (SS / 64)      // 144

typedef __attribute__((ext_vector_type(8))) short bf16x8;
typedef __attribute__((ext_vector_type(4))) short s16x4;
typedef __attribute__((ext_vector_type(4))) float f32x4;

#define VMCNT(n) asm volatile("s_waitcnt vmcnt(" #n ")" ::: "memory")
#define LGKM0()  asm volatile("s_waitcnt lgkmcnt(0)" ::: "memory")
#define SBAR()   __builtin_amdgcn_s_barrier()
#define SCB()    __builtin_amdgcn_sched_barrier(0)

static __device__ __forceinline__ unsigned f2ord(float f) {
    unsigned u = __float_as_uint(f);
    return u ^ ((u & 0x80000000u) ? 0xFFFFFFFFu : 0x80000000u);
}
static __device__ __forceinline__ float ord2f(unsigned o) {
    unsigned u = (o & 0x80000000u) ? (o ^ 0x80000000u) : ~o;
    return __uint_as_float(u);
}
static __device__ __forceinline__ unsigned short f2bf(float x) {
    unsigned u = __float_as_uint(x);
    unsigned r = u + 0x7FFFu + ((u >> 16) & 1u);   // RNE
    return (unsigned short)(r >> 16);
}

// async global->LDS, 16B per lane; dest = wave-uniform base + lane*16
static __device__ __forceinline__ void gload_lds16(const short* g, short* l) {
    __builtin_amdgcn_global_load_lds(
        (const __attribute__((address_space(1))) void*)g,
        (__attribute__((address_space(3))) void*)l, 16, 0, 0);
}

__device__ const float SCALEF = (float)(1.0 / 96.0);  // (M+T)^-0.5

// ---------------- K0: weights -> bf16 planes (zeroing folded into k_proj) ----------------
__global__ __launch_bounds__(256) void k_init(
    const float* __restrict__ Wk, const float* __restrict__ Wq, const float* __restrict__ Wv,
    short* __restrict__ wk, short* __restrict__ wq, short* __restrict__ wv)
{
    int idx = blockIdx.x * 256 + threadIdx.x;
    int m = idx >> 15;
    int o4 = (idx & 32767) * 4;
    const float* W = m == 0 ? Wk : (m == 1 ? Wq : Wv);
    short* D = m == 0 ? wk : (m == 1 ? wq : wv);
    f32x4 v = *(const f32x4*)&W[o4];
    s16x4 h;
#pragma unroll
    for (int j = 0; j < 4; ++j) h[j] = (short)f2bf(v[j]);
    *(s16x4*)&D[o4] = h;
}

// ---------------- K1: fused K,V + Q projection — wave-private W staging ----------------
// Q-path blocks additionally zero out/qtl/rmax in their prologue (drained by the
// prologue __syncthreads before any counted-vmcnt code).
__global__ __launch_bounds__(256, 3) void k_proj(
    const float* __restrict__ memory, const int* __restrict__ mbd,
    const int* __restrict__ bpl, const float* __restrict__ pos_table,
    const float* __restrict__ inp,
    const short* __restrict__ wk, const short* __restrict__ wv,
    const short* __restrict__ wq,
    short* __restrict__ kb, short* __restrict__ vT, short* __restrict__ qb,
    float* __restrict__ outZ, float* __restrict__ rmaxZ)
{
    __shared__ __align__(16) short smA[2][64 * 64];        // 16KB (A panel dbuf)
    __shared__ __align__(16) short smB[2][2][4][1024];     // 32KB: [buf][plane][wave][32x32 slice]

    const int tid = threadIdx.x;
    const int b   = blockIdx.y;
    const int lane = tid & 63, wid = tid >> 6;
    const int wc = wid;
    const int fr = lane & 15, fq = lane >> 4;
    const int arow = tid >> 2;
    const int aq   = tid & 3;
    const int hl0 = (lane >> 2);
    const int sch = (lane & 3);

    if (blockIdx.x < NKVBLK) {
        // ================= KV path =================
        const int s0 = blockIdx.x * 64;
        const bool reset = (bpl[b] == 0);
        int pix;
        const float* abase;
        {
            int s = s0 + arow;
            if (s < MM) {
                int d = reset ? 1 : (mbd[b * MM + s] + 1);
                pix = 31 - __clz(d);
                abase = reset ? nullptr : &memory[((size_t)b * MM + s) * EE];
            } else {
                pix = -1;
                abase = &inp[((size_t)b * TT + (s - MM)) * EE];
            }
        }

        f32x4 accK[4][2], accV[4][2];
#pragma unroll
        for (int m = 0; m < 4; ++m)
#pragma unroll
            for (int n = 0; n < 2; ++n) {
                accK[m][n] = (f32x4){0.f, 0.f, 0.f, 0.f};
                accV[m][n] = (f32x4){0.f, 0.f, 0.f, 0.f};
            }

        auto STAGEW = [&](int e0, int buf) {   // 4 gload_lds, wave-private dest
#pragma unroll
            for (int c2 = 0; c2 < 2; ++c2) {
                int hlocal = c2 * 16 + hl0;
                int h = wc * 32 + hlocal;
                int ec = ((sch ^ (hlocal & 3)) << 3);
                size_t g = (size_t)h * EE + e0 + ec;
                gload_lds16(&wk[g], &smB[buf][0][wid][c2 * 512]);
                gload_lds16(&wv[g], &smB[buf][1][wid][c2 * 512]);
            }
        };
        auto LOADP = [&](int p, f32x4 xa[4]) {
            int e0 = p * 64 + aq * 16;
#pragma unroll
            for (int j = 0; j < 4; ++j) {
                f32x4 v = (f32x4){0.f, 0.f, 0.f, 0.f};
                if (abase) v = *(const f32x4*)&abase[e0 + j * 4];
                if (pix >= 0) {
                    f32x4 pt = *(const f32x4*)&pos_table[(size_t)pix * EE + e0 + j * 4];
                    v[0] += pt[0]; v[1] += pt[1]; v[2] += pt[2]; v[3] += pt[3];
                }
                xa[j] = v;
            }
        };
        auto STOREP = [&](const f32x4 xa[4], int abuf) {
#pragma unroll
            for (int j = 0; j < 2; ++j) {
                bf16x8 h;
#pragma unroll
                for (int c = 0; c < 4; ++c) {
                    h[c]     = (short)f2bf(xa[2 * j][c]);
                    h[4 + c] = (short)f2bf(xa[2 * j + 1][c]);
                }
                int g = (aq * 2 + j) ^ (arow & 7);
                *(bf16x8*)&smA[abuf][arow * 64 + g * 8] = h;
            }
        };

        f32x4 xa[4];
        LOADP(0, xa);
        STOREP(xa, 0);
        STAGEW(0, 0);
        __syncthreads();          // prologue: full drain (STAGEW(0) + smA visible)
        LOADP(1, xa);

        for (int step = 0; step < 32; ++step) {
            const int wbuf = step & 1;
            const int pbuf = (step >> 1) & 1;
            if (step < 31) STAGEW((step + 1) * BK, wbuf ^ 1);
            SCB();
            if (step == 31)           { VMCNT(0); }
            else if (step & 1)        { VMCNT(4); }
            else if (step <= 28)      { VMCNT(8); }
            else                      { VMCNT(4); }
            SCB();

            const int sseg = step & 1;
            bf16x8 ah[4];
#pragma unroll
            for (int m = 0; m < 4; ++m) {
                int r = m * 16 + fr;
                int g = (sseg * 4 + fq) ^ (r & 7);
                ah[m] = *(const bf16x8*)&smA[pbuf][r * 64 + g * 8];
            }
#pragma unroll
            for (int n = 0; n < 2; ++n) {
                int off = n * 512 + fr * 32 + ((fq ^ (fr & 3)) << 3);
                bf16x8 kh = *(const bf16x8*)&smB[wbuf][0][wid][off];
                bf16x8 vh = *(const bf16x8*)&smB[wbuf][1][wid][off];
#pragma unroll
                for (int m = 0; m < 4; ++m) {
                    accK[m][n] = __builtin_amdgcn_mfma_f32_16x16x32_bf16(ah[m], kh, accK[m][n], 0, 0, 0);
                    accV[m][n] = __builtin_amdgcn_mfma_f32_16x16x32_bf16(ah[m], vh, accV[m][n], 0, 0, 0);
                }
            }
            if ((step & 1) && step < 31) {      // A-panel swap: lgkm-only barrier
                STOREP(xa, pbuf ^ 1);
                LGKM0(); SBAR(); SCB();
                if (step < 29) LOADP((step >> 1) + 2, xa);
            }
        }

        // K epilogue
#pragma unroll
        for (int m = 0; m < 4; ++m) {
            int row = s0 + m * 16 + fq * 4;
#pragma unroll
            for (int n = 0; n < 2; ++n) {
                int col = wc * 32 + n * 16 + fr;
#pragma unroll
                for (int i = 0; i < 4; ++i)
                    kb[((size_t)b * SS + row + i) * HH + col] = (short)f2bf(accK[m][n][i]);
            }
        }
        // V epilogue: transpose via LDS (aliasing smB)
        float* tpT = (float*)smB;
#pragma unroll
        for (int hp = 0; hp < 4; ++hp) {
            __syncthreads();
            if (wc == hp) {
#pragma unroll
                for (int m = 0; m < 4; ++m)
#pragma unroll
                    for (int n = 0; n < 2; ++n) {
                        int cl = n * 16 + fr;
                        int row = m * 16 + fq * 4;
                        *(f32x4*)&tpT[cl * 68 + row] = accV[m][n];
                    }
            }
            __syncthreads();
            for (int idx = tid; idx < 32 * 16; idx += 256) {
                int hcl = idx >> 4, s4 = (idx & 15) << 2;
                f32x4 v = *(const f32x4*)&tpT[hcl * 68 + s4];
                s16x4 hi;
#pragma unroll
                for (int j = 0; j < 4; ++j) hi[j] = (short)f2bf(v[j]);
                size_t o = ((size_t)b * HH + hp * 32 + hcl) * SS + s0 + s4;
                *(s16x4*)&vT[o] = hi;
            }
        }
    } else {
        // ================= Q path =================
        // prologue zeroing of out/qtl/rmax (128 Q blocks across the grid)
        {
            const int zid = (b * (TT / 64) + (blockIdx.x - NKVBLK)) * 256 + tid;  // [0, 32768)
            const f32x4 zero = (f32x4){0.f, 0.f, 0.f, 0.f};
#pragma unroll
            for (int i = 0; i < 8; ++i)
                ((f32x4*)outZ)[zid + i * 32768] = zero;        // 262144 f32x4 = out[B,T,H]
            if (zid == 0) outZ[BB * TT * HH] = 0.f;            // qt_loss scalar
            if (zid < (BB * TT) / 4) ((f32x4*)rmaxZ)[zid] = zero;
        }

        const int t0 = (blockIdx.x - NKVBLK) * 64;
        const float* abase = &inp[((size_t)b * TT + t0 + arow) * EE];

        f32x4 acc[4][2];
#pragma unroll
        for (int m = 0; m < 4; ++m)
#pragma unroll
            for (int n = 0; n < 2; ++n) acc[m][n] = (f32x4){0.f, 0.f, 0.f, 0.f};

        auto STAGEWQ = [&](int e0, int buf) {   // 2 gload_lds, wave-private dest
#pragma unroll
            for (int c2 = 0; c2 < 2; ++c2) {
                int hlocal = c2 * 16 + hl0;
                int h = wc * 32 + hlocal;
                int ec = ((sch ^ (hlocal & 3)) << 3);
                size_t g = (size_t)h * EE + e0 + ec;
                gload_lds16(&wq[g], &smB[buf][0][wid][c2 * 512]);
            }
        };
        auto LOADPQ = [&](int p, f32x4 xa[4]) {
            int e0 = p * 64 + aq * 16;
#pragma unroll
            for (int j = 0; j < 4; ++j) xa[j] = *(const f32x4*)&abase[e0 + j * 4];
        };
        auto STOREPQ = [&](const f32x4 xa[4], int abuf) {
#pragma unroll
            for (int j = 0; j < 2; ++j) {
                bf16x8 h;
#pragma unroll
                for (int c = 0; c < 4; ++c) {
                    h[c]     = (short)f2bf(xa[2 * j][c]);
                    h[4 + c] = (short)f2bf(xa[2 * j + 1][c]);
                }
                int g = (aq * 2 + j) ^ (arow & 7);
                *(bf16x8*)&smA[abuf][arow * 64 + g * 8] = h;
            }
        };

        f32x4 xa[4];
        LOADPQ(0, xa);
        STOREPQ(xa, 0);
        STAGEWQ(0, 0);
        __syncthreads();          // full drain: zero-stores + STAGEWQ(0) retired
        LOADPQ(1, xa);

        for (int step = 0; step < 32; ++step) {
            const int wbuf = step & 1;
            const int pbuf = (step >> 1) & 1;
            if (step < 31) STAGEWQ((step + 1) * BK, wbuf ^ 1);
            SCB();
            if (step == 31)           { VMCNT(0); }
            else if (step & 1)        { VMCNT(2); }
            else if (step <= 28)      { VMCNT(6); }
            else                      { VMCNT(2); }
            SCB();

            const int sseg = step & 1;
            bf16x8 ah[4];
#pragma unroll
            for (int m = 0; m < 4; ++m) {
                int r = m * 16 + fr;
                int g = (sseg * 4 + fq) ^ (r & 7);
                ah[m] = *(const bf16x8*)&smA[pbuf][r * 64 + g * 8];
            }
#pragma unroll
            for (int n = 0; n < 2; ++n) {
                int off = n * 512 + fr * 32 + ((fq ^ (fr & 3)) << 3);
                bf16x8 bh = *(const bf16x8*)&smB[wbuf][0][wid][off];
#pragma unroll
                for (int m = 0; m < 4; ++m)
                    acc[m][n] = __builtin_amdgcn_mfma_f32_16x16x32_bf16(ah[m], bh, acc[m][n], 0, 0, 0);
            }
            if ((step & 1) && step < 31) {
                STOREPQ(xa, pbuf ^ 1);
                LGKM0(); SBAR(); SCB();
                if (step < 29) LOADPQ((step >> 1) + 2, xa);
            }
        }
#pragma unroll
        for (int m = 0; m < 4; ++m) {
            int row = t0 + m * 16 + fq * 4;
#pragma unroll
            for (int n = 0; n < 2; ++n) {
                int col = wc * 32 + n * 16 + fr;
#pragma unroll
                for (int i = 0; i < 4; ++i)
                    qb[((size_t)b * TT + row + i) * HH + col] = (short)f2bf(acc[m][n][i]);
            }
        }
    }
}

// ---------------- shared attn helpers ----------------
__device__ __forceinline__ void stage_k64_async(const short* __restrict__ src,
                                                size_t rowBase, int tid, short* sh)
{
#pragma unroll
    for (int c2 = 0; c2 < 4; ++c2) {
        int srow = c2 * 16 + (tid >> 4);
        int scol = ((tid & 15) * 8) ^ ((srow & 7) << 3);
        size_t g = (rowBase + srow) * HH + scol;
        gload_lds16(&src[g], &sh[c2 * 2048 + (tid >> 6) * 512]);
    }
}

__device__ __forceinline__ void stage_v64_async(const short* __restrict__ vT,
                                                int b, int st, int tid, short* vs)
{
#pragma unroll
    for (int c2 = 0; c2 < 4; ++c2) {
        int h = c2 * 32 + (tid >> 3);
        int sc = ((tid & 7) * 8) ^ ((h & 7) << 3);
        size_t g = ((size_t)b * HH + h) * SS + st + sc;
        gload_lds16(&vT[g], &vs[c2 * 2048 + (tid >> 6) * 512]);
    }
}

__device__ __forceinline__ void load_qfrags(const short* __restrict__ qb,
                                            size_t rowIx, int fq, bf16x8 qh[4])
{
    size_t base = rowIx * HH + fq * 8;
#pragma unroll
    for (int k = 0; k < 4; ++k)
        qh[k] = *(const bf16x8*)&qb[base + k * 32];
}

__device__ __forceinline__ void qk_mfma4(const bf16x8 qh[4], const short* sh,
                                         int fr, int fq, f32x4 acc[4])
{
#pragma unroll
    for (int n = 0; n < 4; ++n) {
        int sc = n * 16 + fr;
        int ro = sc * 128, msk = (sc & 7) << 3;
#pragma unroll
        for (int k = 0; k < 4; ++k) {
            int off = ro + ((k * 32 + fq * 8) ^ msk);
            bf16x8 bh = *(const bf16x8*)&sh[off];
            acc[n] = __builtin_amdgcn_mfma_f32_16x16x32_bf16(qh[k], bh, acc[n], 0, 0, 0);
        }
    }
}

// XCD-aware remap: flat f in [0,512) -> (b, split, ttile); all 16 ttile-members of
// a (b,split) group share f%8 (same XCD under round-robin dispatch).
__device__ __forceinline__ void xcd_remap(int f, int& b, int& split, int& ttile)
{
    int xcd = f & 7, slot = f >> 3;
    int g = (slot >> 4) * 8 + xcd;    // group id in [0,32)
    ttile = slot & 15;
    b = g >> 2;
    split = g & 3;
}

// ---------------- K3: rowmax of (qk*scale)^2 via MFMA (dbuf K, 32KB) ----------------
__global__ __launch_bounds__(256) void k_rowmax(
    const short* __restrict__ qb, const short* __restrict__ kb,
    float* __restrict__ rowmax)
{
    __shared__ short Ks[2][64 * 128];   // 32KB
    const int tid = threadIdx.x, lane = tid & 63, wloc = tid >> 6;
    const int fr = lane & 15, fq = lane >> 4;
    int b, split, ttile;
    xcd_remap(blockIdx.x, b, split, ttile);
    const int t0 = ttile * 64;

    bf16x8 qh[4];
    load_qfrags(qb, (size_t)b * TT + t0 + wloc * 16 + fr, fq, qh);

    float rm[4] = {0.f, 0.f, 0.f, 0.f};
    const int sBeg = split * SCHUNK;
    const size_t kbase = (size_t)b * SS;

    stage_k64_async(kb, kbase + sBeg, tid, Ks[0]);
    __syncthreads();
    for (int t = 0; t < NT; ++t) {
        const int bf = t & 1;
        if (t + 1 < NT)
            stage_k64_async(kb, kbase + sBeg + (t + 1) * 64, tid, Ks[bf ^ 1]);
        f32x4 acc[4];
#pragma unroll
        for (int n = 0; n < 4; ++n) acc[n] = (f32x4){0.f, 0.f, 0.f, 0.f};
        __builtin_amdgcn_s_setprio(1);
        qk_mfma4(qh, Ks[bf], fr, fq, acc);
        __builtin_amdgcn_s_setprio(0);
#pragma unroll
        for (int n = 0; n < 4; ++n)
#pragma unroll
            for (int i = 0; i < 4; ++i) {
                float w = acc[n][i] * SCALEF;
                rm[i] = fmaxf(rm[i], w * w);
            }
        __syncthreads();   // next tile staged (covered by QK)
    }
#pragma unroll
    for (int d = 1; d < 16; d <<= 1)
#pragma unroll
        for (int i = 0; i < 4; ++i)
            rm[i] = fmaxf(rm[i], __shfl_xor(rm[i], d, 64));
    if (fr == 0)
#pragma unroll
        for (int i = 0; i < 4; ++i)
            atomicMax((int*)&rowmax[b * TT + t0 + wloc * 16 + fq * 4 + i], __float_as_int(rm[i]));
}

// ---------------- K4: attention — per-tile colsum, grouped qt_loss logs ----------------
__global__ __launch_bounds__(256) void k_attn(
    const short* __restrict__ qb, const short* __restrict__ kb,
    const short* __restrict__ vT,
    const float* __restrict__ rowmax,
    float* __restrict__ outAcc, float* __restrict__ cpart, float* __restrict__ qtloss)
{
    __shared__ short Ks[2][64 * 128];   // 32KB
    __shared__ short Vs[2][128 * 64];   // 32KB
    __shared__ short Ph[64 * 64];       // 8KB
    __shared__ float csT[2][64];        // 512B (per-tile colsum, dbuf)
    __shared__ float qred[256];
    const int tid = threadIdx.x, lane = tid & 63, wloc = tid >> 6;
    const int fr = lane & 15, fq = lane >> 4;
    int b, split, ttile;
    xcd_remap(blockIdx.x, b, split, ttile);
    const int t0 = ttile * 64;

    if (tid < 128) ((float*)csT)[tid] = 0.f;

    bf16x8 qh[4];
    load_qfrags(qb, (size_t)b * TT + t0 + wloc * 16 + fr, fq, qh);

    float inv[4];
#pragma unroll
    for (int i = 0; i < 4; ++i)
        inv[i] = 1.0f / rowmax[b * TT + t0 + wloc * 16 + fq * 4 + i];

    f32x4 oacc[8];
#pragma unroll
    for (int n = 0; n < 8; ++n) oacc[n] = (f32x4){0.f, 0.f, 0.f, 0.f};
    float qtp = 0.f;

    const int sBeg = split * SCHUNK;
    const size_t kbase = (size_t)b * SS;
    float* cprow = &cpart[((size_t)(b * 16 + ttile)) * SS + sBeg];

    stage_k64_async(kb, kbase + sBeg, tid, Ks[0]);
    stage_v64_async(vT, b, sBeg, tid, Vs[0]);

    for (int t = 0; t < NT; ++t) {
        const int bf = t & 1;
        __syncthreads();   // stage(t) landed; Ph + victim buffers free

        if (t + 1 < NT) {  // issue next-tile staging NOW — covered by QK+softmax+PV
            stage_k64_async(kb, kbase + sBeg + (t + 1) * 64, tid, Ks[bf ^ 1]);
            stage_v64_async(vT, b, sBeg + (t + 1) * 64, tid, Vs[bf ^ 1]);
        }

        f32x4 acc[4];
#pragma unroll
        for (int n = 0; n < 4; ++n) acc[n] = (f32x4){0.f, 0.f, 0.f, 0.f};
        __builtin_amdgcn_s_setprio(1);
        qk_mfma4(qh, Ks[bf], fr, fq, acc);
        __builtin_amdgcn_s_setprio(0);

        // softmax: wei bits unchanged; qt_loss logs grouped 8-to-1
        float prod = 1.f;
#pragma unroll
        for (int n = 0; n < 4; ++n) {
            float cp = 0.f;
#pragma unroll
            for (int i = 0; i < 4; ++i) {
                float w = acc[n][i] * SCALEF;
                float w2 = w * w;
                float wei = w2 * inv[i];
                prod *= (wei + 1e-4f);
                cp += wei;
                int r = wloc * 16 + fq * 4 + i;
                int sw = (n * 16 + fr) ^ ((r & 7) << 3);
                Ph[r * 64 + sw] = (short)f2bf(wei);
            }
            cp += __shfl_xor(cp, 16, 64);
            cp += __shfl_xor(cp, 32, 64);
            if (fq == 0) atomicAdd(&csT[bf][n * 16 + fr], cp);
            if (n == 1) { qtp += __logf(prod); prod = 1.f; }
        }
        qtp += __logf(prod);

        LGKM0();
        SBAR(); SCB();   // Ph + csT[bf] visible; staged loads NOT drained
        if (tid < 64) {
            cprow[t * 64 + tid] = csT[bf][tid];
            csT[bf][tid] = 0.f;
        }
        // PV
        {
            int rA = wloc * 16 + fr;
            __builtin_amdgcn_s_setprio(1);
#pragma unroll
            for (int k = 0; k < 2; ++k) {
                int offA = rA * 64 + ((k * 32 + fq * 8) ^ ((rA & 7) << 3));
                bf16x8 ph = *(const bf16x8*)&Ph[offA];
#pragma unroll
                for (int n = 0; n < 8; ++n) {
                    int hc = n * 16 + fr;
                    int offB = hc * 64 + ((k * 32 + fq * 8) ^ ((hc & 7) << 3));
                    bf16x8 vh = *(const bf16x8*)&Vs[bf][offB];
                    oacc[n] = __builtin_amdgcn_mfma_f32_16x16x32_bf16(ph, vh, oacc[n], 0, 0, 0);
                }
            }
            __builtin_amdgcn_s_setprio(0);
        }
    }

#pragma unroll
    for (int n = 0; n < 8; ++n)
#pragma unroll
        for (int i = 0; i < 4; ++i)
            atomicAdd(&outAcc[((size_t)b * TT + t0 + wloc * 16 + fq * 4 + i) * HH + n * 16 + fr],
                      oacc[n][i]);

    qred[tid] = qtp;
    __syncthreads();
    for (int off = 128; off; off >>= 1) {
        if (tid < off) qred[tid] += qred[tid + off];
        __syncthreads();
    }
    if (tid == 0) atomicAdd(qtloss, qred[0]);
}

// ---------------- K5: fused rank + bitonic sort (blocks 0..7) + eviction-tail copy ----
__global__ __launch_bounds__(1024) void k_ranksort(
    const float* __restrict__ cpart, const float* __restrict__ mrank,
    unsigned long long* __restrict__ keys,
    const float* __restrict__ inp, float* __restrict__ nmem,
    float* __restrict__ ndist, float* __restrict__ nrank)
{
    __shared__ unsigned long long a[MM];   // 64KB
    __shared__ float red[1024];            // 4KB
    const int blk = blockIdx.x, tid = threadIdx.x;

    if (blk >= BB) {
        // ---- tail copy: new_memory[RKEEP..MM) = inp tail; dist=0, rank=1 ----
        const int idx = blk - BB;            // 0..1023, 128 blocks per batch
        const int b = idx >> 7;
        const int r0 = RKEEP + (idx & 127) * 8;
#pragma unroll
        for (int rr = 0; rr < 2; ++rr) {
            int row = r0 + rr * 4 + (tid >> 8);     // 4 rows per pass
            int irow = row - RKEEP;
            int c4 = (tid & 255) * 4;
            *(f32x4*)&nmem[((size_t)b * MM + row) * EE + c4] =
                *(const f32x4*)&inp[((size_t)b * TT + irow) * EE + c4];
        }
        if (tid < 8) {
            int p = r0 + tid;
            ndist[b * MM + p] = 0.f;
            nrank[b * MM + p] = 1.0f;
        }
        return;
    }

    const int b = blk;
    // ---- rank phase: colsum kept in registers (same summation order as before) ----
    float csl[9];
    float p = 0.f;
#pragma unroll
    for (int j = 0; j < 9; ++j) {
        int s = tid + j * 1024;
        float cs = 0.f;
#pragma unroll
        for (int tt = 0; tt < 16; ++tt) cs += cpart[((size_t)(b * 16 + tt)) * SS + s];
        csl[j] = cs;
        p += cs;
    }
    red[tid] = p;
    __syncthreads();
    for (int off = 512; off; off >>= 1) {
        if (tid < off) red[tid] += red[tid + off];
        __syncthreads();
    }
    float mean = red[0] / (float)SS;
#pragma unroll
    for (int j = 0; j < 8; ++j) {
        int m = tid + j * 1024;
        float rank = ((mrank[b * MM + m] + csl[j] / mean) - 1.0f) - 0.01f;
        a[m] = ((unsigned long long)(unsigned)(~f2ord(rank)) << 32) | (unsigned)m;
    }
    __syncthreads();

    // ---- bitonic sort phase (asc by key == desc by rank, idx tiebreak) ----
    for (int k = 2; k <= MM; k <<= 1) {
        for (int j = k >> 1; j > 0; j >>= 1) {
            for (int i = tid; i < MM; i += 1024) {
                int l = i ^ j;
                if (l > i) {
                    unsigned long long x = a[i], y = a[l];
                    bool up = ((i & k) == 0);
                    if ((x > y) == up) { a[i] = y; a[l] = x; }
                }
            }
            __syncthreads();
        }
    }
    for (int i = tid; i < MM; i += 1024) keys[(size_t)b * MM + i] = a[i];
}

// ---------------- K6: scatter kept rows only (p < RKEEP), prefetched ----------------
__global__ __launch_bounds__(256) void k_scatter(
    const float* __restrict__ memory, const int* __restrict__ mbd,
    const int* __restrict__ bpl, const unsigned long long* __restrict__ keys,
    float* __restrict__ nmem, float* __restrict__ ndist, float* __restrict__ nrank)
{
    const int blk = blockIdx.x;
    const int b = blk / (RKEEP / 8);           // 896 blocks per batch
    const int p0 = (blk % (RKEEP / 8)) * 8;
    const bool reset = (bpl[b] == 0);
    const int tid = threadIdx.x;
    const f32x4 zero = (f32x4){0.f, 0.f, 0.f, 0.f};

    f32x4 vr[8];
    float dist[8], rankv[8];
#pragma unroll
    for (int r = 0; r < 8; ++r) {
        int p = p0 + r;
        unsigned long long key = keys[(size_t)b * MM + p];
        int src = (int)(unsigned)(key & 0xFFFFFFFFu);
        vr[r] = reset ? zero
                      : *(const f32x4*)&memory[((size_t)b * MM + src) * EE + tid * 4];
        dist[r]  = reset ? 1.0f : (float)(mbd[b * MM + src] + 1);
        rankv[r] = ord2f(~(unsigned)(key >> 32));
    }
#pragma unroll
    for (int r = 0; r < 8; ++r) {
        int p = p0 + r;
        *(f32x4*)&nmem[((size_t)b * MM + p) * EE + tid * 4] = vr[r];
        if (tid == 0) { ndist[b * MM + p] = dist[r]; nrank[b * MM + p] = rankv[r]; }
    }
}

// ---------------- launcher ----------------
extern "C" void kernel_launch(void* const* d_in, const int* in_sizes, int n_in,
                              void* d_out, int out_size, void* d_ws, size_t ws_size,
                              hipStream_t stream)
{
    const int*   bpl    = (const int*)d_in[0];
    const float* inp    = (const float*)d_in[1];
    const float* memory = (const float*)d_in[2];
    const int*   mbd    = (const int*)d_in[3];
    const float* mrank  = (const float*)d_in[4];
    const float* pos    = (const float*)d_in[5];
    const float* Wk     = (const float*)d_in[6];
    const float* Wq     = (const float*)d_in[7];
    const float* Wv     = (const float*)d_in[8];

    float* out   = (float*)d_out;                    // [B,T,H]
    float* qtl   = out + (size_t)BB * TT * HH;       // scalar
    float* nmem  = qtl + 1;                          // [B,M,E]
    float* ndist = nmem + (size_t)BB * MM * EE;      // [B,M]
    float* nrank = ndist + (size_t)BB * MM;          // [B,M]

    char* w = (char*)d_ws;
    short* qb = (short*)w; w += (size_t)BB * TT * HH * 2;
    short* kb = (short*)w; w += (size_t)BB * SS * HH * 2;
    short* vT = (short*)w; w += (size_t)BB * HH * SS * 2;
    float* rmax = (float*)w; w += (size_t)BB * TT * 4;
    float* csum = (float*)w; w += (size_t)BB * SS * 4;   // (unused, layout kept)
    float* cpart = (float*)w; w += (size_t)BB * 16 * SS * 4;
    unsigned long long* keys = (unsigned long long*)w; w += (size_t)BB * MM * 8;
    short* wk = (short*)w; w += (size_t)HH * EE * 2;
    short* wq = (short*)w; w += (size_t)HH * EE * 2;
    short* wv = (short*)w; w += (size_t)HH * EE * 2;
    (void)csum;
    if ((size_t)(w - (char*)d_ws) > ws_size) return;

    k_init   <<<384, 256, 0, stream>>>(Wk, Wq, Wv, wk, wq, wv);
    k_proj   <<<dim3(NKVBLK + TT / 64, BB), 256, 0, stream>>>(memory, mbd, bpl, pos, inp,
                                                              wk, wv, wq, kb, vT, qb,
                                                              out, rmax);
    k_rowmax <<<NSPLIT * (TT / 64) * BB, 256, 0, stream>>>(qb, kb, rmax);
    k_attn   <<<NSPLIT * (TT / 64) * BB, 256, 0, stream>>>(qb, kb, vT,
                                                           rmax, out, cpart, qtl);
    k_ranksort<<<BB + BB * 128, 1024, 0, stream>>>(cpart, mrank, keys,
                                                   inp, nmem, ndist, nrank);
    k_scatter<<<BB * (RKEEP / 8), 256, 0, stream>>>(memory, mbd, bpl, keys,
                                                    nmem, ndist, nrank);
}